// Round 3
// baseline (2126.791 us; speedup 1.0000x reference)
//
#include <hip/hip_runtime.h>

#define NB 2
#define NS 2048
#define ND 1024
#define NH 16
#define NDK 64
#define NM (NB*NS)   // 4096

// NOTE (layout, verified via npz sizes round 0-2): d_out = REAL part of the
// reference output only: out_size = B*S*D f32. Imag parts of V/O projections
// are dead code; imag contributes only through scores = QrKr - QiKi.

// ========= dual-plane projection (Q, K): Y{r,i} = (X{r,i} @ W + b) * scale =========
// scatter to (B, NH, S, DK) planes.
__global__ __launch_bounds__(256)
void gemm_qk(const float* __restrict__ Xr, const float* __restrict__ Xi,
             const float* __restrict__ W, const float* __restrict__ bias,
             float* __restrict__ Yr, float* __restrict__ Yi, const float scale)
{
    __shared__ float As_r[64][20];
    __shared__ float As_i[64][20];
    __shared__ float Bs[16][68];

    const int tid = threadIdx.x;
    const int tx = tid & 15;
    const int ty = tid >> 4;
    const int row0 = blockIdx.y * 64;
    const int col0 = blockIdx.x * 64;

    const int lr = tid >> 2;
    const int lk = (tid & 3) * 4;
    const int bk = tid >> 4;
    const int bc = (tid & 15) * 4;

    float accr[4][4] = {{0.f}};
    float acci[4][4] = {{0.f}};

    for (int k0 = 0; k0 < ND; k0 += 16) {
        const float4 a_r = *reinterpret_cast<const float4*>(&Xr[(size_t)(row0 + lr) * ND + k0 + lk]);
        const float4 a_i = *reinterpret_cast<const float4*>(&Xi[(size_t)(row0 + lr) * ND + k0 + lk]);
        const float4 b_v = *reinterpret_cast<const float4*>(&W [(size_t)(k0 + bk) * ND + col0 + bc]);
        *reinterpret_cast<float4*>(&As_r[lr][lk]) = a_r;
        *reinterpret_cast<float4*>(&As_i[lr][lk]) = a_i;
        *reinterpret_cast<float4*>(&Bs[bk][bc])   = b_v;
        __syncthreads();

        #pragma unroll
        for (int k = 0; k < 16; ++k) {
            float bv[4];
            #pragma unroll
            for (int j = 0; j < 4; ++j) bv[j] = Bs[k][tx*4 + j];
            #pragma unroll
            for (int i = 0; i < 4; ++i) {
                const float ar = As_r[ty*4 + i][k];
                const float ai = As_i[ty*4 + i][k];
                #pragma unroll
                for (int j = 0; j < 4; ++j) {
                    accr[i][j] = fmaf(ar, bv[j], accr[i][j]);
                    acci[i][j] = fmaf(ai, bv[j], acci[i][j]);
                }
            }
        }
        __syncthreads();
    }

    #pragma unroll
    for (int i = 0; i < 4; ++i) {
        const int m = row0 + ty*4 + i;
        const int b = m >> 11;
        const int s = m & (NS - 1);
        #pragma unroll
        for (int j = 0; j < 4; ++j) {
            const int n  = col0 + tx*4 + j;
            const int h  = n >> 6;
            const int dk = n & 63;
            const size_t idx = (((size_t)(b*NH + h) * NS) + s) * NDK + dk;
            Yr[idx] = (accr[i][j] + bias[n]) * scale;
            Yi[idx] = acci[i][j] * scale;
        }
    }
}

// ========= single-plane projection (V real part): Yr = Xr @ W + b =========
__global__ __launch_bounds__(256)
void gemm_v(const float* __restrict__ Xr, const float* __restrict__ W,
            const float* __restrict__ bias, float* __restrict__ Yr)
{
    __shared__ float As[64][20];
    __shared__ float Bs[16][68];

    const int tid = threadIdx.x;
    const int tx = tid & 15;
    const int ty = tid >> 4;
    const int row0 = blockIdx.y * 64;
    const int col0 = blockIdx.x * 64;

    const int lr = tid >> 2;
    const int lk = (tid & 3) * 4;
    const int bk = tid >> 4;
    const int bc = (tid & 15) * 4;

    float acc[4][4] = {{0.f}};

    for (int k0 = 0; k0 < ND; k0 += 16) {
        const float4 a_v = *reinterpret_cast<const float4*>(&Xr[(size_t)(row0 + lr) * ND + k0 + lk]);
        const float4 b_v = *reinterpret_cast<const float4*>(&W [(size_t)(k0 + bk) * ND + col0 + bc]);
        *reinterpret_cast<float4*>(&As[lr][lk]) = a_v;
        *reinterpret_cast<float4*>(&Bs[bk][bc]) = b_v;
        __syncthreads();

        #pragma unroll
        for (int k = 0; k < 16; ++k) {
            float bv[4];
            #pragma unroll
            for (int j = 0; j < 4; ++j) bv[j] = Bs[k][tx*4 + j];
            #pragma unroll
            for (int i = 0; i < 4; ++i) {
                const float av = As[ty*4 + i][k];
                #pragma unroll
                for (int j = 0; j < 4; ++j)
                    acc[i][j] = fmaf(av, bv[j], acc[i][j]);
            }
        }
        __syncthreads();
    }

    #pragma unroll
    for (int i = 0; i < 4; ++i) {
        const int m = row0 + ty*4 + i;
        const int b = m >> 11;
        const int s = m & (NS - 1);
        #pragma unroll
        for (int j = 0; j < 4; ++j) {
            const int n  = col0 + tx*4 + j;
            const int h  = n >> 6;
            const int dk = n & 63;
            const size_t idx = (((size_t)(b*NH + h) * NS) + s) * NDK + dk;
            Yr[idx] = acc[i][j] + bias[n];
        }
    }
}

// ========= final projection: out = X @ Wo + bo (all real), plain (M,N) =========
__global__ __launch_bounds__(256)
void gemm_o(const float* __restrict__ X, const float* __restrict__ W,
            const float* __restrict__ bias, float* __restrict__ Y)
{
    __shared__ float As[64][20];
    __shared__ float Bs[16][68];

    const int tid = threadIdx.x;
    const int tx = tid & 15;
    const int ty = tid >> 4;
    const int row0 = blockIdx.y * 64;
    const int col0 = blockIdx.x * 64;

    const int lr = tid >> 2;
    const int lk = (tid & 3) * 4;
    const int bk = tid >> 4;
    const int bc = (tid & 15) * 4;

    float acc[4][4] = {{0.f}};

    for (int k0 = 0; k0 < ND; k0 += 16) {
        const float4 a_v = *reinterpret_cast<const float4*>(&X[(size_t)(row0 + lr) * ND + k0 + lk]);
        const float4 b_v = *reinterpret_cast<const float4*>(&W[(size_t)(k0 + bk) * ND + col0 + bc]);
        *reinterpret_cast<float4*>(&As[lr][lk]) = a_v;
        *reinterpret_cast<float4*>(&Bs[bk][bc]) = b_v;
        __syncthreads();

        #pragma unroll
        for (int k = 0; k < 16; ++k) {
            float bv[4];
            #pragma unroll
            for (int j = 0; j < 4; ++j) bv[j] = Bs[k][tx*4 + j];
            #pragma unroll
            for (int i = 0; i < 4; ++i) {
                const float av = As[ty*4 + i][k];
                #pragma unroll
                for (int j = 0; j < 4; ++j)
                    acc[i][j] = fmaf(av, bv[j], acc[i][j]);
            }
        }
        __syncthreads();
    }

    #pragma unroll
    for (int i = 0; i < 4; ++i) {
        const size_t m = row0 + ty*4 + i;
        #pragma unroll
        for (int j = 0; j < 4; ++j) {
            const int n = col0 + tx*4 + j;
            Y[m * ND + n] = acc[i][j] + bias[n];
        }
    }
}

// ========= flash attention: scores = QrKr - QiKi (pre-scaled), real V =========
__global__ __launch_bounds__(256)
void attn_kernel(const float* __restrict__ Qg_r, const float* __restrict__ Qg_i,
                 const float* __restrict__ Kg_r, const float* __restrict__ Kg_i,
                 const float* __restrict__ Vg_r, float* __restrict__ Og_r)
{
    __shared__ float Qs_r[32][65];
    __shared__ float Qs_i[32][65];
    __shared__ float KVs_r[64][65];   // K real, then reused for V real
    __shared__ float Ks_i[64][65];    // K imag
    __shared__ float Ps[32][65];

    const int tid = threadIdx.x;
    const int tx = tid & 31;
    const int ty = tid >> 5;
    const int bh = blockIdx.y;            // b*NH + h
    const int q0 = blockIdx.x * 32;
    const size_t base = (size_t)bh * NS * NDK;

    {
        const int r = tid >> 4;
        const int c = (tid & 15) * 4;
        #pragma unroll
        for (int i = 0; i < 2; ++i) {
            const int rr = r + i*16;
            const float4 t = *reinterpret_cast<const float4*>(&Qg_r[base + (size_t)(q0 + rr)*NDK + c]);
            Qs_r[rr][c] = t.x; Qs_r[rr][c+1] = t.y; Qs_r[rr][c+2] = t.z; Qs_r[rr][c+3] = t.w;
            const float4 u = *reinterpret_cast<const float4*>(&Qg_i[base + (size_t)(q0 + rr)*NDK + c]);
            Qs_i[rr][c] = u.x; Qs_i[rr][c+1] = u.y; Qs_i[rr][c+2] = u.z; Qs_i[rr][c+3] = u.w;
        }
    }

    float mrow[4], lrow[4], o_r[4][2];
    #pragma unroll
    for (int i = 0; i < 4; ++i) {
        mrow[i] = -1e30f; lrow[i] = 0.f;
        o_r[i][0] = o_r[i][1] = 0.f;
    }
    __syncthreads();

    for (int kt = 0; kt < NS/64; ++kt) {
        const int k0 = kt * 64;
        // load K tile (both planes)
        {
            const int r = tid >> 4;
            const int c = (tid & 15) * 4;
            #pragma unroll
            for (int i = 0; i < 4; ++i) {
                const int rr = r + i*16;
                const float4 t = *reinterpret_cast<const float4*>(&Kg_r[base + (size_t)(k0 + rr)*NDK + c]);
                KVs_r[rr][c] = t.x; KVs_r[rr][c+1] = t.y; KVs_r[rr][c+2] = t.z; KVs_r[rr][c+3] = t.w;
                const float4 u = *reinterpret_cast<const float4*>(&Kg_i[base + (size_t)(k0 + rr)*NDK + c]);
                Ks_i[rr][c] = u.x; Ks_i[rr][c+1] = u.y; Ks_i[rr][c+2] = u.z; Ks_i[rr][c+3] = u.w;
            }
        }
        __syncthreads();

        // scores: sc[i][j] = sum_dk Qr*Kr - Qi*Ki
        float sc[4][2];
        #pragma unroll
        for (int i = 0; i < 4; ++i) { sc[i][0] = 0.f; sc[i][1] = 0.f; }
        #pragma unroll 4
        for (int dk = 0; dk < NDK; ++dk) {
            const float kr0 = KVs_r[tx*2  ][dk];
            const float kr1 = KVs_r[tx*2+1][dk];
            const float ki0 = Ks_i[tx*2  ][dk];
            const float ki1 = Ks_i[tx*2+1][dk];
            #pragma unroll
            for (int i = 0; i < 4; ++i) {
                const float qr = Qs_r[ty*4+i][dk];
                const float qi = Qs_i[ty*4+i][dk];
                sc[i][0] = fmaf(qr, kr0, sc[i][0]);
                sc[i][0] = fmaf(-qi, ki0, sc[i][0]);
                sc[i][1] = fmaf(qr, kr1, sc[i][1]);
                sc[i][1] = fmaf(-qi, ki1, sc[i][1]);
            }
        }
        __syncthreads();   // K reads done -> KVs_r reusable for V

        // V tile (real only) -> KVs_r
        {
            const int r = tid >> 4;
            const int c = (tid & 15) * 4;
            #pragma unroll
            for (int i = 0; i < 4; ++i) {
                const int rr = r + i*16;
                const float4 t = *reinterpret_cast<const float4*>(&Vg_r[base + (size_t)(k0 + rr)*NDK + c]);
                KVs_r[rr][c] = t.x; KVs_r[rr][c+1] = t.y; KVs_r[rr][c+2] = t.z; KVs_r[rr][c+3] = t.w;
            }
        }

        // online softmax (32-lane butterfly per row)
        #pragma unroll
        for (int i = 0; i < 4; ++i) {
            float tmax = fmaxf(sc[i][0], sc[i][1]);
            #pragma unroll
            for (int d = 1; d < 32; d <<= 1)
                tmax = fmaxf(tmax, __shfl_xor(tmax, d, 64));
            const float mnew = fmaxf(mrow[i], tmax);
            const float corr = __expf(mrow[i] - mnew);
            const float p0 = __expf(sc[i][0] - mnew);
            const float p1 = __expf(sc[i][1] - mnew);
            float psum = p0 + p1;
            #pragma unroll
            for (int d = 1; d < 32; d <<= 1)
                psum += __shfl_xor(psum, d, 64);
            lrow[i] = lrow[i] * corr + psum;
            mrow[i] = mnew;
            o_r[i][0] *= corr; o_r[i][1] *= corr;
            Ps[ty*4+i][tx*2]   = p0;
            Ps[ty*4+i][tx*2+1] = p1;
        }
        __syncthreads();   // V staged + P written

        // O += P @ V
        #pragma unroll 4
        for (int kk = 0; kk < 64; ++kk) {
            const float vr0 = KVs_r[kk][tx*2  ];
            const float vr1 = KVs_r[kk][tx*2+1];
            #pragma unroll
            for (int i = 0; i < 4; ++i) {
                const float pv = Ps[ty*4+i][kk];
                o_r[i][0] = fmaf(pv, vr0, o_r[i][0]);
                o_r[i][1] = fmaf(pv, vr1, o_r[i][1]);
            }
        }
        __syncthreads();
    }

    // epilogue -> (B*S, D) layout, real plane
    const int b = bh >> 4;
    const int h = bh & 15;
    #pragma unroll
    for (int i = 0; i < 4; ++i) {
        const int s = q0 + ty*4 + i;
        const float inv = 1.0f / lrow[i];
        #pragma unroll
        for (int j = 0; j < 2; ++j) {
            const int dk = tx*2 + j;
            Og_r[((size_t)(b*NS + s)) * ND + h*NDK + dk] = o_r[i][j] * inv;
        }
    }
}

extern "C" void kernel_launch(void* const* d_in, const int* in_sizes, int n_in,
                              void* d_out, int out_size, void* d_ws, size_t ws_size,
                              hipStream_t stream)
{
    const float* xr = (const float*)d_in[0];
    const float* xi = (const float*)d_in[1];
    const float* Wq = (const float*)d_in[2];
    const float* bq = (const float*)d_in[3];
    const float* Wk = (const float*)d_in[4];
    const float* bk = (const float*)d_in[5];
    const float* Wv = (const float*)d_in[6];
    const float* bv = (const float*)d_in[7];
    const float* Wo = (const float*)d_in[8];
    const float* bo = (const float*)d_in[9];
    float* out = (float*)d_out;

    float* ws = (float*)d_ws;
    const size_t NN = (size_t)NM * ND;      // 4,194,304 floats per plane
    float* Qr = ws + 0*NN; float* Qi = ws + 1*NN;
    float* Kr = ws + 2*NN; float* Ki = ws + 3*NN;
    float* Vr = ws + 4*NN;
    float* Or_ = ws + 5*NN;                 // 6 planes = 100.7 MB total

    const dim3 pgrid(ND/64, NM/64);         // (16, 64)

    gemm_qk<<<pgrid, 256, 0, stream>>>(xr, xi, Wq, bq, Qr, Qi, 0.125f);  // 1/sqrt(64)
    gemm_qk<<<pgrid, 256, 0, stream>>>(xr, xi, Wk, bk, Kr, Ki, 1.0f);
    gemm_v <<<pgrid, 256, 0, stream>>>(xr, Wv, bv, Vr);

    attn_kernel<<<dim3(NS/32, NB*NH), 256, 0, stream>>>(Qr, Qi, Kr, Ki, Vr, Or_);

    gemm_o <<<pgrid, 256, 0, stream>>>(Or_, Wo, bo, out);
}

// Round 4
// 874.752 us; speedup vs baseline: 2.4313x; 2.4313x over previous
//
#include <hip/hip_runtime.h>

#define NB 2
#define NS 2048
#define ND 1024
#define NH 16
#define NDK 64
#define NM (NB*NS)   // 4096

typedef short bf16x8 __attribute__((ext_vector_type(8)));
typedef float f32x4 __attribute__((ext_vector_type(4)));

__device__ __forceinline__ unsigned short f2bf(float f) {
    unsigned u = __builtin_bit_cast(unsigned, f);
    u += 0x7fffu + ((u >> 16) & 1u);         // round-to-nearest-even
    return (unsigned short)(u >> 16);
}

// ========= dual-plane projection (Q, K): Y{r,i} = (X{r,i} @ W + b) * scale =========
__global__ __launch_bounds__(256)
void gemm_qk(const float* __restrict__ Xr, const float* __restrict__ Xi,
             const float* __restrict__ W, const float* __restrict__ bias,
             float* __restrict__ Yr, float* __restrict__ Yi, const float scale)
{
    __shared__ float As_r[64][20];
    __shared__ float As_i[64][20];
    __shared__ float Bs[16][68];

    const int tid = threadIdx.x;
    const int tx = tid & 15;
    const int ty = tid >> 4;
    const int row0 = blockIdx.y * 64;
    const int col0 = blockIdx.x * 64;

    const int lr = tid >> 2;
    const int lk = (tid & 3) * 4;
    const int bk = tid >> 4;
    const int bc = (tid & 15) * 4;

    float accr[4][4] = {{0.f}};
    float acci[4][4] = {{0.f}};

    for (int k0 = 0; k0 < ND; k0 += 16) {
        const float4 a_r = *reinterpret_cast<const float4*>(&Xr[(size_t)(row0 + lr) * ND + k0 + lk]);
        const float4 a_i = *reinterpret_cast<const float4*>(&Xi[(size_t)(row0 + lr) * ND + k0 + lk]);
        const float4 b_v = *reinterpret_cast<const float4*>(&W [(size_t)(k0 + bk) * ND + col0 + bc]);
        *reinterpret_cast<float4*>(&As_r[lr][lk]) = a_r;
        *reinterpret_cast<float4*>(&As_i[lr][lk]) = a_i;
        *reinterpret_cast<float4*>(&Bs[bk][bc])   = b_v;
        __syncthreads();

        #pragma unroll
        for (int k = 0; k < 16; ++k) {
            float bv[4];
            #pragma unroll
            for (int j = 0; j < 4; ++j) bv[j] = Bs[k][tx*4 + j];
            #pragma unroll
            for (int i = 0; i < 4; ++i) {
                const float ar = As_r[ty*4 + i][k];
                const float ai = As_i[ty*4 + i][k];
                #pragma unroll
                for (int j = 0; j < 4; ++j) {
                    accr[i][j] = fmaf(ar, bv[j], accr[i][j]);
                    acci[i][j] = fmaf(ai, bv[j], acci[i][j]);
                }
            }
        }
        __syncthreads();
    }

    #pragma unroll
    for (int i = 0; i < 4; ++i) {
        const int m = row0 + ty*4 + i;
        const int b = m >> 11;
        const int s = m & (NS - 1);
        #pragma unroll
        for (int j = 0; j < 4; ++j) {
            const int n  = col0 + tx*4 + j;
            const int h  = n >> 6;
            const int dk = n & 63;
            const size_t idx = (((size_t)(b*NH + h) * NS) + s) * NDK + dk;
            Yr[idx] = (accr[i][j] + bias[n]) * scale;
            Yi[idx] = acci[i][j] * scale;
        }
    }
}

// ========= single-plane projection (V real part): Yr = Xr @ W + b =========
__global__ __launch_bounds__(256)
void gemm_v(const float* __restrict__ Xr, const float* __restrict__ W,
            const float* __restrict__ bias, float* __restrict__ Yr)
{
    __shared__ float As[64][20];
    __shared__ float Bs[16][68];

    const int tid = threadIdx.x;
    const int tx = tid & 15;
    const int ty = tid >> 4;
    const int row0 = blockIdx.y * 64;
    const int col0 = blockIdx.x * 64;

    const int lr = tid >> 2;
    const int lk = (tid & 3) * 4;
    const int bk = tid >> 4;
    const int bc = (tid & 15) * 4;

    float acc[4][4] = {{0.f}};

    for (int k0 = 0; k0 < ND; k0 += 16) {
        const float4 a_v = *reinterpret_cast<const float4*>(&Xr[(size_t)(row0 + lr) * ND + k0 + lk]);
        const float4 b_v = *reinterpret_cast<const float4*>(&W [(size_t)(k0 + bk) * ND + col0 + bc]);
        *reinterpret_cast<float4*>(&As[lr][lk]) = a_v;
        *reinterpret_cast<float4*>(&Bs[bk][bc]) = b_v;
        __syncthreads();

        #pragma unroll
        for (int k = 0; k < 16; ++k) {
            float bv[4];
            #pragma unroll
            for (int j = 0; j < 4; ++j) bv[j] = Bs[k][tx*4 + j];
            #pragma unroll
            for (int i = 0; i < 4; ++i) {
                const float av = As[ty*4 + i][k];
                #pragma unroll
                for (int j = 0; j < 4; ++j)
                    acc[i][j] = fmaf(av, bv[j], acc[i][j]);
            }
        }
        __syncthreads();
    }

    #pragma unroll
    for (int i = 0; i < 4; ++i) {
        const int m = row0 + ty*4 + i;
        const int b = m >> 11;
        const int s = m & (NS - 1);
        #pragma unroll
        for (int j = 0; j < 4; ++j) {
            const int n  = col0 + tx*4 + j;
            const int h  = n >> 6;
            const int dk = n & 63;
            const size_t idx = (((size_t)(b*NH + h) * NS) + s) * NDK + dk;
            Yr[idx] = acc[i][j] + bias[n];
        }
    }
}

// ========= final projection: out = X @ Wo + bo (all real) =========
__global__ __launch_bounds__(256)
void gemm_o(const float* __restrict__ X, const float* __restrict__ W,
            const float* __restrict__ bias, float* __restrict__ Y)
{
    __shared__ float As[64][20];
    __shared__ float Bs[16][68];

    const int tid = threadIdx.x;
    const int tx = tid & 15;
    const int ty = tid >> 4;
    const int row0 = blockIdx.y * 64;
    const int col0 = blockIdx.x * 64;

    const int lr = tid >> 2;
    const int lk = (tid & 3) * 4;
    const int bk = tid >> 4;
    const int bc = (tid & 15) * 4;

    float acc[4][4] = {{0.f}};

    for (int k0 = 0; k0 < ND; k0 += 16) {
        const float4 a_v = *reinterpret_cast<const float4*>(&X[(size_t)(row0 + lr) * ND + k0 + lk]);
        const float4 b_v = *reinterpret_cast<const float4*>(&W[(size_t)(k0 + bk) * ND + col0 + bc]);
        *reinterpret_cast<float4*>(&As[lr][lk]) = a_v;
        *reinterpret_cast<float4*>(&Bs[bk][bc]) = b_v;
        __syncthreads();

        #pragma unroll
        for (int k = 0; k < 16; ++k) {
            float bv[4];
            #pragma unroll
            for (int j = 0; j < 4; ++j) bv[j] = Bs[k][tx*4 + j];
            #pragma unroll
            for (int i = 0; i < 4; ++i) {
                const float av = As[ty*4 + i][k];
                #pragma unroll
                for (int j = 0; j < 4; ++j)
                    acc[i][j] = fmaf(av, bv[j], acc[i][j]);
            }
        }
        __syncthreads();
    }

    #pragma unroll
    for (int i = 0; i < 4; ++i) {
        const size_t m = row0 + ty*4 + i;
        #pragma unroll
        for (int j = 0; j < 4; ++j) {
            const int n = col0 + tx*4 + j;
            Y[m * ND + n] = acc[i][j] + bias[n];
        }
    }
}

// ========= MFMA flash attention =========
// S = [Qr | -Qi] (16x128 per wave) @ [Kr | Ki]^T via mfma_f32_16x16x32_bf16,
// online softmax in registers, O += P @ V with V staged transposed in LDS.
// Fragment layouts (m97-lineage): A: row=lane&15, k=8*(lane>>4)+b (contiguous);
// B: k=8*(lane>>4)+b, col=lane&15; D: row=(lane>>4)*4+j, col=lane&15.
#define LDK 136   // K' row length in bf16 (128 + 8 pad) -> 2-way banks on b128
#define LDV 72    // V^T row length (64 + 8 pad)
#define LDP 72    // P row length

__global__ __launch_bounds__(256)
void attn_mfma(const float* __restrict__ Qgr, const float* __restrict__ Qgi,
               const float* __restrict__ Kgr, const float* __restrict__ Kgi,
               const float* __restrict__ Vgr, float* __restrict__ Og)
{
    __shared__ __align__(16) unsigned short Ks[64 * LDK];    // [kv][ Kr | Ki ]
    __shared__ __align__(16) unsigned short Vs[64 * LDV];    // [dk][kv] (transposed)
    __shared__ __align__(16) unsigned short Ps[4][16 * LDP]; // per-wave P

    const int tid  = threadIdx.x;
    const int wave = tid >> 6;
    const int lane = tid & 63;
    const int g = lane >> 4;     // fragment k-group
    const int c = lane & 15;     // fragment row/col

    const int bh = blockIdx.y;               // b*NH + h
    const int q0 = blockIdx.x * 64;
    const size_t base = (size_t)bh * NS * NDK;

    // ---- Q' fragments: A[row=c][k], K=128 = [Qr | -Qi], loaded once ----
    bf16x8 qa[4];
    {
        const float* qr = Qgr + base + (size_t)(q0 + wave*16 + c) * NDK;
        const float* qi = Qgi + base + (size_t)(q0 + wave*16 + c) * NDK;
        #pragma unroll
        for (int s = 0; s < 2; ++s) {
            const float4 a = *(const float4*)(qr + 32*s + 8*g);
            const float4 b = *(const float4*)(qr + 32*s + 8*g + 4);
            bf16x8 f;
            f[0]=f2bf(a.x); f[1]=f2bf(a.y); f[2]=f2bf(a.z); f[3]=f2bf(a.w);
            f[4]=f2bf(b.x); f[5]=f2bf(b.y); f[6]=f2bf(b.z); f[7]=f2bf(b.w);
            qa[s] = f;
            const float4 ai = *(const float4*)(qi + 32*s + 8*g);
            const float4 bi = *(const float4*)(qi + 32*s + 8*g + 4);
            bf16x8 fi;
            fi[0]=f2bf(-ai.x); fi[1]=f2bf(-ai.y); fi[2]=f2bf(-ai.z); fi[3]=f2bf(-ai.w);
            fi[4]=f2bf(-bi.x); fi[5]=f2bf(-bi.y); fi[6]=f2bf(-bi.z); fi[7]=f2bf(-bi.w);
            qa[2+s] = fi;
        }
    }

    f32x4 oacc[4];
    float mrun[4], lrun[4];
    #pragma unroll
    for (int j = 0; j < 4; ++j) {
        oacc[j] = (f32x4){0.f, 0.f, 0.f, 0.f};
        mrun[j] = -1e30f;
        lrun[j] = 0.f;
    }

    for (int kt = 0; kt < NS/64; ++kt) {
        const int k0 = kt * 64;

        // ---- stage K' = [Kr | Ki] row-major bf16 ----
        {
            const int r  = tid >> 2;
            const int q4 = (tid & 3) * 16;
            const float* kr = Kgr + base + (size_t)(k0 + r) * NDK + q4;
            const float* ki = Kgi + base + (size_t)(k0 + r) * NDK + q4;
            #pragma unroll
            for (int i = 0; i < 4; ++i) {
                const float4 v = *(const float4*)(kr + 4*i);
                ushort4 h;
                h.x = f2bf(v.x); h.y = f2bf(v.y); h.z = f2bf(v.z); h.w = f2bf(v.w);
                *(ushort4*)&Ks[r*LDK + q4 + 4*i] = h;
            }
            #pragma unroll
            for (int i = 0; i < 4; ++i) {
                const float4 v = *(const float4*)(ki + 4*i);
                ushort4 h;
                h.x = f2bf(v.x); h.y = f2bf(v.y); h.z = f2bf(v.z); h.w = f2bf(v.w);
                *(ushort4*)&Ks[r*LDK + 64 + q4 + 4*i] = h;
            }
            // ---- stage V transposed: Vs[dk][kv], kv-pairs packed as u32 ----
            const int a2 = tid >> 3;          // kv pair index 0..31
            const int b8 = (tid & 7) * 8;     // dk col start
            const float* v0 = Vgr + base + (size_t)(k0 + 2*a2) * NDK + b8;
            const float* v1 = v0 + NDK;
            const float4 x0 = *(const float4*)(v0);
            const float4 x1 = *(const float4*)(v0 + 4);
            const float4 y0 = *(const float4*)(v1);
            const float4 y1 = *(const float4*)(v1 + 4);
            const float xs[8] = {x0.x,x0.y,x0.z,x0.w,x1.x,x1.y,x1.z,x1.w};
            const float ys[8] = {y0.x,y0.y,y0.z,y0.w,y1.x,y1.y,y1.z,y1.w};
            #pragma unroll
            for (int j = 0; j < 8; ++j) {
                const unsigned pk = (unsigned)f2bf(xs[j]) | ((unsigned)f2bf(ys[j]) << 16);
                *(unsigned*)&Vs[(b8 + j)*LDV + 2*a2] = pk;
            }
        }
        __syncthreads();

        // ---- QK^T: per wave S[16][64], 16 MFMAs over K=128 ----
        f32x4 sacc[4];
        #pragma unroll
        for (int nt = 0; nt < 4; ++nt) sacc[nt] = (f32x4){0.f, 0.f, 0.f, 0.f};
        #pragma unroll
        for (int s = 0; s < 4; ++s) {
            #pragma unroll
            for (int nt = 0; nt < 4; ++nt) {
                const bf16x8 kb = *(const bf16x8*)&Ks[(nt*16 + c)*LDK + 32*s + 8*g];
                sacc[nt] = __builtin_amdgcn_mfma_f32_16x16x32_bf16(qa[s], kb, sacc[nt], 0, 0, 0);
            }
        }

        // ---- online softmax (rows = 4*g + j, shared by the 16 lanes of group g) ----
        float corr[4], psum[4];
        #pragma unroll
        for (int j = 0; j < 4; ++j) {
            float mx = fmaxf(fmaxf(sacc[0][j], sacc[1][j]), fmaxf(sacc[2][j], sacc[3][j]));
            #pragma unroll
            for (int m = 1; m < 16; m <<= 1) mx = fmaxf(mx, __shfl_xor(mx, m, 64));
            const float mnew = fmaxf(mrun[j], mx);
            corr[j] = __expf(mrun[j] - mnew);
            mrun[j] = mnew;
            psum[j] = 0.f;
        }
        #pragma unroll
        for (int nt = 0; nt < 4; ++nt) {
            #pragma unroll
            for (int j = 0; j < 4; ++j) {
                const float p = __expf(sacc[nt][j] - mrun[j]);
                psum[j] += p;
                Ps[wave][(4*g + j)*LDP + nt*16 + c] = f2bf(p);
            }
        }
        #pragma unroll
        for (int j = 0; j < 4; ++j) {
            float ps = psum[j];
            #pragma unroll
            for (int m = 1; m < 16; m <<= 1) ps += __shfl_xor(ps, m, 64);
            lrun[j] = lrun[j] * corr[j] + ps;
        }
        #pragma unroll
        for (int nt = 0; nt < 4; ++nt) {
            #pragma unroll
            for (int j = 0; j < 4; ++j) oacc[nt][j] *= corr[j];
        }

        // ---- PV: O += P @ V (A from Ps, B from transposed Vs) ----
        #pragma unroll
        for (int s = 0; s < 2; ++s) {
            const bf16x8 pa = *(const bf16x8*)&Ps[wave][c*LDP + 32*s + 8*g];
            #pragma unroll
            for (int nt = 0; nt < 4; ++nt) {
                const bf16x8 vb = *(const bf16x8*)&Vs[(nt*16 + c)*LDV + 32*s + 8*g];
                oacc[nt] = __builtin_amdgcn_mfma_f32_16x16x32_bf16(pa, vb, oacc[nt], 0, 0, 0);
            }
        }
        __syncthreads();
    }

    // ---- epilogue: O/l -> (B*S, D) real plane ----
    const int b = bh >> 4;
    const int h = bh & 15;
    #pragma unroll
    for (int j = 0; j < 4; ++j) {
        const float inv = 1.0f / lrun[j];
        const int srow = q0 + wave*16 + 4*g + j;
        #pragma unroll
        for (int nt = 0; nt < 4; ++nt)
            Og[(size_t)(b*NS + srow)*ND + h*NDK + nt*16 + c] = oacc[nt][j] * inv;
    }
}

extern "C" void kernel_launch(void* const* d_in, const int* in_sizes, int n_in,
                              void* d_out, int out_size, void* d_ws, size_t ws_size,
                              hipStream_t stream)
{
    const float* xr = (const float*)d_in[0];
    const float* xi = (const float*)d_in[1];
    const float* Wq = (const float*)d_in[2];
    const float* bq = (const float*)d_in[3];
    const float* Wk = (const float*)d_in[4];
    const float* bk = (const float*)d_in[5];
    const float* Wv = (const float*)d_in[6];
    const float* bv = (const float*)d_in[7];
    const float* Wo = (const float*)d_in[8];
    const float* bo = (const float*)d_in[9];
    float* out = (float*)d_out;

    float* ws = (float*)d_ws;
    const size_t NN = (size_t)NM * ND;
    float* Qr = ws + 0*NN; float* Qi = ws + 1*NN;
    float* Kr = ws + 2*NN; float* Ki = ws + 3*NN;
    float* Vr = ws + 4*NN;
    float* Or_ = ws + 5*NN;

    const dim3 pgrid(ND/64, NM/64);

    gemm_qk<<<pgrid, 256, 0, stream>>>(xr, xi, Wq, bq, Qr, Qi, 0.125f);
    gemm_qk<<<pgrid, 256, 0, stream>>>(xr, xi, Wk, bk, Kr, Ki, 1.0f);
    gemm_v <<<pgrid, 256, 0, stream>>>(xr, Wv, bv, Vr);

    attn_mfma<<<dim3(NS/64, NB*NH), 256, 0, stream>>>(Qr, Qi, Kr, Ki, Vr, Or_);

    gemm_o <<<pgrid, 256, 0, stream>>>(Or_, Wo, bo, out);
}

// Round 5
// 488.108 us; speedup vs baseline: 4.3572x; 1.7921x over previous
//
#include <hip/hip_runtime.h>

#define NB 2
#define NS 2048
#define ND 1024
#define NH 16
#define NDK 64
#define NM (NB*NS)   // 4096

typedef unsigned short u16;
typedef short bf16x8 __attribute__((ext_vector_type(8)));
typedef float f32x4 __attribute__((ext_vector_type(4)));

__device__ __forceinline__ u16 f2bf(float f) {
    unsigned u = __builtin_bit_cast(unsigned, f);
    u += 0x7fffu + ((u >> 16) & 1u);         // RTNE
    return (u16)(u >> 16);
}
__device__ __forceinline__ float bf2f(u16 h) {
    return __builtin_bit_cast(float, (unsigned)h << 16);
}

// ============ conv_x: xr,xi fp32 -> stacked hi/lo bf16 planes [xr; xi] ============
__global__ __launch_bounds__(256)
void conv_x(const float* __restrict__ xr, const float* __restrict__ xi,
            u16* __restrict__ XH, u16* __restrict__ XL)
{
    const size_t gid = (size_t)blockIdx.x * 256 + threadIdx.x;
    const size_t PQ = (size_t)NM * ND / 4;           // float4 count per plane
    const int p = gid >= PQ;
    const size_t off = (gid - (p ? PQ : 0)) * 4;
    const float4 v = *(const float4*)&((p ? xi : xr)[off]);
    const size_t d = (size_t)p * NM * ND + off;
    float vs[4] = {v.x, v.y, v.z, v.w};
    ushort4 h, l;
    u16* hp = (u16*)&h; u16* lp = (u16*)&l;
    #pragma unroll
    for (int j = 0; j < 4; ++j) {
        hp[j] = f2bf(vs[j]);
        lp[j] = f2bf(vs[j] - bf2f(hp[j]));
    }
    *(ushort4*)&XH[d] = h;
    *(ushort4*)&XL[d] = l;
}

// ============ conv_wt: W (K x N fp32) -> W^T hi/lo bf16 (N x K) ============
__global__ __launch_bounds__(256)
void conv_wt(const float* __restrict__ W0, const float* __restrict__ W1,
             const float* __restrict__ W2, const float* __restrict__ W3,
             u16* __restrict__ WT)   // per weight: hi (1M us), then lo (1M us)
{
    __shared__ float tls[64][68];
    const int z = blockIdx.z;
    const float* W = z == 0 ? W0 : z == 1 ? W1 : z == 2 ? W2 : W3;
    u16* dh = WT + (size_t)z * 2097152;
    u16* dl = dh + 1048576;
    const int kt0 = blockIdx.y * 64;
    const int nt0 = blockIdx.x * 64;
    const int tid = threadIdx.x;

    // read 64x64 tile coalesced
    {
        const int kk = tid >> 4;
        const int nn = (tid & 15) * 4;
        #pragma unroll
        for (int i = 0; i < 4; ++i) {
            const float4 v = *(const float4*)&W[(size_t)(kt0 + kk + 16*i) * ND + nt0 + nn];
            tls[kk + 16*i][nn] = v.x; tls[kk + 16*i][nn+1] = v.y;
            tls[kk + 16*i][nn+2] = v.z; tls[kk + 16*i][nn+3] = v.w;
        }
    }
    __syncthreads();

    // write transposed rows, split hi/lo
    const int n  = tid >> 2;
    const int kc = (tid & 3) * 16;
    u16 hb[16], lb[16];
    #pragma unroll
    for (int k = 0; k < 16; ++k) {
        const float v = tls[kc + k][n];
        hb[k] = f2bf(v);
        lb[k] = f2bf(v - bf2f(hb[k]));
    }
    #pragma unroll
    for (int half = 0; half < 2; ++half) {
        *(bf16x8*)&dh[(size_t)(nt0 + n) * ND + kt0 + kc + 8*half] = *(bf16x8*)&hb[8*half];
        *(bf16x8*)&dl[(size_t)(nt0 + n) * ND + kt0 + kc + 8*half] = *(bf16x8*)&lb[8*half];
    }
}

// ============ split-precision bf16 MFMA GEMM ============
// C = (Ah+Al) @ (Bh+Bl)^T-compensated: Ah@Bh + Ah@Bl + Al@Bh, fp32 accum.
// A planes: M x 1024 bf16 row-major. B planes: W^T, [n][k] 1024x1024 bf16.
// mode 0: scatter bf16 to (B,NH,S,DK) planes Yr (m<4096) / Yi, bias on real, *scale.
// mode 1: Yf[m][n] = acc + bias[n] (fp32).
#define GLD 72   // LDS row length (bf16): 64 + 8 pad -> 2-way banks on b128

__global__ __launch_bounds__(256)
void gemm_split(const u16* __restrict__ Ah, const u16* __restrict__ Al,
                const u16* __restrict__ Bh, const u16* __restrict__ Bl,
                const float* __restrict__ bias,
                u16* __restrict__ Yr, u16* __restrict__ Yi,
                float* __restrict__ Yf, const int mode, const float scale)
{
    __shared__ u16 As[128 * GLD];
    __shared__ u16 Bs[128 * GLD];

    const int tid  = threadIdx.x;
    const int wave = tid >> 6;
    const int lane = tid & 63;
    const int g = lane >> 4;
    const int c = lane & 15;
    const int wm = wave >> 1;
    const int wn = wave & 1;
    const int row0 = blockIdx.y * 128;
    const int col0 = blockIdx.x * 128;

    const int sr  = tid >> 1;        // staging row 0..127
    const int seg = tid & 1;         // 0 hi, 1 lo

    f32x4 acc[4][4];
    #pragma unroll
    for (int i = 0; i < 4; ++i)
        #pragma unroll
        for (int j = 0; j < 4; ++j)
            acc[i][j] = (f32x4){0.f, 0.f, 0.f, 0.f};

    const u16* Apl = seg ? Al : Ah;
    const u16* Bpl = seg ? Bl : Bh;

    for (int k0 = 0; k0 < ND; k0 += 32) {
        const u16* Ap = Apl + (size_t)(row0 + sr) * ND + k0;
        const u16* Bp = Bpl + (size_t)(col0 + sr) * ND + k0;
        #pragma unroll
        for (int i = 0; i < 4; ++i) {
            *(bf16x8*)&As[sr*GLD + seg*32 + 8*i] = *(const bf16x8*)(Ap + 8*i);
            *(bf16x8*)&Bs[sr*GLD + seg*32 + 8*i] = *(const bf16x8*)(Bp + 8*i);
        }
        __syncthreads();

        bf16x8 a_h[4], a_l[4], b_h[4], b_l[4];
        #pragma unroll
        for (int f = 0; f < 4; ++f) {
            a_h[f] = *(const bf16x8*)&As[(wm*64 + f*16 + c)*GLD + 8*g];
            a_l[f] = *(const bf16x8*)&As[(wm*64 + f*16 + c)*GLD + 32 + 8*g];
            b_h[f] = *(const bf16x8*)&Bs[(wn*64 + f*16 + c)*GLD + 8*g];
            b_l[f] = *(const bf16x8*)&Bs[(wn*64 + f*16 + c)*GLD + 32 + 8*g];
        }
        #pragma unroll
        for (int fm = 0; fm < 4; ++fm) {
            #pragma unroll
            for (int fn = 0; fn < 4; ++fn) {
                acc[fm][fn] = __builtin_amdgcn_mfma_f32_16x16x32_bf16(a_h[fm], b_h[fn], acc[fm][fn], 0, 0, 0);
                acc[fm][fn] = __builtin_amdgcn_mfma_f32_16x16x32_bf16(a_h[fm], b_l[fn], acc[fm][fn], 0, 0, 0);
                acc[fm][fn] = __builtin_amdgcn_mfma_f32_16x16x32_bf16(a_l[fm], b_h[fn], acc[fm][fn], 0, 0, 0);
            }
        }
        __syncthreads();
    }

    // epilogue (D: row = 4g + j, col = c within each 16x16 frag)
    #pragma unroll
    for (int fm = 0; fm < 4; ++fm) {
        #pragma unroll
        for (int fn = 0; fn < 4; ++fn) {
            #pragma unroll
            for (int j = 0; j < 4; ++j) {
                const int m = row0 + wm*64 + fm*16 + 4*g + j;
                const int n = col0 + wn*64 + fn*16 + c;
                const float v = acc[fm][fn][j];
                if (mode == 0) {
                    const int plane = m >> 12;
                    const int mm = m & 4095;
                    const int b  = mm >> 11;
                    const int s  = mm & (NS - 1);
                    const int hh = n >> 6;
                    const int dk = n & 63;
                    const float val = v*scale + (plane == 0 ? bias[n]*scale : 0.f);
                    (plane ? Yi : Yr)[(((size_t)(b*NH + hh) * NS) + s) * NDK + dk] = f2bf(val);
                } else {
                    Yf[(size_t)m * ND + n] = v + bias[n];
                }
            }
        }
    }
}

// ============ MFMA flash attention (bf16 planes in, hi/lo bf16 O out) ============
#define LDK 136
#define LDV 72
#define LDP 72

__global__ __launch_bounds__(256)
void attn_mfma(const u16* __restrict__ Qr, const u16* __restrict__ Qi,
               const u16* __restrict__ Kr, const u16* __restrict__ Ki,
               const u16* __restrict__ Vv,
               u16* __restrict__ OH, u16* __restrict__ OL)
{
    __shared__ __align__(16) u16 Ks[64 * LDK];    // [kv][ Kr | Ki ]
    __shared__ __align__(16) u16 Vs[64 * LDV];    // [dk][kv]
    __shared__ __align__(16) u16 Ps[4][16 * LDP];

    const int tid  = threadIdx.x;
    const int wave = tid >> 6;
    const int lane = tid & 63;
    const int g = lane >> 4;
    const int c = lane & 15;

    const int bh = blockIdx.y;
    const int q0 = blockIdx.x * 64;
    const size_t base = (size_t)bh * NS * NDK;

    // Q fragments: [Qr | -Qi], K=128
    bf16x8 qa[4];
    {
        const u16* qr = Qr + base + (size_t)(q0 + wave*16 + c) * NDK;
        const u16* qi = Qi + base + (size_t)(q0 + wave*16 + c) * NDK;
        #pragma unroll
        for (int s = 0; s < 2; ++s) {
            qa[s] = *(const bf16x8*)(qr + 32*s + 8*g);
            const bf16x8 t = *(const bf16x8*)(qi + 32*s + 8*g);
            bf16x8 f;
            #pragma unroll
            for (int j = 0; j < 8; ++j) f[j] = t[j] ^ (short)0x8000;  // negate
            qa[2+s] = f;
        }
    }

    f32x4 oacc[4];
    float mrun[4], lrun[4];
    #pragma unroll
    for (int j = 0; j < 4; ++j) {
        oacc[j] = (f32x4){0.f, 0.f, 0.f, 0.f};
        mrun[j] = -1e30f;
        lrun[j] = 0.f;
    }

    for (int kt = 0; kt < NS/64; ++kt) {
        const int k0 = kt * 64;
        // stage K' = [Kr | Ki]
        {
            const int r = tid >> 2;
            const int q = (tid & 3) * 16;
            const u16* kr = Kr + base + (size_t)(k0 + r) * NDK + q;
            const u16* ki = Ki + base + (size_t)(k0 + r) * NDK + q;
            *(bf16x8*)&Ks[r*LDK + q]          = *(const bf16x8*)(kr);
            *(bf16x8*)&Ks[r*LDK + q + 8]      = *(const bf16x8*)(kr + 8);
            *(bf16x8*)&Ks[r*LDK + 64 + q]     = *(const bf16x8*)(ki);
            *(bf16x8*)&Ks[r*LDK + 64 + q + 8] = *(const bf16x8*)(ki + 8);
            // stage V transposed, kv-pairs packed
            const int a2 = tid >> 3;
            const int b8 = (tid & 7) * 8;
            const u16* v0 = Vv + base + (size_t)(k0 + 2*a2) * NDK + b8;
            const bf16x8 x = *(const bf16x8*)(v0);
            const bf16x8 y = *(const bf16x8*)(v0 + NDK);
            #pragma unroll
            for (int j = 0; j < 8; ++j) {
                const unsigned pk = (unsigned)(u16)x[j] | ((unsigned)(u16)y[j] << 16);
                *(unsigned*)&Vs[(b8 + j)*LDV + 2*a2] = pk;
            }
        }
        __syncthreads();

        // QK^T
        f32x4 sacc[4];
        #pragma unroll
        for (int nt = 0; nt < 4; ++nt) sacc[nt] = (f32x4){0.f, 0.f, 0.f, 0.f};
        #pragma unroll
        for (int s = 0; s < 4; ++s) {
            #pragma unroll
            for (int nt = 0; nt < 4; ++nt) {
                const bf16x8 kb = *(const bf16x8*)&Ks[(nt*16 + c)*LDK + 32*s + 8*g];
                sacc[nt] = __builtin_amdgcn_mfma_f32_16x16x32_bf16(qa[s], kb, sacc[nt], 0, 0, 0);
            }
        }

        // online softmax
        float corr[4], psum[4];
        #pragma unroll
        for (int j = 0; j < 4; ++j) {
            float mx = fmaxf(fmaxf(sacc[0][j], sacc[1][j]), fmaxf(sacc[2][j], sacc[3][j]));
            #pragma unroll
            for (int m = 1; m < 16; m <<= 1) mx = fmaxf(mx, __shfl_xor(mx, m, 64));
            const float mnew = fmaxf(mrun[j], mx);
            corr[j] = __expf(mrun[j] - mnew);
            mrun[j] = mnew;
            psum[j] = 0.f;
        }
        #pragma unroll
        for (int nt = 0; nt < 4; ++nt) {
            #pragma unroll
            for (int j = 0; j < 4; ++j) {
                const float p = __expf(sacc[nt][j] - mrun[j]);
                psum[j] += p;
                Ps[wave][(4*g + j)*LDP + nt*16 + c] = f2bf(p);
            }
        }
        #pragma unroll
        for (int j = 0; j < 4; ++j) {
            float ps = psum[j];
            #pragma unroll
            for (int m = 1; m < 16; m <<= 1) ps += __shfl_xor(ps, m, 64);
            lrun[j] = lrun[j] * corr[j] + ps;
        }
        #pragma unroll
        for (int nt = 0; nt < 4; ++nt) {
            #pragma unroll
            for (int j = 0; j < 4; ++j) oacc[nt][j] *= corr[j];
        }

        // PV
        #pragma unroll
        for (int s = 0; s < 2; ++s) {
            const bf16x8 pa = *(const bf16x8*)&Ps[wave][c*LDP + 32*s + 8*g];
            #pragma unroll
            for (int nt = 0; nt < 4; ++nt) {
                const bf16x8 vb = *(const bf16x8*)&Vs[(nt*16 + c)*LDV + 32*s + 8*g];
                oacc[nt] = __builtin_amdgcn_mfma_f32_16x16x32_bf16(pa, vb, oacc[nt], 0, 0, 0);
            }
        }
        __syncthreads();
    }

    // epilogue: hi/lo split of O/l into (B*S, D) planes
    const int b  = bh >> 4;
    const int hh = bh & 15;
    #pragma unroll
    for (int j = 0; j < 4; ++j) {
        const float inv = 1.0f / lrun[j];
        const int srow = q0 + wave*16 + 4*g + j;
        #pragma unroll
        for (int nt = 0; nt < 4; ++nt) {
            const float val = oacc[nt][j] * inv;
            const u16 hb = f2bf(val);
            const u16 lb = f2bf(val - bf2f(hb));
            const size_t o = (size_t)(b*NS + srow)*ND + hh*NDK + nt*16 + c;
            OH[o] = hb;
            OL[o] = lb;
        }
    }
}

extern "C" void kernel_launch(void* const* d_in, const int* in_sizes, int n_in,
                              void* d_out, int out_size, void* d_ws, size_t ws_size,
                              hipStream_t stream)
{
    const float* xr = (const float*)d_in[0];
    const float* xi = (const float*)d_in[1];
    const float* Wq = (const float*)d_in[2];
    const float* bq = (const float*)d_in[3];
    const float* Wk = (const float*)d_in[4];
    const float* bk = (const float*)d_in[5];
    const float* Wv = (const float*)d_in[6];
    const float* bv = (const float*)d_in[7];
    const float* Wo = (const float*)d_in[8];
    const float* bo = (const float*)d_in[9];
    float* out = (float*)d_out;

    u16* ws = (u16*)d_ws;
    const size_t PL = (size_t)NM * ND;          // 4,194,304 elems per plane
    u16* XH = ws;                                // stacked [xr_hi; xi_hi], 2*PL
    u16* XL = ws + 2*PL;                         // stacked lo
    u16* WT = ws + 4*PL;                         // 4 weights x (hi 1M + lo 1M)
    u16* QP = WT + 8 * 1048576;
    u16* Qr = QP;          u16* Qi = QP + PL;
    u16* Kr = QP + 2*PL;   u16* Ki = QP + 3*PL;
    u16* Vv = QP + 4*PL;
    u16* OH = ws;                                // alias dead x_hi region
    u16* OL = ws + PL;

    conv_x<<<2*PL/(256*4), 256, 0, stream>>>(xr, xi, XH, XL);
    conv_wt<<<dim3(ND/64, ND/64, 4), 256, 0, stream>>>(Wq, Wk, Wv, Wo, WT);

    u16* WTq = WT;  u16* WTk = WT + 2097152;  u16* WTv = WT + 2*2097152;  u16* WTo = WT + 3*2097152;

    gemm_split<<<dim3(ND/128, 2*NM/128), 256, 0, stream>>>(XH, XL, WTq, WTq + 1048576, bq, Qr, Qi, nullptr, 0, 0.125f);
    gemm_split<<<dim3(ND/128, 2*NM/128), 256, 0, stream>>>(XH, XL, WTk, WTk + 1048576, bk, Kr, Ki, nullptr, 0, 1.0f);
    gemm_split<<<dim3(ND/128,   NM/128), 256, 0, stream>>>(XH, XL, WTv, WTv + 1048576, bv, Vv, Vv, nullptr, 0, 1.0f);

    attn_mfma<<<dim3(NS/64, NB*NH), 256, 0, stream>>>(Qr, Qi, Kr, Ki, Vv, OH, OL);

    gemm_split<<<dim3(ND/128,   NM/128), 256, 0, stream>>>(OH, OL, WTo, WTo + 1048576, bo, nullptr, nullptr, out, 1, 1.0f);
}

// Round 7
// 375.487 us; speedup vs baseline: 5.6641x; 1.2999x over previous
//
#include <hip/hip_runtime.h>

#define NB 2
#define NS 2048
#define ND 1024
#define NH 16
#define NDK 64
#define NM (NB*NS)   // 4096

typedef unsigned short u16;
typedef short bf16x8 __attribute__((ext_vector_type(8)));
typedef float f32x4 __attribute__((ext_vector_type(4)));
typedef const __attribute__((address_space(1))) void* gas_p;
typedef __attribute__((address_space(3))) void* las_p;

#define LOG2E 1.4426950408889634f

__device__ __forceinline__ u16 f2bf(float f) {
    unsigned u = __builtin_bit_cast(unsigned, f);
    u += 0x7fffu + ((u >> 16) & 1u);         // RTNE
    return (u16)(u >> 16);
}
__device__ __forceinline__ float bf2f(u16 h) {
    return __builtin_bit_cast(float, (unsigned)h << 16);
}

// ============ conv_x: xr,xi fp32 -> stacked hi/lo bf16 planes [xr; xi] ============
__global__ __launch_bounds__(256)
void conv_x(const float* __restrict__ xr, const float* __restrict__ xi,
            u16* __restrict__ XH, u16* __restrict__ XL)
{
    const size_t gid = (size_t)blockIdx.x * 256 + threadIdx.x;
    const size_t PQ = (size_t)NM * ND / 4;
    const int p = gid >= PQ;
    const size_t off = (gid - (p ? PQ : 0)) * 4;
    const float4 v = *(const float4*)&((p ? xi : xr)[off]);
    const size_t d = (size_t)p * NM * ND + off;
    float vs[4] = {v.x, v.y, v.z, v.w};
    ushort4 h, l;
    u16* hp = (u16*)&h; u16* lp = (u16*)&l;
    #pragma unroll
    for (int j = 0; j < 4; ++j) {
        hp[j] = f2bf(vs[j]);
        lp[j] = f2bf(vs[j] - bf2f(hp[j]));
    }
    *(ushort4*)&XH[d] = h;
    *(ushort4*)&XL[d] = l;
}

// ============ conv_wt: W (K x N fp32) -> W^T hi/lo bf16 (N x K) ============
__global__ __launch_bounds__(256)
void conv_wt(const float* __restrict__ W0, const float* __restrict__ W1,
             const float* __restrict__ W2, const float* __restrict__ W3,
             u16* __restrict__ WT)
{
    __shared__ float tls[64][68];
    const int z = blockIdx.z;
    const float* W = z == 0 ? W0 : z == 1 ? W1 : z == 2 ? W2 : W3;
    u16* dh = WT + (size_t)z * 2097152;
    u16* dl = dh + 1048576;
    const int kt0 = blockIdx.y * 64;
    const int nt0 = blockIdx.x * 64;
    const int tid = threadIdx.x;

    {
        const int kk = tid >> 4;
        const int nn = (tid & 15) * 4;
        #pragma unroll
        for (int i = 0; i < 4; ++i) {
            const float4 v = *(const float4*)&W[(size_t)(kt0 + kk + 16*i) * ND + nt0 + nn];
            tls[kk + 16*i][nn] = v.x; tls[kk + 16*i][nn+1] = v.y;
            tls[kk + 16*i][nn+2] = v.z; tls[kk + 16*i][nn+3] = v.w;
        }
    }
    __syncthreads();

    const int n  = tid >> 2;
    const int kc = (tid & 3) * 16;
    u16 hb[16], lb[16];
    #pragma unroll
    for (int k = 0; k < 16; ++k) {
        const float v = tls[kc + k][n];
        hb[k] = f2bf(v);
        lb[k] = f2bf(v - bf2f(hb[k]));
    }
    #pragma unroll
    for (int half = 0; half < 2; ++half) {
        *(bf16x8*)&dh[(size_t)(nt0 + n) * ND + kt0 + kc + 8*half] = *(bf16x8*)&hb[8*half];
        *(bf16x8*)&dl[(size_t)(nt0 + n) * ND + kt0 + kc + 8*half] = *(bf16x8*)&lb[8*half];
    }
}

// ============ split-precision bf16 MFMA GEMM, global_load_lds staging ============
// C = Ah@Bh + Ah@Bl + Al@Bh, fp32 accum. A: M x 1024 bf16; B: W^T [n][k].
// mode 0: scatter bf16 to (B,NH,S,DK) planes (bias real, *scale); mode 1: fp32 out.
__global__ __launch_bounds__(256)
void gemm_split(const u16* __restrict__ Ah, const u16* __restrict__ Al,
                const u16* __restrict__ Bh, const u16* __restrict__ Bl,
                const float* __restrict__ bias,
                u16* __restrict__ Yr, u16* __restrict__ Yi,
                float* __restrict__ Yf, const int mode, const float scale)
{
    __shared__ u16 AsH[4096];   // [128][32] u16, unpadded 64B rows
    __shared__ u16 AsL[4096];
    __shared__ u16 BsH[4096];
    __shared__ u16 BsL[4096];

    const int tid  = threadIdx.x;
    const int wave = tid >> 6;
    const int lane = tid & 63;
    const int g = lane >> 4;
    const int c = lane & 15;
    const int wm = wave >> 1;
    const int wn = wave & 1;
    const int row0 = blockIdx.y * 128;
    const int col0 = blockIdx.x * 128;

    // staging: wave w owns one plane; 8 chunks of 16 rows x 64B each
    const u16* gplane = wave == 0 ? Ah : wave == 1 ? Al : wave == 2 ? Bh : Bl;
    u16* lplane = wave == 0 ? AsH : wave == 1 ? AsL : wave == 2 ? BsH : BsL;
    const int rbase = (wave < 2 ? row0 : col0);
    const int lrow = lane >> 2;
    const int lcol = (lane & 3) * 8;
    const u16* gthread = gplane + (size_t)(rbase + lrow) * ND + lcol;

    f32x4 acc[4][4];
    #pragma unroll
    for (int i = 0; i < 4; ++i)
        #pragma unroll
        for (int j = 0; j < 4; ++j)
            acc[i][j] = (f32x4){0.f, 0.f, 0.f, 0.f};

    for (int k0 = 0; k0 < ND; k0 += 32) {
        #pragma unroll
        for (int i = 0; i < 8; ++i) {
            __builtin_amdgcn_global_load_lds(
                (gas_p)(gthread + k0 + (size_t)16 * i * ND),
                (las_p)(lplane + i * 512), 16, 0, 0);
        }
        __syncthreads();   // drains vmcnt -> staged data visible

        bf16x8 a_h[4], a_l[4], b_h[4], b_l[4];
        #pragma unroll
        for (int f = 0; f < 4; ++f) {
            const int ar = wm*64 + f*16 + c;
            const int br = wn*64 + f*16 + c;
            a_h[f] = *(const bf16x8*)&AsH[ar*32 + 8*g];
            a_l[f] = *(const bf16x8*)&AsL[ar*32 + 8*g];
            b_h[f] = *(const bf16x8*)&BsH[br*32 + 8*g];
            b_l[f] = *(const bf16x8*)&BsL[br*32 + 8*g];
        }
        #pragma unroll
        for (int fm = 0; fm < 4; ++fm) {
            #pragma unroll
            for (int fn = 0; fn < 4; ++fn) {
                acc[fm][fn] = __builtin_amdgcn_mfma_f32_16x16x32_bf16(a_h[fm], b_h[fn], acc[fm][fn], 0, 0, 0);
                acc[fm][fn] = __builtin_amdgcn_mfma_f32_16x16x32_bf16(a_h[fm], b_l[fn], acc[fm][fn], 0, 0, 0);
                acc[fm][fn] = __builtin_amdgcn_mfma_f32_16x16x32_bf16(a_l[fm], b_h[fn], acc[fm][fn], 0, 0, 0);
            }
        }
        __syncthreads();
    }

    #pragma unroll
    for (int fm = 0; fm < 4; ++fm) {
        #pragma unroll
        for (int fn = 0; fn < 4; ++fn) {
            #pragma unroll
            for (int j = 0; j < 4; ++j) {
                const int m = row0 + wm*64 + fm*16 + 4*g + j;
                const int n = col0 + wn*64 + fn*16 + c;
                const float v = acc[fm][fn][j];
                if (mode == 0) {
                    const int plane = m >> 12;
                    const int mm = m & 4095;
                    const int b  = mm >> 11;
                    const int s  = mm & (NS - 1);
                    const int hh = n >> 6;
                    const int dk = n & 63;
                    const float val = v*scale + (plane == 0 ? bias[n]*scale : 0.f);
                    (plane ? Yi : Yr)[(((size_t)(b*NH + hh) * NS) + s) * NDK + dk] = f2bf(val);
                } else {
                    Yf[(size_t)m * ND + n] = v + bias[n];
                }
            }
        }
    }
}

// ============ MFMA flash attention, swapped QK^T, exp2-domain softmax ============
// Q planes pre-scaled by (1/8)*log2(e). S[kv][q] = mfma(K', Q') with
// K' = [Kr|Ki] (XOR-swizzled linear LDS rows), Q' = [Qr|-Qi] in registers.
// Per-lane softmax for q-row c (2 shfl per reduce). P -> per-wave LDS (b64
// stores) -> PV with packed-transposed V.
#define LDV 72
#define LDP 72

__global__ __launch_bounds__(256)
void attn_mfma(const u16* __restrict__ Qr, const u16* __restrict__ Qi,
               const u16* __restrict__ Kr, const u16* __restrict__ Ki,
               const u16* __restrict__ Vv,
               u16* __restrict__ OH, u16* __restrict__ OL)
{
    __shared__ __align__(16) u16 Ks[64 * 128];    // [kv][128], rows 256B, XOR-swz
    __shared__ __align__(16) u16 Vs[64 * LDV];    // [dk][kv] packed pairs
    __shared__ __align__(16) u16 Ps[4][16 * LDP]; // per-wave P[q][kv]

    const int tid  = threadIdx.x;
    const int wave = tid >> 6;
    const int lane = tid & 63;
    const int g = lane >> 4;
    const int c = lane & 15;

    const int bh = blockIdx.y;
    const int q0 = blockIdx.x * 64;
    const size_t base = (size_t)bh * NS * NDK;

    // Q' fragments (B-operand): lane (g,c) holds Q'[q=c][k=32s+8g+b]
    bf16x8 qb[4];
    {
        const u16* qr = Qr + base + (size_t)(q0 + wave*16 + c) * NDK;
        const u16* qi = Qi + base + (size_t)(q0 + wave*16 + c) * NDK;
        #pragma unroll
        for (int s = 0; s < 2; ++s) {
            qb[s] = *(const bf16x8*)(qr + 32*s + 8*g);
            const bf16x8 t = *(const bf16x8*)(qi + 32*s + 8*g);
            bf16x8 f;
            #pragma unroll
            for (int j = 0; j < 8; ++j) f[j] = t[j] ^ (short)0x8000;
            qb[2+s] = f;
        }
    }

    // K staging map: 16 lanes per row (8 Kr slots | 8 Ki slots)
    const int kr_row = tid >> 4;          // 0..15 (+16p)
    const int kc16 = tid & 15;            // 16B slot in 256B row
    const u16* Ksrc = (kc16 < 8 ? Kr : Ki) + base;
    const int kcol = (kc16 & 7) * 8;
    // V staging map: a2 = kv-pair, bi = dk block (banks 4j+a2 -> 2-way free)
    const int a2 = tid & 31;
    const int bi = tid >> 5;

    f32x4 oacc[4];
    #pragma unroll
    for (int nt = 0; nt < 4; ++nt) oacc[nt] = (f32x4){0.f, 0.f, 0.f, 0.f};
    float mrun = -1e30f, lrun = 0.f;      // state for q-row = c

    for (int kt = 0; kt < NS/64; ++kt) {
        const int k0 = kt * 64;

        // ---- stage K' (XOR-swizzled): one 256B row per 16 lanes ----
        #pragma unroll
        for (int p = 0; p < 4; ++p) {
            const int r = kr_row + 16*p;
            const bf16x8 v = *(const bf16x8*)(Ksrc + (size_t)(k0 + r) * NDK + kcol);
            *(bf16x8*)((char*)Ks + r*256 + ((kc16*16) ^ ((r & 7) << 4))) = v;
        }
        // ---- stage V packed-transpose ----
        {
            const u16* v0 = Vv + base + (size_t)(k0 + 2*a2) * NDK + bi*8;
            const bf16x8 x = *(const bf16x8*)v0;
            const bf16x8 y = *(const bf16x8*)(v0 + NDK);
            #pragma unroll
            for (int j = 0; j < 8; ++j) {
                const unsigned pk = (unsigned)(u16)x[j] | ((unsigned)(u16)y[j] << 16);
                *(unsigned*)&Vs[(bi*8 + j)*LDV + 2*a2] = pk;
            }
        }
        __syncthreads();

        // ---- swapped QK^T: sacc[nt] = S[kv=16nt+4g+j][q=c] ----
        f32x4 sacc[4];
        #pragma unroll
        for (int nt = 0; nt < 4; ++nt) sacc[nt] = (f32x4){0.f, 0.f, 0.f, 0.f};
        #pragma unroll
        for (int s = 0; s < 4; ++s) {
            #pragma unroll
            for (int nt = 0; nt < 4; ++nt) {
                const bf16x8 ka = *(const bf16x8*)((char*)Ks + (nt*16 + c)*256
                                    + ((64*s + 16*g) ^ ((c & 7) << 4)));
                sacc[nt] = __builtin_amdgcn_mfma_f32_16x16x32_bf16(ka, qb[s], sacc[nt], 0, 0, 0);
            }
        }

        // ---- per-lane softmax for q-row c (exp2 domain) ----
        float tmax = sacc[0][0];
        #pragma unroll
        for (int nt = 0; nt < 4; ++nt)
            #pragma unroll
            for (int j = 0; j < 4; ++j) tmax = fmaxf(tmax, sacc[nt][j]);
        tmax = fmaxf(tmax, __shfl_xor(tmax, 16, 64));
        tmax = fmaxf(tmax, __shfl_xor(tmax, 32, 64));
        const float mnew = fmaxf(mrun, tmax);
        const float corr = exp2f(mrun - mnew);
        mrun = mnew;

        float psum = 0.f;
        #pragma unroll
        for (int nt = 0; nt < 4; ++nt) {
            float p0 = exp2f(sacc[nt][0] - mnew);
            float p1 = exp2f(sacc[nt][1] - mnew);
            float p2 = exp2f(sacc[nt][2] - mnew);
            float p3 = exp2f(sacc[nt][3] - mnew);
            psum += (p0 + p1) + (p2 + p3);
            ushort4 pk4;
            pk4.x = f2bf(p0); pk4.y = f2bf(p1); pk4.z = f2bf(p2); pk4.w = f2bf(p3);
            *(ushort4*)&Ps[wave][c*LDP + nt*16 + 4*g] = pk4;
        }
        psum += __shfl_xor(psum, 16, 64);
        psum += __shfl_xor(psum, 32, 64);
        lrun = lrun * corr + psum;

        // rescale O (rows q=4g+j need corr from lane 4g+j)
        float corr4[4];
        #pragma unroll
        for (int j = 0; j < 4; ++j) corr4[j] = __shfl(corr, 4*g + j, 64);
        #pragma unroll
        for (int nt = 0; nt < 4; ++nt)
            #pragma unroll
            for (int j = 0; j < 4; ++j) oacc[nt][j] *= corr4[j];

        // ---- PV: O += P @ V ----
        #pragma unroll
        for (int s = 0; s < 2; ++s) {
            const bf16x8 pa = *(const bf16x8*)&Ps[wave][c*LDP + 32*s + 8*g];
            #pragma unroll
            for (int nt = 0; nt < 4; ++nt) {
                const bf16x8 vb = *(const bf16x8*)&Vs[(nt*16 + c)*LDV + 32*s + 8*g];
                oacc[nt] = __builtin_amdgcn_mfma_f32_16x16x32_bf16(pa, vb, oacc[nt], 0, 0, 0);
            }
        }
        __syncthreads();
    }

    // ---- epilogue: hi/lo split of O/l -> (B*S, D) ----
    const int b  = bh >> 4;
    const int hh = bh & 15;
    float linv[4];
    #pragma unroll
    for (int j = 0; j < 4; ++j) linv[j] = 1.0f / __shfl(lrun, 4*g + j, 64);
    #pragma unroll
    for (int j = 0; j < 4; ++j) {
        const int srow = q0 + wave*16 + 4*g + j;
        #pragma unroll
        for (int nt = 0; nt < 4; ++nt) {
            const float val = oacc[nt][j] * linv[j];
            const u16 hb = f2bf(val);
            const u16 lb = f2bf(val - bf2f(hb));
            const size_t o = (size_t)(b*NS + srow)*ND + hh*NDK + nt*16 + c;
            OH[o] = hb;
            OL[o] = lb;
        }
    }
}

extern "C" void kernel_launch(void* const* d_in, const int* in_sizes, int n_in,
                              void* d_out, int out_size, void* d_ws, size_t ws_size,
                              hipStream_t stream)
{
    const float* xr = (const float*)d_in[0];
    const float* xi = (const float*)d_in[1];
    const float* Wq = (const float*)d_in[2];
    const float* bq = (const float*)d_in[3];
    const float* Wk = (const float*)d_in[4];
    const float* bk = (const float*)d_in[5];
    const float* Wv = (const float*)d_in[6];
    const float* bv = (const float*)d_in[7];
    const float* Wo = (const float*)d_in[8];
    const float* bo = (const float*)d_in[9];
    float* out = (float*)d_out;

    u16* ws = (u16*)d_ws;
    const size_t PL = (size_t)NM * ND;
    u16* XH = ws;
    u16* XL = ws + 2*PL;
    u16* WT = ws + 4*PL;
    u16* QP = WT + 8 * 1048576;
    u16* Qr = QP;          u16* Qi = QP + PL;
    u16* Kr = QP + 2*PL;   u16* Ki = QP + 3*PL;
    u16* Vv = QP + 4*PL;
    u16* OH = ws;                                // alias dead x_hi region
    u16* OL = ws + PL;

    conv_x<<<2*PL/(256*4), 256, 0, stream>>>(xr, xi, XH, XL);
    conv_wt<<<dim3(ND/64, ND/64, 4), 256, 0, stream>>>(Wq, Wk, Wv, Wo, WT);

    u16* WTq = WT;  u16* WTk = WT + 2097152;  u16* WTv = WT + 2*2097152;  u16* WTo = WT + 3*2097152;

    // Q scaled by (1/8)*log2e for exp2-domain softmax
    gemm_split<<<dim3(ND/128, 2*NM/128), 256, 0, stream>>>(XH, XL, WTq, WTq + 1048576, bq, Qr, Qi, nullptr, 0, 0.125f * LOG2E);
    gemm_split<<<dim3(ND/128, 2*NM/128), 256, 0, stream>>>(XH, XL, WTk, WTk + 1048576, bk, Kr, Ki, nullptr, 0, 1.0f);
    gemm_split<<<dim3(ND/128,   NM/128), 256, 0, stream>>>(XH, XL, WTv, WTv + 1048576, bv, Vv, Vv, nullptr, 0, 1.0f);

    attn_mfma<<<dim3(NS/64, NB*NH), 256, 0, stream>>>(Qr, Qi, Kr, Ki, Vv, OH, OL);

    gemm_split<<<dim3(ND/128,   NM/128), 256, 0, stream>>>(OH, OL, WTo, WTo + 1048576, bo, nullptr, nullptr, out, 1, 1.0f);
}

// Round 8
// 341.645 us; speedup vs baseline: 6.2252x; 1.0991x over previous
//
#include <hip/hip_runtime.h>

#define NB 2
#define NS 2048
#define ND 1024
#define NH 16
#define NDK 64
#define NM (NB*NS)   // 4096

typedef unsigned short u16;
typedef short bf16x8 __attribute__((ext_vector_type(8)));
typedef float f32x4 __attribute__((ext_vector_type(4)));
typedef const __attribute__((address_space(1))) void* gas_p;
typedef __attribute__((address_space(3))) void* las_p;

#define LOG2E 1.4426950408889634f

__device__ __forceinline__ u16 f2bf(float f) {
    unsigned u = __builtin_bit_cast(unsigned, f);
    u += 0x7fffu + ((u >> 16) & 1u);         // RTNE
    return (u16)(u >> 16);
}
__device__ __forceinline__ float bf2f(u16 h) {
    return __builtin_bit_cast(float, (unsigned)h << 16);
}

// ============ conv_x: xr,xi fp32 -> stacked hi/lo bf16 planes [xr; xi] ============
__global__ __launch_bounds__(256)
void conv_x(const float* __restrict__ xr, const float* __restrict__ xi,
            u16* __restrict__ XH, u16* __restrict__ XL)
{
    const size_t gid = (size_t)blockIdx.x * 256 + threadIdx.x;
    const size_t PQ = (size_t)NM * ND / 4;
    const int p = gid >= PQ;
    const size_t off = (gid - (p ? PQ : 0)) * 4;
    const float4 v = *(const float4*)&((p ? xi : xr)[off]);
    const size_t d = (size_t)p * NM * ND + off;
    float vs[4] = {v.x, v.y, v.z, v.w};
    ushort4 h, l;
    u16* hp = (u16*)&h; u16* lp = (u16*)&l;
    #pragma unroll
    for (int j = 0; j < 4; ++j) {
        hp[j] = f2bf(vs[j]);
        lp[j] = f2bf(vs[j] - bf2f(hp[j]));
    }
    *(ushort4*)&XH[d] = h;
    *(ushort4*)&XL[d] = l;
}

// ============ conv_wt: W (K x N fp32) -> W^T hi/lo bf16 (N x K) ============
__global__ __launch_bounds__(256)
void conv_wt(const float* __restrict__ W0, const float* __restrict__ W1,
             const float* __restrict__ W2, const float* __restrict__ W3,
             u16* __restrict__ WT)
{
    __shared__ float tls[64][68];
    const int z = blockIdx.z;
    const float* W = z == 0 ? W0 : z == 1 ? W1 : z == 2 ? W2 : W3;
    u16* dh = WT + (size_t)z * 2097152;
    u16* dl = dh + 1048576;
    const int kt0 = blockIdx.y * 64;
    const int nt0 = blockIdx.x * 64;
    const int tid = threadIdx.x;

    {
        const int kk = tid >> 4;
        const int nn = (tid & 15) * 4;
        #pragma unroll
        for (int i = 0; i < 4; ++i) {
            const float4 v = *(const float4*)&W[(size_t)(kt0 + kk + 16*i) * ND + nt0 + nn];
            tls[kk + 16*i][nn] = v.x; tls[kk + 16*i][nn+1] = v.y;
            tls[kk + 16*i][nn+2] = v.z; tls[kk + 16*i][nn+3] = v.w;
        }
    }
    __syncthreads();

    const int n  = tid >> 2;
    const int kc = (tid & 3) * 16;
    u16 hb[16], lb[16];
    #pragma unroll
    for (int k = 0; k < 16; ++k) {
        const float v = tls[kc + k][n];
        hb[k] = f2bf(v);
        lb[k] = f2bf(v - bf2f(hb[k]));
    }
    #pragma unroll
    for (int half = 0; half < 2; ++half) {
        *(bf16x8*)&dh[(size_t)(nt0 + n) * ND + kt0 + kc + 8*half] = *(bf16x8*)&hb[8*half];
        *(bf16x8*)&dl[(size_t)(nt0 + n) * ND + kt0 + kc + 8*half] = *(bf16x8*)&lb[8*half];
    }
}

// ============ split-precision bf16 MFMA GEMM, dbuf global_load_lds pipeline ============
// C = Ah@Bh + Ah@Bl + Al@Bh, fp32 accum. 2-phase double-buffer, counted vmcnt,
// raw barriers (never drain vmcnt to 0 in the main loop). XCD-chunked swizzle.
__global__ __launch_bounds__(256)
void gemm_split(const u16* __restrict__ Ah, const u16* __restrict__ Al,
                const u16* __restrict__ Bh, const u16* __restrict__ Bl,
                const float* __restrict__ bias,
                u16* __restrict__ Yr, u16* __restrict__ Yi,
                float* __restrict__ Yf, const int mode, const float scale)
{
    __shared__ u16 LDS[2][4][4096];   // [buf][plane AH/AL/BH/BL][128*32] u16

    const int tid  = threadIdx.x;
    const int wave = tid >> 6;
    const int lane = tid & 63;
    const int g = lane >> 4;
    const int c = lane & 15;
    const int wm = wave >> 1;
    const int wn = wave & 1;

    // XCD-chunked bijective swizzle (nwg % 8 == 0 for all our grids)
    const int nbx = gridDim.x;
    const int nwg = nbx * gridDim.y;
    const int wgid = blockIdx.y * nbx + blockIdx.x;
    const int swz = (wgid & 7) * (nwg >> 3) + (wgid >> 3);
    const int row0 = (swz / nbx) * 128;
    const int col0 = (swz % nbx) * 128;

    // staging: wave w owns one plane; 8 chunks of 16 rows x 64B per k-step
    const u16* gplane = wave == 0 ? Ah : wave == 1 ? Al : wave == 2 ? Bh : Bl;
    const int rbase = (wave < 2 ? row0 : col0);
    const int lrow = lane >> 2;
    const int lcol = (lane & 3) * 8;
    const u16* gthread = gplane + (size_t)(rbase + lrow) * ND + lcol;
    u16* lplane = &LDS[0][wave][0];

    f32x4 acc[4][4];
    #pragma unroll
    for (int i = 0; i < 4; ++i)
        #pragma unroll
        for (int j = 0; j < 4; ++j)
            acc[i][j] = (f32x4){0.f, 0.f, 0.f, 0.f};

    // prologue: stage k-tile 0 into buf 0
    #pragma unroll
    for (int i = 0; i < 8; ++i)
        __builtin_amdgcn_global_load_lds((gas_p)(gthread + (size_t)16 * i * ND),
                                         (las_p)(lplane + i * 512), 16, 0, 0);

    for (int t = 0; t < 32; ++t) {
        if (t < 31) {
            const u16* gsrc = gthread + (size_t)(t + 1) * 32;
            u16* ldst = lplane + ((t + 1) & 1) * (4 * 4096);
            #pragma unroll
            for (int i = 0; i < 8; ++i)
                __builtin_amdgcn_global_load_lds((gas_p)(gsrc + (size_t)16 * i * ND),
                                                 (las_p)(ldst + i * 512), 16, 0, 0);
            asm volatile("s_waitcnt vmcnt(8)" ::: "memory");
        } else {
            asm volatile("s_waitcnt vmcnt(0)" ::: "memory");
        }
        __builtin_amdgcn_sched_barrier(0);
        __builtin_amdgcn_s_barrier();       // cur buffer fully staged, all waves
        __builtin_amdgcn_sched_barrier(0);

        const u16* AsH = &LDS[t & 1][0][0];
        const u16* AsL = &LDS[t & 1][1][0];
        const u16* BsH = &LDS[t & 1][2][0];
        const u16* BsL = &LDS[t & 1][3][0];

        bf16x8 a_h[4], a_l[4], b_h[4], b_l[4];
        #pragma unroll
        for (int f = 0; f < 4; ++f) {
            const int ar = wm*64 + f*16 + c;
            const int br = wn*64 + f*16 + c;
            a_h[f] = *(const bf16x8*)&AsH[ar*32 + 8*g];
            a_l[f] = *(const bf16x8*)&AsL[ar*32 + 8*g];
            b_h[f] = *(const bf16x8*)&BsH[br*32 + 8*g];
            b_l[f] = *(const bf16x8*)&BsL[br*32 + 8*g];
        }
        __builtin_amdgcn_s_setprio(1);
        #pragma unroll
        for (int fm = 0; fm < 4; ++fm) {
            #pragma unroll
            for (int fn = 0; fn < 4; ++fn) {
                acc[fm][fn] = __builtin_amdgcn_mfma_f32_16x16x32_bf16(a_h[fm], b_h[fn], acc[fm][fn], 0, 0, 0);
                acc[fm][fn] = __builtin_amdgcn_mfma_f32_16x16x32_bf16(a_h[fm], b_l[fn], acc[fm][fn], 0, 0, 0);
                acc[fm][fn] = __builtin_amdgcn_mfma_f32_16x16x32_bf16(a_l[fm], b_h[fn], acc[fm][fn], 0, 0, 0);
            }
        }
        __builtin_amdgcn_s_setprio(0);
        __builtin_amdgcn_sched_barrier(0);
        __builtin_amdgcn_s_barrier();       // readers done before rewrite
        __builtin_amdgcn_sched_barrier(0);
    }

    #pragma unroll
    for (int fm = 0; fm < 4; ++fm) {
        #pragma unroll
        for (int fn = 0; fn < 4; ++fn) {
            #pragma unroll
            for (int j = 0; j < 4; ++j) {
                const int m = row0 + wm*64 + fm*16 + 4*g + j;
                const int n = col0 + wn*64 + fn*16 + c;
                const float v = acc[fm][fn][j];
                if (mode == 0) {
                    const int plane = m >> 12;
                    const int mm = m & 4095;
                    const int b  = mm >> 11;
                    const int s  = mm & (NS - 1);
                    const int hh = n >> 6;
                    const int dk = n & 63;
                    const float val = v*scale + (plane == 0 ? bias[n]*scale : 0.f);
                    (plane ? Yi : Yr)[(((size_t)(b*NH + hh) * NS) + s) * NDK + dk] = f2bf(val);
                } else {
                    Yf[(size_t)m * ND + n] = v + bias[n];
                }
            }
        }
    }
}

// ============ MFMA flash attention: swapped QK^T, T14 async staging, defer-max ============
#define LDV 72
#define LDP 72
#define NT (NS/64)

__global__ __launch_bounds__(256)
void attn_mfma(const u16* __restrict__ Qr, const u16* __restrict__ Qi,
               const u16* __restrict__ Kr, const u16* __restrict__ Ki,
               const u16* __restrict__ Vv,
               u16* __restrict__ OH, u16* __restrict__ OL)
{
    __shared__ __align__(16) u16 Ks[64 * 128];    // [kv][128], rows 256B, XOR-swz
    __shared__ __align__(16) u16 Vs[64 * LDV];    // [dk][kv] packed pairs
    __shared__ __align__(16) u16 Ps[4][16 * LDP]; // per-wave P[q][kv]

    const int tid  = threadIdx.x;
    const int wave = tid >> 6;
    const int lane = tid & 63;
    const int g = lane >> 4;
    const int c = lane & 15;

    // XCD-chunked swizzle: consecutive q-tiles of one head stay on one XCD
    const int nbx = gridDim.x;
    const int nwg = nbx * gridDim.y;
    const int wgid = blockIdx.y * nbx + blockIdx.x;
    const int swz = (wgid & 7) * (nwg >> 3) + (wgid >> 3);
    const int bh = swz / nbx;
    const int q0 = (swz % nbx) * 64;
    const size_t base = (size_t)bh * NS * NDK;

    // Q' fragments (B-operand): lane (g,c) holds Q'[q=c][k=32s+8g+b]
    bf16x8 qb[4];
    {
        const u16* qr = Qr + base + (size_t)(q0 + wave*16 + c) * NDK;
        const u16* qi = Qi + base + (size_t)(q0 + wave*16 + c) * NDK;
        #pragma unroll
        for (int s = 0; s < 2; ++s) {
            qb[s] = *(const bf16x8*)(qr + 32*s + 8*g);
            const bf16x8 t = *(const bf16x8*)(qi + 32*s + 8*g);
            bf16x8 f;
            #pragma unroll
            for (int j = 0; j < 8; ++j) f[j] = t[j] ^ (short)0x8000;
            qb[2+s] = f;
        }
    }

    // staging maps
    const int kr_row = tid >> 4;          // K: one 256B row per 16 lanes
    const int kc16 = tid & 15;
    const u16* Ksrc = (kc16 < 8 ? Kr : Ki) + base;
    const int kcol = (kc16 & 7) * 8;
    const int a2 = tid & 31;              // V: kv-pair index
    const int bi = tid >> 5;              // V: dk block

    f32x4 oacc[4];
    #pragma unroll
    for (int nt = 0; nt < 4; ++nt) oacc[nt] = (f32x4){0.f, 0.f, 0.f, 0.f};
    float mrun = -1e30f, lrun = 0.f;      // state for q-row = c

    // prologue: load tile 0 into regs
    bf16x8 kreg[4], vx, vy;
    #pragma unroll
    for (int p = 0; p < 4; ++p)
        kreg[p] = *(const bf16x8*)(Ksrc + (size_t)(kr_row + 16*p) * NDK + kcol);
    {
        const u16* v0 = Vv + base + (size_t)(2*a2) * NDK + bi*8;
        vx = *(const bf16x8*)v0;
        vy = *(const bf16x8*)(v0 + NDK);
    }

    for (int kt = 0; kt < NT; ++kt) {
        // ---- write staged regs (tile kt) into LDS ----
        #pragma unroll
        for (int p = 0; p < 4; ++p) {
            const int r = kr_row + 16*p;
            *(bf16x8*)((char*)Ks + r*256 + ((kc16*16) ^ ((r & 7) << 4))) = kreg[p];
        }
        #pragma unroll
        for (int j = 0; j < 8; ++j) {
            const unsigned pk = (unsigned)(u16)vx[j] | ((unsigned)(u16)vy[j] << 16);
            *(unsigned*)&Vs[(bi*8 + j)*LDV + 2*a2] = pk;
        }
        // ---- prefetch tile kt+1 into regs (latency hides under compute) ----
        if (kt + 1 < NT) {
            const int k0n = (kt + 1) * 64;
            #pragma unroll
            for (int p = 0; p < 4; ++p)
                kreg[p] = *(const bf16x8*)(Ksrc + (size_t)(k0n + kr_row + 16*p) * NDK + kcol);
            const u16* v0 = Vv + base + (size_t)(k0n + 2*a2) * NDK + bi*8;
            vx = *(const bf16x8*)v0;
            vy = *(const bf16x8*)(v0 + NDK);
        }
        asm volatile("s_waitcnt lgkmcnt(0)" ::: "memory");   // ds_writes done (NOT vmcnt)
        __builtin_amdgcn_sched_barrier(0);
        __builtin_amdgcn_s_barrier();
        __builtin_amdgcn_sched_barrier(0);

        // ---- swapped QK^T: sacc[nt] = S[kv=16nt+4g+j][q=c] ----
        f32x4 sacc[4];
        #pragma unroll
        for (int nt = 0; nt < 4; ++nt) sacc[nt] = (f32x4){0.f, 0.f, 0.f, 0.f};
        __builtin_amdgcn_s_setprio(1);
        #pragma unroll
        for (int s = 0; s < 4; ++s) {
            #pragma unroll
            for (int nt = 0; nt < 4; ++nt) {
                const bf16x8 ka = *(const bf16x8*)((char*)Ks + (nt*16 + c)*256
                                    + ((64*s + 16*g) ^ ((c & 7) << 4)));
                sacc[nt] = __builtin_amdgcn_mfma_f32_16x16x32_bf16(ka, qb[s], sacc[nt], 0, 0, 0);
            }
        }
        __builtin_amdgcn_s_setprio(0);

        // ---- per-lane softmax for q-row c (exp2 domain) with defer-max ----
        float tmax = sacc[0][0];
        #pragma unroll
        for (int nt = 0; nt < 4; ++nt)
            #pragma unroll
            for (int j = 0; j < 4; ++j) tmax = fmaxf(tmax, sacc[nt][j]);
        tmax = fmaxf(tmax, __shfl_xor(tmax, 16, 64));
        tmax = fmaxf(tmax, __shfl_xor(tmax, 32, 64));

        const bool noskip = !__all(tmax - mrun <= 11.0f);
        float corr = 1.0f;
        if (noskip) {
            const float mnew = fmaxf(mrun, tmax);
            corr = exp2f(mrun - mnew);
            mrun = mnew;
        }

        float psum = 0.f;
        #pragma unroll
        for (int nt = 0; nt < 4; ++nt) {
            float p0 = exp2f(sacc[nt][0] - mrun);
            float p1 = exp2f(sacc[nt][1] - mrun);
            float p2 = exp2f(sacc[nt][2] - mrun);
            float p3 = exp2f(sacc[nt][3] - mrun);
            psum += (p0 + p1) + (p2 + p3);
            ushort4 pk4;
            pk4.x = f2bf(p0); pk4.y = f2bf(p1); pk4.z = f2bf(p2); pk4.w = f2bf(p3);
            *(ushort4*)&Ps[wave][c*LDP + nt*16 + 4*g] = pk4;
        }
        psum += __shfl_xor(psum, 16, 64);
        psum += __shfl_xor(psum, 32, 64);

        if (noskip) {
            lrun = lrun * corr + psum;
            float corr4[4];
            #pragma unroll
            for (int j = 0; j < 4; ++j) corr4[j] = __shfl(corr, 4*g + j, 64);
            #pragma unroll
            for (int nt = 0; nt < 4; ++nt)
                #pragma unroll
                for (int j = 0; j < 4; ++j) oacc[nt][j] *= corr4[j];
        } else {
            lrun += psum;
        }

        // ---- PV: O += P @ V ----
        __builtin_amdgcn_s_setprio(1);
        #pragma unroll
        for (int s = 0; s < 2; ++s) {
            const bf16x8 pa = *(const bf16x8*)&Ps[wave][c*LDP + 32*s + 8*g];
            #pragma unroll
            for (int nt = 0; nt < 4; ++nt) {
                const bf16x8 vb = *(const bf16x8*)&Vs[(nt*16 + c)*LDV + 32*s + 8*g];
                oacc[nt] = __builtin_amdgcn_mfma_f32_16x16x32_bf16(pa, vb, oacc[nt], 0, 0, 0);
            }
        }
        __builtin_amdgcn_s_setprio(0);
        __builtin_amdgcn_sched_barrier(0);
        __builtin_amdgcn_s_barrier();       // raw: prefetch loads stay in flight
        __builtin_amdgcn_sched_barrier(0);
    }

    // ---- epilogue: hi/lo split of O/l -> (B*S, D) ----
    const int b  = bh >> 4;
    const int hh = bh & 15;
    float linv[4];
    #pragma unroll
    for (int j = 0; j < 4; ++j) linv[j] = 1.0f / __shfl(lrun, 4*g + j, 64);
    #pragma unroll
    for (int j = 0; j < 4; ++j) {
        const int srow = q0 + wave*16 + 4*g + j;
        #pragma unroll
        for (int nt = 0; nt < 4; ++nt) {
            const float val = oacc[nt][j] * linv[j];
            const u16 hb = f2bf(val);
            const u16 lb = f2bf(val - bf2f(hb));
            const size_t o = (size_t)(b*NS + srow)*ND + hh*NDK + nt*16 + c;
            OH[o] = hb;
            OL[o] = lb;
        }
    }
}

extern "C" void kernel_launch(void* const* d_in, const int* in_sizes, int n_in,
                              void* d_out, int out_size, void* d_ws, size_t ws_size,
                              hipStream_t stream)
{
    const float* xr = (const float*)d_in[0];
    const float* xi = (const float*)d_in[1];
    const float* Wq = (const float*)d_in[2];
    const float* bq = (const float*)d_in[3];
    const float* Wk = (const float*)d_in[4];
    const float* bk = (const float*)d_in[5];
    const float* Wv = (const float*)d_in[6];
    const float* bv = (const float*)d_in[7];
    const float* Wo = (const float*)d_in[8];
    const float* bo = (const float*)d_in[9];
    float* out = (float*)d_out;

    u16* ws = (u16*)d_ws;
    const size_t PL = (size_t)NM * ND;
    u16* XH = ws;
    u16* XL = ws + 2*PL;
    u16* WT = ws + 4*PL;
    u16* QP = WT + 8 * 1048576;
    u16* Qr = QP;          u16* Qi = QP + PL;
    u16* Kr = QP + 2*PL;   u16* Ki = QP + 3*PL;
    u16* Vv = QP + 4*PL;
    u16* OH = ws;                                // alias dead x_hi region
    u16* OL = ws + PL;

    conv_x<<<2*PL/(256*4), 256, 0, stream>>>(xr, xi, XH, XL);
    conv_wt<<<dim3(ND/64, ND/64, 4), 256, 0, stream>>>(Wq, Wk, Wv, Wo, WT);

    u16* WTq = WT;  u16* WTk = WT + 2097152;  u16* WTv = WT + 2*2097152;  u16* WTo = WT + 3*2097152;

    // Q scaled by (1/8)*log2e for exp2-domain softmax
    gemm_split<<<dim3(ND/128, 2*NM/128), 256, 0, stream>>>(XH, XL, WTq, WTq + 1048576, bq, Qr, Qi, nullptr, 0, 0.125f * LOG2E);
    gemm_split<<<dim3(ND/128, 2*NM/128), 256, 0, stream>>>(XH, XL, WTk, WTk + 1048576, bk, Kr, Ki, nullptr, 0, 1.0f);
    gemm_split<<<dim3(ND/128,   NM/128), 256, 0, stream>>>(XH, XL, WTv, WTv + 1048576, bv, Vv, Vv, nullptr, 0, 1.0f);

    attn_mfma<<<dim3(NS/64, NB*NH), 256, 0, stream>>>(Qr, Qi, Kr, Ki, Vv, OH, OL);

    gemm_split<<<dim3(ND/128,   NM/128), 256, 0, stream>>>(OH, OL, WTo, WTo + 1048576, bo, nullptr, nullptr, out, 1, 1.0f);
}

// Round 9
// 309.814 us; speedup vs baseline: 6.8647x; 1.1027x over previous
//
#include <hip/hip_runtime.h>

#define NB 2
#define NS 2048
#define ND 1024
#define NH 16
#define NDK 64
#define NM (NB*NS)   // 4096

typedef unsigned short u16;
typedef short bf16x8 __attribute__((ext_vector_type(8)));
typedef float f32x4 __attribute__((ext_vector_type(4)));
typedef const __attribute__((address_space(1))) void* gas_p;
typedef __attribute__((address_space(3))) void* las_p;

#define LOG2E 1.4426950408889634f

__device__ __forceinline__ u16 f2bf(float f) {
    unsigned u = __builtin_bit_cast(unsigned, f);
    u += 0x7fffu + ((u >> 16) & 1u);         // RTNE
    return (u16)(u >> 16);
}
__device__ __forceinline__ float bf2f(u16 h) {
    return __builtin_bit_cast(float, (unsigned)h << 16);
}

// ============ conv_x: xr,xi fp32 -> stacked hi bf16 plane [xr; xi] ============
__global__ __launch_bounds__(256)
void conv_x(const float* __restrict__ xr, const float* __restrict__ xi,
            u16* __restrict__ XH)
{
    const size_t gid = (size_t)blockIdx.x * 256 + threadIdx.x;
    const size_t PQ = (size_t)NM * ND / 4;
    const int p = gid >= PQ;
    const size_t off = (gid - (p ? PQ : 0)) * 4;
    const float4 v = *(const float4*)&((p ? xi : xr)[off]);
    const size_t d = (size_t)p * NM * ND + off;
    float vs[4] = {v.x, v.y, v.z, v.w};
    ushort4 h;
    u16* hp = (u16*)&h;
    #pragma unroll
    for (int j = 0; j < 4; ++j) hp[j] = f2bf(vs[j]);
    *(ushort4*)&XH[d] = h;
}

// ============ conv_wt: W (K x N fp32) -> W^T hi/lo bf16 (N x K) ============
__global__ __launch_bounds__(256)
void conv_wt(const float* __restrict__ W0, const float* __restrict__ W1,
             const float* __restrict__ W2, const float* __restrict__ W3,
             u16* __restrict__ WT)
{
    __shared__ float tls[64][68];
    const int z = blockIdx.z;
    const float* W = z == 0 ? W0 : z == 1 ? W1 : z == 2 ? W2 : W3;
    u16* dh = WT + (size_t)z * 2097152;
    u16* dl = dh + 1048576;
    const int kt0 = blockIdx.y * 64;
    const int nt0 = blockIdx.x * 64;
    const int tid = threadIdx.x;

    {
        const int kk = tid >> 4;
        const int nn = (tid & 15) * 4;
        #pragma unroll
        for (int i = 0; i < 4; ++i) {
            const float4 v = *(const float4*)&W[(size_t)(kt0 + kk + 16*i) * ND + nt0 + nn];
            tls[kk + 16*i][nn] = v.x; tls[kk + 16*i][nn+1] = v.y;
            tls[kk + 16*i][nn+2] = v.z; tls[kk + 16*i][nn+3] = v.w;
        }
    }
    __syncthreads();

    const int n  = tid >> 2;
    const int kc = (tid & 3) * 16;
    u16 hb[16], lb[16];
    #pragma unroll
    for (int k = 0; k < 16; ++k) {
        const float v = tls[kc + k][n];
        hb[k] = f2bf(v);
        lb[k] = f2bf(v - bf2f(hb[k]));
    }
    #pragma unroll
    for (int half = 0; half < 2; ++half) {
        *(bf16x8*)&dh[(size_t)(nt0 + n) * ND + kt0 + kc + 8*half] = *(bf16x8*)&hb[8*half];
        *(bf16x8*)&dl[(size_t)(nt0 + n) * ND + kt0 + kc + 8*half] = *(bf16x8*)&lb[8*half];
    }
}

// ============ vt_trans: Vv [bh][s][dk] -> Vt [bh][dk][s] ============
__global__ __launch_bounds__(256)
void vt_trans(const u16* __restrict__ Vv, u16* __restrict__ Vt)
{
    __shared__ u16 T[64][72];
    const int bh = blockIdx.y;
    const int s0 = blockIdx.x * 64;
    const int tid = threadIdx.x;
    const size_t base = (size_t)bh * NS * NDK;

    const int r = tid >> 3, cb = (tid & 7) * 8;
    #pragma unroll
    for (int i = 0; i < 2; ++i) {
        const int row = r + 32*i;
        *(bf16x8*)&T[row][cb] = *(const bf16x8*)(Vv + base + (size_t)(s0 + row) * NDK + cb);
    }
    __syncthreads();

    const int dk = tid >> 2, sb = (tid & 3) * 16;
    u16 buf[16];
    #pragma unroll
    for (int k = 0; k < 16; ++k) buf[k] = T[sb + k][dk];
    *(bf16x8*)(Vt + base + (size_t)dk * NS + s0 + sb)     = *(bf16x8*)&buf[0];
    *(bf16x8*)(Vt + base + (size_t)dk * NS + s0 + sb + 8) = *(bf16x8*)&buf[8];
}

// ============ split-precision bf16 MFMA GEMM, dbuf gld_lds pipeline ============
// TERMS=2: C = Ah@Bh + Ah@Bl (A single bf16) — for Q/K/V (output bf16 anyway).
// TERMS=3: + Al@Bh — for the fp32 final projection.
template<int TERMS>
__global__ __launch_bounds__(256)
void gemm_split(const u16* __restrict__ Ah, const u16* __restrict__ Al,
                const u16* __restrict__ Bh, const u16* __restrict__ Bl,
                const float* __restrict__ bias,
                u16* __restrict__ Yr, u16* __restrict__ Yi,
                float* __restrict__ Yf, const int mode, const float scale)
{
    constexpr int NP = TERMS + 1;            // planes: AH, BH, BL [, AL]
    __shared__ u16 LDS[2][NP][4096];         // [buf][plane][128*32]

    const int tid  = threadIdx.x;
    const int wave = tid >> 6;
    const int lane = tid & 63;
    const int g = lane >> 4;
    const int c = lane & 15;
    const int wm = wave >> 1;
    const int wn = wave & 1;

    const int nbx = gridDim.x;
    const int nwg = nbx * gridDim.y;
    const int wgid = blockIdx.y * nbx + blockIdx.x;
    const int swz = (wgid & 7) * (nwg >> 3) + (wgid >> 3);
    const int row0 = (swz / nbx) * 128;
    const int col0 = (swz % nbx) * 128;

    // per-chunk staging maps (NP*2 chunks of 1KB per wave-set)
    const int lr = lane >> 2;
    const int lq = lane & 3;
    const u16* srcs[8];
    int doffs[8];
    #pragma unroll
    for (int i = 0; i < NP*2; ++i) {
        const int ci = wave * (NP*2) + i;
        const int p = ci >> 3;
        const int o = ci & 7;
        const u16* pl = (p == 0) ? Ah : (p == 1) ? Bh : (p == 2) ? Bl : Al;
        const int rb = (p == 0 || p == 3) ? row0 : col0;
        srcs[i] = pl + (size_t)(rb + o*16 + lr) * ND + lq*8;
        doffs[i] = p*4096 + o*512;
    }

    f32x4 acc[4][4];
    #pragma unroll
    for (int i = 0; i < 4; ++i)
        #pragma unroll
        for (int j = 0; j < 4; ++j)
            acc[i][j] = (f32x4){0.f, 0.f, 0.f, 0.f};

    // prologue: stage k-tile 0 into buf 0
    #pragma unroll
    for (int i = 0; i < NP*2; ++i)
        __builtin_amdgcn_global_load_lds((gas_p)srcs[i],
                                         (las_p)(&LDS[0][0][0] + doffs[i]), 16, 0, 0);

    for (int t = 0; t < 32; ++t) {
        if (t < 31) {
            u16* ldst = &LDS[(t + 1) & 1][0][0];
            #pragma unroll
            for (int i = 0; i < NP*2; ++i)
                __builtin_amdgcn_global_load_lds((gas_p)(srcs[i] + (size_t)(t + 1) * 32),
                                                 (las_p)(ldst + doffs[i]), 16, 0, 0);
            if constexpr (TERMS == 2) asm volatile("s_waitcnt vmcnt(6)" ::: "memory");
            else                      asm volatile("s_waitcnt vmcnt(8)" ::: "memory");
        } else {
            asm volatile("s_waitcnt vmcnt(0)" ::: "memory");
        }
        __builtin_amdgcn_sched_barrier(0);
        __builtin_amdgcn_s_barrier();
        __builtin_amdgcn_sched_barrier(0);

        const u16* AsH = &LDS[t & 1][0][0];
        const u16* BsH = &LDS[t & 1][1][0];
        const u16* BsL = &LDS[t & 1][2][0];

        bf16x8 a_h[4], b_h[4], b_l[4], a_l[4];
        #pragma unroll
        for (int f = 0; f < 4; ++f) {
            const int ar = wm*64 + f*16 + c;
            const int br = wn*64 + f*16 + c;
            a_h[f] = *(const bf16x8*)&AsH[ar*32 + 8*g];
            b_h[f] = *(const bf16x8*)&BsH[br*32 + 8*g];
            b_l[f] = *(const bf16x8*)&BsL[br*32 + 8*g];
            if constexpr (TERMS == 3)
                a_l[f] = *(const bf16x8*)&LDS[t & 1][3][ar*32 + 8*g];
        }
        __builtin_amdgcn_s_setprio(1);
        #pragma unroll
        for (int fm = 0; fm < 4; ++fm) {
            #pragma unroll
            for (int fn = 0; fn < 4; ++fn) {
                acc[fm][fn] = __builtin_amdgcn_mfma_f32_16x16x32_bf16(a_h[fm], b_h[fn], acc[fm][fn], 0, 0, 0);
                acc[fm][fn] = __builtin_amdgcn_mfma_f32_16x16x32_bf16(a_h[fm], b_l[fn], acc[fm][fn], 0, 0, 0);
                if constexpr (TERMS == 3)
                    acc[fm][fn] = __builtin_amdgcn_mfma_f32_16x16x32_bf16(a_l[fm], b_h[fn], acc[fm][fn], 0, 0, 0);
            }
        }
        __builtin_amdgcn_s_setprio(0);
        __builtin_amdgcn_sched_barrier(0);
        __builtin_amdgcn_s_barrier();
        __builtin_amdgcn_sched_barrier(0);
    }

    #pragma unroll
    for (int fm = 0; fm < 4; ++fm) {
        #pragma unroll
        for (int fn = 0; fn < 4; ++fn) {
            #pragma unroll
            for (int j = 0; j < 4; ++j) {
                const int m = row0 + wm*64 + fm*16 + 4*g + j;
                const int n = col0 + wn*64 + fn*16 + c;
                const float v = acc[fm][fn][j];
                if (mode == 0) {
                    const int plane = m >> 12;
                    const int mm = m & 4095;
                    const int b  = mm >> 11;
                    const int s  = mm & (NS - 1);
                    const int hh = n >> 6;
                    const int dk = n & 63;
                    const float val = v*scale + (plane == 0 ? bias[n]*scale : 0.f);
                    (plane ? Yi : Yr)[(((size_t)(b*NH + hh) * NS) + s) * NDK + dk] = f2bf(val);
                } else {
                    Yf[(size_t)m * ND + n] = v + bias[n];
                }
            }
        }
    }
}

// ============ MFMA flash attention: gld_lds K/V staging (pre-swizzled source),
// dbuf + counted vmcnt, swapped QK^T, swizzled Ps, defer-max ============
__global__ __launch_bounds__(256)
void attn_mfma(const u16* __restrict__ Qr, const u16* __restrict__ Qi,
               const u16* __restrict__ Kr, const u16* __restrict__ Ki,
               const u16* __restrict__ Vt,
               u16* __restrict__ OH, u16* __restrict__ OL)
{
    __shared__ __align__(16) u16 Ks[2][8192];   // [buf][kv64][128], XOR-swz content
    __shared__ __align__(16) u16 Vs[2][4096];   // [buf][dk64][64],  XOR-swz content
    __shared__ __align__(16) u16 Ps[4][1024];   // per-wave P[q16][kv64], XOR-swz

    const int tid  = threadIdx.x;
    const int wave = tid >> 6;
    const int lane = tid & 63;
    const int g = lane >> 4;
    const int c = lane & 15;

    const int nbx = gridDim.x;
    const int nwg = nbx * gridDim.y;
    const int wgid = blockIdx.y * nbx + blockIdx.x;
    const int swz = (wgid & 7) * (nwg >> 3) + (wgid >> 3);
    const int bh = swz / nbx;
    const int q0 = (swz % nbx) * 64;
    const size_t base = (size_t)bh * NS * NDK;

    // Q' fragments (B-operand): lane (g,c) holds Q'[q=c][k=32s+8g+b]
    bf16x8 qb[4];
    {
        const u16* qr = Qr + base + (size_t)(q0 + wave*16 + c) * NDK;
        const u16* qi = Qi + base + (size_t)(q0 + wave*16 + c) * NDK;
        #pragma unroll
        for (int s = 0; s < 2; ++s) {
            qb[s] = *(const bf16x8*)(qr + 32*s + 8*g);
            const bf16x8 t = *(const bf16x8*)(qi + 32*s + 8*g);
            bf16x8 f;
            #pragma unroll
            for (int j = 0; j < 8; ++j) f[j] = t[j] ^ (short)0x8000;
            qb[2+s] = f;
        }
    }

    // staging maps: pre-swizzled global source + linear LDS dest (rule #21)
    const int slot = lane & 15;           // K: 16B slot in 256B row
    const int rloc = lane >> 4;           // K: row within 4-row chunk
    const u16* kplane = (slot < 8 ? Kr : Ki) + base;
    const u16* srcK[4];
    #pragma unroll
    for (int i = 0; i < 4; ++i) {
        const int row = (wave*4 + i)*4 + rloc;
        srcK[i] = kplane + (size_t)row * NDK + ((slot ^ (row & 7)) & 7) * 8;
    }
    const int r8 = lane >> 3, sl = lane & 7;   // V: 8 rows x 8 slots per chunk
    const u16* vbase = Vt + base;
    const u16* srcV[2];
    #pragma unroll
    for (int i = 0; i < 2; ++i) {
        const int dk = (wave*2 + i)*8 + r8;
        srcV[i] = vbase + (size_t)dk * NS + ((sl ^ r8) & 7) * 8;
    }

    f32x4 oacc[4];
    #pragma unroll
    for (int nt = 0; nt < 4; ++nt) oacc[nt] = (f32x4){0.f, 0.f, 0.f, 0.f};
    float mrun = -1e30f, lrun = 0.f;      // state for q-row = c

    // prologue: stage tile 0 into buf 0 (6 chunks/wave)
    #pragma unroll
    for (int i = 0; i < 4; ++i)
        __builtin_amdgcn_global_load_lds((gas_p)srcK[i],
                                         (las_p)(&Ks[0][0] + (wave*4 + i)*512), 16, 0, 0);
    #pragma unroll
    for (int i = 0; i < 2; ++i)
        __builtin_amdgcn_global_load_lds((gas_p)srcV[i],
                                         (las_p)(&Vs[0][0] + (wave*2 + i)*512), 16, 0, 0);

    for (int kt = 0; kt < NS/64; ++kt) {
        const int cur = kt & 1;
        if (kt < NS/64 - 1) {
            const int nk0 = (kt + 1) * 64;
            #pragma unroll
            for (int i = 0; i < 4; ++i)
                __builtin_amdgcn_global_load_lds((gas_p)(srcK[i] + (size_t)nk0 * NDK),
                                                 (las_p)(&Ks[cur ^ 1][0] + (wave*4 + i)*512), 16, 0, 0);
            #pragma unroll
            for (int i = 0; i < 2; ++i)
                __builtin_amdgcn_global_load_lds((gas_p)(srcV[i] + nk0),
                                                 (las_p)(&Vs[cur ^ 1][0] + (wave*2 + i)*512), 16, 0, 0);
            asm volatile("s_waitcnt vmcnt(6)" ::: "memory");
        } else {
            asm volatile("s_waitcnt vmcnt(0)" ::: "memory");
        }
        __builtin_amdgcn_sched_barrier(0);
        __builtin_amdgcn_s_barrier();
        __builtin_amdgcn_sched_barrier(0);

        // ---- swapped QK^T: sacc[nt] = S[kv=16nt+4g+j][q=c] ----
        f32x4 sacc[4];
        #pragma unroll
        for (int nt = 0; nt < 4; ++nt) sacc[nt] = (f32x4){0.f, 0.f, 0.f, 0.f};
        __builtin_amdgcn_s_setprio(1);
        #pragma unroll
        for (int s = 0; s < 4; ++s) {
            #pragma unroll
            for (int nt = 0; nt < 4; ++nt) {
                const bf16x8 ka = *(const bf16x8*)((const char*)&Ks[cur][0]
                                    + (nt*16 + c)*256 + ((64*s + 16*g) ^ ((c & 7) << 4)));
                sacc[nt] = __builtin_amdgcn_mfma_f32_16x16x32_bf16(ka, qb[s], sacc[nt], 0, 0, 0);
            }
        }
        __builtin_amdgcn_s_setprio(0);

        // ---- per-lane softmax for q-row c (exp2 domain), defer-max ----
        float tmax = sacc[0][0];
        #pragma unroll
        for (int nt = 0; nt < 4; ++nt)
            #pragma unroll
            for (int j = 0; j < 4; ++j) tmax = fmaxf(tmax, sacc[nt][j]);
        tmax = fmaxf(tmax, __shfl_xor(tmax, 16, 64));
        tmax = fmaxf(tmax, __shfl_xor(tmax, 32, 64));

        const bool noskip = !__all(tmax - mrun <= 11.0f);
        float corr = 1.0f;
        if (noskip) {
            const float mnew = fmaxf(mrun, tmax);
            corr = exp2f(mrun - mnew);
            mrun = mnew;
        }

        float psum = 0.f;
        #pragma unroll
        for (int nt = 0; nt < 4; ++nt) {
            float p0 = exp2f(sacc[nt][0] - mrun);
            float p1 = exp2f(sacc[nt][1] - mrun);
            float p2 = exp2f(sacc[nt][2] - mrun);
            float p3 = exp2f(sacc[nt][3] - mrun);
            psum += (p0 + p1) + (p2 + p3);
            ushort4 pk4;
            pk4.x = f2bf(p0); pk4.y = f2bf(p1); pk4.z = f2bf(p2); pk4.w = f2bf(p3);
            *(ushort4*)((char*)&Ps[wave][0] + c*128 + ((32*nt + 8*g) ^ ((c & 7) << 4))) = pk4;
        }
        psum += __shfl_xor(psum, 16, 64);
        psum += __shfl_xor(psum, 32, 64);

        if (noskip) {
            lrun = lrun * corr + psum;
            float corr4[4];
            #pragma unroll
            for (int j = 0; j < 4; ++j) corr4[j] = __shfl(corr, 4*g + j, 64);
            #pragma unroll
            for (int nt = 0; nt < 4; ++nt)
                #pragma unroll
                for (int j = 0; j < 4; ++j) oacc[nt][j] *= corr4[j];
        } else {
            lrun += psum;
        }

        // ---- PV: O += P @ V^T-tiles ----
        __builtin_amdgcn_s_setprio(1);
        #pragma unroll
        for (int s = 0; s < 2; ++s) {
            const bf16x8 pa = *(const bf16x8*)((const char*)&Ps[wave][0]
                                + c*128 + ((64*s + 16*g) ^ ((c & 7) << 4)));
            #pragma unroll
            for (int nt = 0; nt < 4; ++nt) {
                const bf16x8 vb = *(const bf16x8*)((const char*)&Vs[cur][0]
                                    + (nt*16 + c)*128 + ((64*s + 16*g) ^ ((c & 7) << 4)));
                oacc[nt] = __builtin_amdgcn_mfma_f32_16x16x32_bf16(pa, vb, oacc[nt], 0, 0, 0);
            }
        }
        __builtin_amdgcn_s_setprio(0);
        __builtin_amdgcn_sched_barrier(0);
        __builtin_amdgcn_s_barrier();       // raw: next tile's loads issue after this
        __builtin_amdgcn_sched_barrier(0);
    }

    // ---- epilogue: hi/lo split of O/l -> (B*S, D) ----
    const int b  = bh >> 4;
    const int hh = bh & 15;
    float linv[4];
    #pragma unroll
    for (int j = 0; j < 4; ++j) linv[j] = 1.0f / __shfl(lrun, 4*g + j, 64);
    #pragma unroll
    for (int j = 0; j < 4; ++j) {
        const int srow = q0 + wave*16 + 4*g + j;
        #pragma unroll
        for (int nt = 0; nt < 4; ++nt) {
            const float val = oacc[nt][j] * linv[j];
            const u16 hb = f2bf(val);
            const u16 lb = f2bf(val - bf2f(hb));
            const size_t o = (size_t)(b*NS + srow)*ND + hh*NDK + nt*16 + c;
            OH[o] = hb;
            OL[o] = lb;
        }
    }
}

extern "C" void kernel_launch(void* const* d_in, const int* in_sizes, int n_in,
                              void* d_out, int out_size, void* d_ws, size_t ws_size,
                              hipStream_t stream)
{
    const float* xr = (const float*)d_in[0];
    const float* xi = (const float*)d_in[1];
    const float* Wq = (const float*)d_in[2];
    const float* bq = (const float*)d_in[3];
    const float* Wk = (const float*)d_in[4];
    const float* bk = (const float*)d_in[5];
    const float* Wv = (const float*)d_in[6];
    const float* bv = (const float*)d_in[7];
    const float* Wo = (const float*)d_in[8];
    const float* bo = (const float*)d_in[9];
    float* out = (float*)d_out;

    u16* ws = (u16*)d_ws;
    const size_t PL = (size_t)NM * ND;           // 4,194,304 elems
    u16* XH = ws;                                 // stacked [xr;xi] hi, 2*PL
    u16* WT = ws + 2*PL;                          // 4 x (hi 1M + lo 1M)
    u16* QP = WT + 8 * 1048576;
    u16* Qr = QP;          u16* Qi = QP + PL;
    u16* Kr = QP + 2*PL;   u16* Ki = QP + 3*PL;
    u16* Vv = QP + 4*PL;   u16* Vt = QP + 5*PL;
    u16* OH = ws;                                 // alias dead XH region
    u16* OL = ws + PL;

    conv_x<<<2*PL/(256*4), 256, 0, stream>>>(xr, xi, XH);
    conv_wt<<<dim3(ND/64, ND/64, 4), 256, 0, stream>>>(Wq, Wk, Wv, Wo, WT);

    u16* WTq = WT;  u16* WTk = WT + 2097152;  u16* WTv = WT + 2*2097152;  u16* WTo = WT + 3*2097152;

    // Q scaled by (1/8)*log2e for exp2-domain softmax
    gemm_split<2><<<dim3(ND/128, 2*NM/128), 256, 0, stream>>>(XH, XH, WTq, WTq + 1048576, bq, Qr, Qi, nullptr, 0, 0.125f * LOG2E);
    gemm_split<2><<<dim3(ND/128, 2*NM/128), 256, 0, stream>>>(XH, XH, WTk, WTk + 1048576, bk, Kr, Ki, nullptr, 0, 1.0f);
    gemm_split<2><<<dim3(ND/128,   NM/128), 256, 0, stream>>>(XH, XH, WTv, WTv + 1048576, bv, Vv, Vv, nullptr, 0, 1.0f);

    vt_trans<<<dim3(NS/64, NB*NH), 256, 0, stream>>>(Vv, Vt);

    attn_mfma<<<dim3(NS/64, NB*NH), 256, 0, stream>>>(Qr, Qi, Kr, Ki, Vt, OH, OL);

    gemm_split<3><<<dim3(ND/128,   NM/128), 256, 0, stream>>>(OH, OL, WTo, WTo + 1048576, bo, nullptr, nullptr, out, 1, 1.0f);
}

// Round 10
// 307.020 us; speedup vs baseline: 6.9272x; 1.0091x over previous
//
#include <hip/hip_runtime.h>

#define NB 2
#define NS 2048
#define ND 1024
#define NH 16
#define NDK 64
#define NM (NB*NS)   // 4096

typedef unsigned short u16;
typedef unsigned int u32;
typedef short bf16x8 __attribute__((ext_vector_type(8)));
typedef float f32x4 __attribute__((ext_vector_type(4)));
typedef const __attribute__((address_space(1))) void* gas_p;
typedef __attribute__((address_space(3))) void* las_p;

#define LOG2E 1.4426950408889634f

__device__ __forceinline__ u16 f2bf(float f) {
    unsigned u = __builtin_bit_cast(unsigned, f);
    u += 0x7fffu + ((u >> 16) & 1u);         // RTNE
    return (u16)(u >> 16);
}
__device__ __forceinline__ float bf2f(u16 h) {
    return __builtin_bit_cast(float, (unsigned)h << 16);
}
__device__ __forceinline__ u32 cvt_pk_bf16(float a, float b) {
    u32 r;
    asm("v_cvt_pk_bf16_f32 %0, %1, %2" : "=v"(r) : "v"(a), "v"(b));
    return r;   // [15:0]=bf16(a), [31:16]=bf16(b)
}

// ============ conv_x: xr,xi fp32 -> stacked hi bf16 plane [xr; xi] ============
__global__ __launch_bounds__(256)
void conv_x(const float* __restrict__ xr, const float* __restrict__ xi,
            u16* __restrict__ XH)
{
    const size_t gid = (size_t)blockIdx.x * 256 + threadIdx.x;
    const size_t PQ = (size_t)NM * ND / 4;
    const int p = gid >= PQ;
    const size_t off = (gid - (p ? PQ : 0)) * 4;
    const float4 v = *(const float4*)&((p ? xi : xr)[off]);
    const size_t d = (size_t)p * NM * ND + off;
    float vs[4] = {v.x, v.y, v.z, v.w};
    ushort4 h;
    u16* hp = (u16*)&h;
    #pragma unroll
    for (int j = 0; j < 4; ++j) hp[j] = f2bf(vs[j]);
    *(ushort4*)&XH[d] = h;
}

// ============ conv_wt: W (K x N fp32) -> W^T hi/lo bf16 (N x K) ============
__global__ __launch_bounds__(256)
void conv_wt(const float* __restrict__ W0, const float* __restrict__ W1,
             const float* __restrict__ W2, const float* __restrict__ W3,
             u16* __restrict__ WT)
{
    __shared__ float tls[64][68];
    const int z = blockIdx.z;
    const float* W = z == 0 ? W0 : z == 1 ? W1 : z == 2 ? W2 : W3;
    u16* dh = WT + (size_t)z * 2097152;
    u16* dl = dh + 1048576;
    const int kt0 = blockIdx.y * 64;
    const int nt0 = blockIdx.x * 64;
    const int tid = threadIdx.x;

    {
        const int kk = tid >> 4;
        const int nn = (tid & 15) * 4;
        #pragma unroll
        for (int i = 0; i < 4; ++i) {
            const float4 v = *(const float4*)&W[(size_t)(kt0 + kk + 16*i) * ND + nt0 + nn];
            tls[kk + 16*i][nn] = v.x; tls[kk + 16*i][nn+1] = v.y;
            tls[kk + 16*i][nn+2] = v.z; tls[kk + 16*i][nn+3] = v.w;
        }
    }
    __syncthreads();

    const int n  = tid >> 2;
    const int kc = (tid & 3) * 16;
    u16 hb[16], lb[16];
    #pragma unroll
    for (int k = 0; k < 16; ++k) {
        const float v = tls[kc + k][n];
        hb[k] = f2bf(v);
        lb[k] = f2bf(v - bf2f(hb[k]));
    }
    #pragma unroll
    for (int half = 0; half < 2; ++half) {
        *(bf16x8*)&dh[(size_t)(nt0 + n) * ND + kt0 + kc + 8*half] = *(bf16x8*)&hb[8*half];
        *(bf16x8*)&dl[(size_t)(nt0 + n) * ND + kt0 + kc + 8*half] = *(bf16x8*)&lb[8*half];
    }
}

// ============ vt_trans: Vv [bh][s][dk] -> Vt [bh][dk][s] ============
__global__ __launch_bounds__(256)
void vt_trans(const u16* __restrict__ Vv, u16* __restrict__ Vt)
{
    __shared__ u16 T[64][72];
    const int bh = blockIdx.y;
    const int s0 = blockIdx.x * 64;
    const int tid = threadIdx.x;
    const size_t base = (size_t)bh * NS * NDK;

    const int r = tid >> 3, cb = (tid & 7) * 8;
    #pragma unroll
    for (int i = 0; i < 2; ++i) {
        const int row = r + 32*i;
        *(bf16x8*)&T[row][cb] = *(const bf16x8*)(Vv + base + (size_t)(s0 + row) * NDK + cb);
    }
    __syncthreads();

    const int dk = tid >> 2, sb = (tid & 3) * 16;
    u16 buf[16];
    #pragma unroll
    for (int k = 0; k < 16; ++k) buf[k] = T[sb + k][dk];
    *(bf16x8*)(Vt + base + (size_t)dk * NS + s0 + sb)     = *(bf16x8*)&buf[0];
    *(bf16x8*)(Vt + base + (size_t)dk * NS + s0 + sb + 8) = *(bf16x8*)&buf[8];
}

// ============ split-precision bf16 MFMA GEMM, dbuf gld_lds pipeline ============
// TERMS=2: C = Ah@Bh + Ah@Bl (A single bf16) — for Q/K/V (output bf16 anyway).
// TERMS=3: + Al@Bh — for the fp32 final projection.
template<int TERMS>
__global__ __launch_bounds__(256)
void gemm_split(const u16* __restrict__ Ah, const u16* __restrict__ Al,
                const u16* __restrict__ Bh, const u16* __restrict__ Bl,
                const float* __restrict__ bias,
                u16* __restrict__ Yr, u16* __restrict__ Yi,
                float* __restrict__ Yf, const int mode, const float scale)
{
    constexpr int NP = TERMS + 1;            // planes: AH, BH, BL [, AL]
    __shared__ u16 LDS[2][NP][4096];         // [buf][plane][128*32]

    const int tid  = threadIdx.x;
    const int wave = tid >> 6;
    const int lane = tid & 63;
    const int g = lane >> 4;
    const int c = lane & 15;
    const int wm = wave >> 1;
    const int wn = wave & 1;

    const int nbx = gridDim.x;
    const int nwg = nbx * gridDim.y;
    const int wgid = blockIdx.y * nbx + blockIdx.x;
    const int swz = (wgid & 7) * (nwg >> 3) + (wgid >> 3);
    const int row0 = (swz / nbx) * 128;
    const int col0 = (swz % nbx) * 128;

    // per-chunk staging maps (NP*2 chunks of 1KB per wave-set)
    const int lr = lane >> 2;
    const int lq = lane & 3;
    const u16* srcs[8];
    int doffs[8];
    #pragma unroll
    for (int i = 0; i < NP*2; ++i) {
        const int ci = wave * (NP*2) + i;
        const int p = ci >> 3;
        const int o = ci & 7;
        const u16* pl = (p == 0) ? Ah : (p == 1) ? Bh : (p == 2) ? Bl : Al;
        const int rb = (p == 0 || p == 3) ? row0 : col0;
        srcs[i] = pl + (size_t)(rb + o*16 + lr) * ND + lq*8;
        doffs[i] = p*4096 + o*512;
    }

    f32x4 acc[4][4];
    #pragma unroll
    for (int i = 0; i < 4; ++i)
        #pragma unroll
        for (int j = 0; j < 4; ++j)
            acc[i][j] = (f32x4){0.f, 0.f, 0.f, 0.f};

    // prologue: stage k-tile 0 into buf 0
    #pragma unroll
    for (int i = 0; i < NP*2; ++i)
        __builtin_amdgcn_global_load_lds((gas_p)srcs[i],
                                         (las_p)(&LDS[0][0][0] + doffs[i]), 16, 0, 0);

    for (int t = 0; t < 32; ++t) {
        if (t < 31) {
            u16* ldst = &LDS[(t + 1) & 1][0][0];
            #pragma unroll
            for (int i = 0; i < NP*2; ++i)
                __builtin_amdgcn_global_load_lds((gas_p)(srcs[i] + (size_t)(t + 1) * 32),
                                                 (las_p)(ldst + doffs[i]), 16, 0, 0);
            if constexpr (TERMS == 2) asm volatile("s_waitcnt vmcnt(6)" ::: "memory");
            else                      asm volatile("s_waitcnt vmcnt(8)" ::: "memory");
        } else {
            asm volatile("s_waitcnt vmcnt(0)" ::: "memory");
        }
        __builtin_amdgcn_sched_barrier(0);
        __builtin_amdgcn_s_barrier();
        __builtin_amdgcn_sched_barrier(0);

        const u16* AsH = &LDS[t & 1][0][0];
        const u16* BsH = &LDS[t & 1][1][0];
        const u16* BsL = &LDS[t & 1][2][0];

        bf16x8 a_h[4], b_h[4], b_l[4], a_l[4];
        #pragma unroll
        for (int f = 0; f < 4; ++f) {
            const int ar = wm*64 + f*16 + c;
            const int br = wn*64 + f*16 + c;
            a_h[f] = *(const bf16x8*)&AsH[ar*32 + 8*g];
            b_h[f] = *(const bf16x8*)&BsH[br*32 + 8*g];
            b_l[f] = *(const bf16x8*)&BsL[br*32 + 8*g];
            if constexpr (TERMS == 3)
                a_l[f] = *(const bf16x8*)&LDS[t & 1][3][ar*32 + 8*g];
        }
        __builtin_amdgcn_s_setprio(1);
        #pragma unroll
        for (int fm = 0; fm < 4; ++fm) {
            #pragma unroll
            for (int fn = 0; fn < 4; ++fn) {
                acc[fm][fn] = __builtin_amdgcn_mfma_f32_16x16x32_bf16(a_h[fm], b_h[fn], acc[fm][fn], 0, 0, 0);
                acc[fm][fn] = __builtin_amdgcn_mfma_f32_16x16x32_bf16(a_h[fm], b_l[fn], acc[fm][fn], 0, 0, 0);
                if constexpr (TERMS == 3)
                    acc[fm][fn] = __builtin_amdgcn_mfma_f32_16x16x32_bf16(a_l[fm], b_h[fn], acc[fm][fn], 0, 0, 0);
            }
        }
        __builtin_amdgcn_s_setprio(0);
        __builtin_amdgcn_sched_barrier(0);
        __builtin_amdgcn_s_barrier();
        __builtin_amdgcn_sched_barrier(0);
    }

    #pragma unroll
    for (int fm = 0; fm < 4; ++fm) {
        #pragma unroll
        for (int fn = 0; fn < 4; ++fn) {
            #pragma unroll
            for (int j = 0; j < 4; ++j) {
                const int m = row0 + wm*64 + fm*16 + 4*g + j;
                const int n = col0 + wn*64 + fn*16 + c;
                const float v = acc[fm][fn][j];
                if (mode == 0) {
                    const int plane = m >> 12;
                    const int mm = m & 4095;
                    const int b  = mm >> 11;
                    const int s  = mm & (NS - 1);
                    const int hh = n >> 6;
                    const int dk = n & 63;
                    const float val = v*scale + (plane == 0 ? bias[n]*scale : 0.f);
                    (plane ? Yi : Yr)[(((size_t)(b*NH + hh) * NS) + s) * NDK + dk] = f2bf(val);
                } else {
                    Yf[(size_t)m * ND + n] = v + bias[n];
                }
            }
        }
    }
}

// ============ MFMA flash attention: K single-buffer / V double-buffer,
// gld_lds staging (pre-swizzled source), cvt_pk softmax, defer-max ============
__global__ __launch_bounds__(256)
void attn_mfma(const u16* __restrict__ Qr, const u16* __restrict__ Qi,
               const u16* __restrict__ Kr, const u16* __restrict__ Ki,
               const u16* __restrict__ Vt,
               u16* __restrict__ OH, u16* __restrict__ OL)
{
    __shared__ __align__(16) u16 Ks[8192];      // [kv64][128], XOR-swz content (single buf)
    __shared__ __align__(16) u16 Vs[2][4096];   // [buf][dk64][64], XOR-swz content
    __shared__ __align__(16) u16 Ps[4][1024];   // per-wave P[q16][kv64], XOR-swz

    const int tid  = threadIdx.x;
    const int wave = tid >> 6;
    const int lane = tid & 63;
    const int g = lane >> 4;
    const int c = lane & 15;

    const int nbx = gridDim.x;
    const int nwg = nbx * gridDim.y;
    const int wgid = blockIdx.y * nbx + blockIdx.x;
    const int swz = (wgid & 7) * (nwg >> 3) + (wgid >> 3);
    const int bh = swz / nbx;
    const int q0 = (swz % nbx) * 64;
    const size_t base = (size_t)bh * NS * NDK;

    // Q' fragments (B-operand): lane (g,c) holds Q'[q=c][k=32s+8g+b]
    bf16x8 qb[4];
    {
        const u16* qr = Qr + base + (size_t)(q0 + wave*16 + c) * NDK;
        const u16* qi = Qi + base + (size_t)(q0 + wave*16 + c) * NDK;
        #pragma unroll
        for (int s = 0; s < 2; ++s) {
            qb[s] = *(const bf16x8*)(qr + 32*s + 8*g);
            const bf16x8 t = *(const bf16x8*)(qi + 32*s + 8*g);
            bf16x8 f;
            #pragma unroll
            for (int j = 0; j < 8; ++j) f[j] = t[j] ^ (short)0x8000;
            qb[2+s] = f;
        }
    }

    // staging maps: pre-swizzled global source + linear LDS dest (rule #21)
    const int slot = lane & 15;           // K: 16B slot in 256B row
    const int rloc = lane >> 4;           // K: row within 4-row chunk
    const u16* kplane = (slot < 8 ? Kr : Ki) + base;
    const u16* srcK[4];
    #pragma unroll
    for (int i = 0; i < 4; ++i) {
        const int row = (wave*4 + i)*4 + rloc;
        srcK[i] = kplane + (size_t)row * NDK + ((slot ^ (row & 7)) & 7) * 8;
    }
    const int r8 = lane >> 3, sl = lane & 7;   // V: 8 rows x 8 slots per chunk
    const u16* vbase = Vt + base;
    const u16* srcV[2];
    #pragma unroll
    for (int i = 0; i < 2; ++i) {
        const int dk = (wave*2 + i)*8 + r8;
        srcV[i] = vbase + (size_t)dk * NS + ((sl ^ r8) & 7) * 8;
    }

    f32x4 oacc[4];
    #pragma unroll
    for (int nt = 0; nt < 4; ++nt) oacc[nt] = (f32x4){0.f, 0.f, 0.f, 0.f};
    float mrun = -1e30f, lrun = 0.f;      // state for q-row = c

    // prologue: stage tile 0 (K -> Ks, V -> Vs[0])
    #pragma unroll
    for (int i = 0; i < 4; ++i)
        __builtin_amdgcn_global_load_lds((gas_p)srcK[i],
                                         (las_p)(&Ks[0] + (wave*4 + i)*512), 16, 0, 0);
    #pragma unroll
    for (int i = 0; i < 2; ++i)
        __builtin_amdgcn_global_load_lds((gas_p)srcV[i],
                                         (las_p)(&Vs[0][0] + (wave*2 + i)*512), 16, 0, 0);
    asm volatile("s_waitcnt vmcnt(0)" ::: "memory");
    __builtin_amdgcn_sched_barrier(0);
    __builtin_amdgcn_s_barrier();
    __builtin_amdgcn_sched_barrier(0);

    #define NTI (NS/64)
    for (int kt = 0; kt < NTI; ++kt) {
        const int cur = kt & 1;

        // ---- swapped QK^T: sacc[nt] = S[kv=16nt+4g+j][q=c] ----
        f32x4 sacc[4];
        #pragma unroll
        for (int nt = 0; nt < 4; ++nt) sacc[nt] = (f32x4){0.f, 0.f, 0.f, 0.f};
        __builtin_amdgcn_s_setprio(1);
        #pragma unroll
        for (int s = 0; s < 4; ++s) {
            #pragma unroll
            for (int nt = 0; nt < 4; ++nt) {
                const bf16x8 ka = *(const bf16x8*)((const char*)&Ks[0]
                                    + (nt*16 + c)*256 + ((64*s + 16*g) ^ ((c & 7) << 4)));
                sacc[nt] = __builtin_amdgcn_mfma_f32_16x16x32_bf16(ka, qb[s], sacc[nt], 0, 0, 0);
            }
        }
        __builtin_amdgcn_s_setprio(0);
        __builtin_amdgcn_sched_barrier(0);
        __builtin_amdgcn_s_barrier();       // B1: all waves done reading Ks
        __builtin_amdgcn_sched_barrier(0);

        // ---- issue next tile's loads (land during softmax+PV) ----
        if (kt + 1 < NTI) {
            const int nk0 = (kt + 1) * 64;
            #pragma unroll
            for (int i = 0; i < 4; ++i)
                __builtin_amdgcn_global_load_lds((gas_p)(srcK[i] + (size_t)nk0 * NDK),
                                                 (las_p)(&Ks[0] + (wave*4 + i)*512), 16, 0, 0);
            #pragma unroll
            for (int i = 0; i < 2; ++i)
                __builtin_amdgcn_global_load_lds((gas_p)(srcV[i] + nk0),
                                                 (las_p)(&Vs[cur ^ 1][0] + (wave*2 + i)*512), 16, 0, 0);
        }

        // ---- per-lane softmax for q-row c (exp2 domain), defer-max ----
        float m0 = fmaxf(fmaxf(sacc[0][0], sacc[0][1]), sacc[0][2]);
        float m1 = fmaxf(fmaxf(sacc[0][3], sacc[1][0]), sacc[1][1]);
        float m2 = fmaxf(fmaxf(sacc[1][2], sacc[1][3]), sacc[2][0]);
        float m3 = fmaxf(fmaxf(sacc[2][1], sacc[2][2]), sacc[2][3]);
        float m4 = fmaxf(fmaxf(sacc[3][0], sacc[3][1]), sacc[3][2]);
        float tmax = fmaxf(fmaxf(fmaxf(m0, m1), m2), fmaxf(fmaxf(m3, m4), sacc[3][3]));
        tmax = fmaxf(tmax, __shfl_xor(tmax, 16, 64));
        tmax = fmaxf(tmax, __shfl_xor(tmax, 32, 64));

        const bool noskip = !__all(tmax - mrun <= 11.0f);
        float corr = 1.0f;
        if (noskip) {
            const float mnew = fmaxf(mrun, tmax);
            corr = exp2f(mrun - mnew);
            mrun = mnew;
        }

        float psum = 0.f;
        #pragma unroll
        for (int nt = 0; nt < 4; ++nt) {
            float p0 = exp2f(sacc[nt][0] - mrun);
            float p1 = exp2f(sacc[nt][1] - mrun);
            float p2 = exp2f(sacc[nt][2] - mrun);
            float p3 = exp2f(sacc[nt][3] - mrun);
            psum += (p0 + p1) + (p2 + p3);
            uint2 pk;
            pk.x = cvt_pk_bf16(p0, p1);
            pk.y = cvt_pk_bf16(p2, p3);
            *(uint2*)((char*)&Ps[wave][0] + c*128 + ((32*nt + 8*g) ^ ((c & 7) << 4))) = pk;
        }
        psum += __shfl_xor(psum, 16, 64);
        psum += __shfl_xor(psum, 32, 64);

        if (noskip) {
            lrun = lrun * corr + psum;
            float corr4[4];
            #pragma unroll
            for (int j = 0; j < 4; ++j) corr4[j] = __shfl(corr, 4*g + j, 64);
            #pragma unroll
            for (int nt = 0; nt < 4; ++nt)
                #pragma unroll
                for (int j = 0; j < 4; ++j) oacc[nt][j] *= corr4[j];
        } else {
            lrun += psum;
        }

        // ---- PV: O += P @ V^T-tiles ----
        __builtin_amdgcn_s_setprio(1);
        #pragma unroll
        for (int s = 0; s < 2; ++s) {
            const bf16x8 pa = *(const bf16x8*)((const char*)&Ps[wave][0]
                                + c*128 + ((64*s + 16*g) ^ ((c & 7) << 4)));
            #pragma unroll
            for (int nt = 0; nt < 4; ++nt) {
                const bf16x8 vb = *(const bf16x8*)((const char*)&Vs[cur][0]
                                    + (nt*16 + c)*128 + ((64*s + 16*g) ^ ((c & 7) << 4)));
                oacc[nt] = __builtin_amdgcn_mfma_f32_16x16x32_bf16(pa, vb, oacc[nt], 0, 0, 0);
            }
        }
        __builtin_amdgcn_s_setprio(0);

        if (kt + 1 < NTI) {
            asm volatile("s_waitcnt vmcnt(0)" ::: "memory");   // next K+V landed
            __builtin_amdgcn_sched_barrier(0);
            __builtin_amdgcn_s_barrier();   // B2
            __builtin_amdgcn_sched_barrier(0);
        }
    }

    // ---- epilogue: hi/lo split of O/l -> (B*S, D) ----
    const int b  = bh >> 4;
    const int hh = bh & 15;
    float linv[4];
    #pragma unroll
    for (int j = 0; j < 4; ++j) linv[j] = 1.0f / __shfl(lrun, 4*g + j, 64);
    #pragma unroll
    for (int j = 0; j < 4; ++j) {
        const int srow = q0 + wave*16 + 4*g + j;
        #pragma unroll
        for (int nt = 0; nt < 4; ++nt) {
            const float val = oacc[nt][j] * linv[j];
            const u16 hb = f2bf(val);
            const u16 lb = f2bf(val - bf2f(hb));
            const size_t o = (size_t)(b*NS + srow)*ND + hh*NDK + nt*16 + c;
            OH[o] = hb;
            OL[o] = lb;
        }
    }
}

extern "C" void kernel_launch(void* const* d_in, const int* in_sizes, int n_in,
                              void* d_out, int out_size, void* d_ws, size_t ws_size,
                              hipStream_t stream)
{
    const float* xr = (const float*)d_in[0];
    const float* xi = (const float*)d_in[1];
    const float* Wq = (const float*)d_in[2];
    const float* bq = (const float*)d_in[3];
    const float* Wk = (const float*)d_in[4];
    const float* bk = (const float*)d_in[5];
    const float* Wv = (const float*)d_in[6];
    const float* bv = (const float*)d_in[7];
    const float* Wo = (const float*)d_in[8];
    const float* bo = (const float*)d_in[9];
    float* out = (float*)d_out;

    u16* ws = (u16*)d_ws;
    const size_t PL = (size_t)NM * ND;           // 4,194,304 elems
    u16* XH = ws;                                 // stacked [xr;xi] hi, 2*PL
    u16* WT = ws + 2*PL;                          // 4 x (hi 1M + lo 1M)
    u16* QP = WT + 8 * 1048576;
    u16* Qr = QP;          u16* Qi = QP + PL;
    u16* Kr = QP + 2*PL;   u16* Ki = QP + 3*PL;
    u16* Vv = QP + 4*PL;   u16* Vt = QP + 5*PL;
    u16* OH = ws;                                 // alias dead XH region
    u16* OL = ws + PL;

    conv_x<<<2*PL/(256*4), 256, 0, stream>>>(xr, xi, XH);
    conv_wt<<<dim3(ND/64, ND/64, 4), 256, 0, stream>>>(Wq, Wk, Wv, Wo, WT);

    u16* WTq = WT;  u16* WTk = WT + 2097152;  u16* WTv = WT + 2*2097152;  u16* WTo = WT + 3*2097152;

    // Q scaled by (1/8)*log2e for exp2-domain softmax
    gemm_split<2><<<dim3(ND/128, 2*NM/128), 256, 0, stream>>>(XH, XH, WTq, WTq + 1048576, bq, Qr, Qi, nullptr, 0, 0.125f * LOG2E);
    gemm_split<2><<<dim3(ND/128, 2*NM/128), 256, 0, stream>>>(XH, XH, WTk, WTk + 1048576, bk, Kr, Ki, nullptr, 0, 1.0f);
    gemm_split<2><<<dim3(ND/128,   NM/128), 256, 0, stream>>>(XH, XH, WTv, WTv + 1048576, bv, Vv, Vv, nullptr, 0, 1.0f);

    vt_trans<<<dim3(NS/64, NB*NH), 256, 0, stream>>>(Vv, Vt);

    attn_mfma<<<dim3(NS/64, NB*NH), 256, 0, stream>>>(Qr, Qi, Kr, Ki, Vt, OH, OL);

    gemm_split<3><<<dim3(ND/128,   NM/128), 256, 0, stream>>>(OH, OL, WTo, WTo + 1048576, bo, nullptr, nullptr, out, 1, 1.0f);
}

// Round 11
// 271.116 us; speedup vs baseline: 7.8446x; 1.1324x over previous
//
#include <hip/hip_runtime.h>

#define NB 2
#define NS 2048
#define ND 1024
#define NH 16
#define NDK 64
#define NM (NB*NS)   // 4096

typedef unsigned short u16;
typedef unsigned int u32;
typedef short bf16x8 __attribute__((ext_vector_type(8)));
typedef float f32x4 __attribute__((ext_vector_type(4)));
typedef const __attribute__((address_space(1))) void* gas_p;
typedef __attribute__((address_space(3))) void* las_p;

#define LOG2E 1.4426950408889634f

__device__ __forceinline__ u16 f2bf(float f) {
    unsigned u = __builtin_bit_cast(unsigned, f);
    u += 0x7fffu + ((u >> 16) & 1u);         // RTNE
    return (u16)(u >> 16);
}
__device__ __forceinline__ float bf2f(u16 h) {
    return __builtin_bit_cast(float, (unsigned)h << 16);
}
__device__ __forceinline__ u32 cvt_pk_bf16(float a, float b) {
    u32 r;
    asm("v_cvt_pk_bf16_f32 %0, %1, %2" : "=v"(r) : "v"(a), "v"(b));
    return r;   // [15:0]=bf16(a), [31:16]=bf16(b)
}

// ============ conv_x: xr,xi fp32 -> stacked hi bf16 plane [xr; xi] ============
__global__ __launch_bounds__(256)
void conv_x(const float* __restrict__ xr, const float* __restrict__ xi,
            u16* __restrict__ XH)
{
    const size_t gid = (size_t)blockIdx.x * 256 + threadIdx.x;
    const size_t PQ = (size_t)NM * ND / 4;
    const int p = gid >= PQ;
    const size_t off = (gid - (p ? PQ : 0)) * 4;
    const float4 v = *(const float4*)&((p ? xi : xr)[off]);
    const size_t d = (size_t)p * NM * ND + off;
    float vs[4] = {v.x, v.y, v.z, v.w};
    ushort4 h;
    u16* hp = (u16*)&h;
    #pragma unroll
    for (int j = 0; j < 4; ++j) hp[j] = f2bf(vs[j]);
    *(ushort4*)&XH[d] = h;
}

// ============ conv_wt: W (K x N fp32) -> W^T hi (all) + lo (Wo only) ============
__global__ __launch_bounds__(256)
void conv_wt(const float* __restrict__ W0, const float* __restrict__ W1,
             const float* __restrict__ W2, const float* __restrict__ W3,
             u16* __restrict__ WT)
{
    __shared__ float tls[64][68];
    const int z = blockIdx.z;
    const float* W = z == 0 ? W0 : z == 1 ? W1 : z == 2 ? W2 : W3;
    u16* dh = WT + (size_t)z * 2097152;
    u16* dl = dh + 1048576;
    const int kt0 = blockIdx.y * 64;
    const int nt0 = blockIdx.x * 64;
    const int tid = threadIdx.x;

    {
        const int kk = tid >> 4;
        const int nn = (tid & 15) * 4;
        #pragma unroll
        for (int i = 0; i < 4; ++i) {
            const float4 v = *(const float4*)&W[(size_t)(kt0 + kk + 16*i) * ND + nt0 + nn];
            tls[kk + 16*i][nn] = v.x; tls[kk + 16*i][nn+1] = v.y;
            tls[kk + 16*i][nn+2] = v.z; tls[kk + 16*i][nn+3] = v.w;
        }
    }
    __syncthreads();

    const int n  = tid >> 2;
    const int kc = (tid & 3) * 16;
    u16 hb[16], lb[16];
    #pragma unroll
    for (int k = 0; k < 16; ++k) {
        const float v = tls[kc + k][n];
        hb[k] = f2bf(v);
        lb[k] = f2bf(v - bf2f(hb[k]));
    }
    #pragma unroll
    for (int half = 0; half < 2; ++half)
        *(bf16x8*)&dh[(size_t)(nt0 + n) * ND + kt0 + kc + 8*half] = *(bf16x8*)&hb[8*half];
    if (z == 3) {   // lo plane needed only for the 3-term final projection
        #pragma unroll
        for (int half = 0; half < 2; ++half)
            *(bf16x8*)&dl[(size_t)(nt0 + n) * ND + kt0 + kc + 8*half] = *(bf16x8*)&lb[8*half];
    }
}

// ============ vt_trans: Vv [bh][s][dk] -> Vt [bh][dk][s] ============
__global__ __launch_bounds__(256)
void vt_trans(const u16* __restrict__ Vv, u16* __restrict__ Vt)
{
    __shared__ u16 T[64][72];
    const int bh = blockIdx.y;
    const int s0 = blockIdx.x * 64;
    const int tid = threadIdx.x;
    const size_t base = (size_t)bh * NS * NDK;

    const int r = tid >> 3, cb = (tid & 7) * 8;
    #pragma unroll
    for (int i = 0; i < 2; ++i) {
        const int row = r + 32*i;
        *(bf16x8*)&T[row][cb] = *(const bf16x8*)(Vv + base + (size_t)(s0 + row) * NDK + cb);
    }
    __syncthreads();

    const int dk = tid >> 2, sb = (tid & 3) * 16;
    u16 buf[16];
    #pragma unroll
    for (int k = 0; k < 16; ++k) buf[k] = T[sb + k][dk];
    *(bf16x8*)(Vt + base + (size_t)dk * NS + s0 + sb)     = *(bf16x8*)&buf[0];
    *(bf16x8*)(Vt + base + (size_t)dk * NS + s0 + sb + 8) = *(bf16x8*)&buf[8];
}

// ============ bf16 MFMA GEMM, dbuf gld_lds pipeline ============
// TERMS=1: C = Ah@Bh                 — Q/K/V (outputs stored bf16 anyway).
// TERMS=3: C = Ah@Bh + Ah@Bl + Al@Bh — final fp32 projection.
template<int TERMS>
__global__ __launch_bounds__(256)
void gemm_split(const u16* __restrict__ Ah, const u16* __restrict__ Al,
                const u16* __restrict__ Bh, const u16* __restrict__ Bl,
                const float* __restrict__ bias,
                u16* __restrict__ Yr, u16* __restrict__ Yi,
                float* __restrict__ Yf, const int mode, const float scale)
{
    constexpr int NP = TERMS + 1;            // planes: AH, BH [, BL, AL]
    __shared__ u16 LDS[2][NP][4096];         // [buf][plane][128*32]

    const int tid  = threadIdx.x;
    const int wave = tid >> 6;
    const int lane = tid & 63;
    const int g = lane >> 4;
    const int c = lane & 15;
    const int wm = wave >> 1;
    const int wn = wave & 1;

    const int nbx = gridDim.x;
    const int nwg = nbx * gridDim.y;
    const int wgid = blockIdx.y * nbx + blockIdx.x;
    const int swz = (wgid & 7) * (nwg >> 3) + (wgid >> 3);
    const int row0 = (swz / nbx) * 128;
    const int col0 = (swz % nbx) * 128;

    // per-chunk staging maps (NP*2 chunks of 1KB per wave)
    const int lr = lane >> 2;
    const int lq = lane & 3;
    const u16* srcs[8];
    int doffs[8];
    #pragma unroll
    for (int i = 0; i < NP*2; ++i) {
        const int ci = wave * (NP*2) + i;
        const int p = ci >> 3;
        const int o = ci & 7;
        const u16* pl = (p == 0) ? Ah : (p == 1) ? Bh : (p == 2) ? Bl : Al;
        const int rb = (p == 0 || p == 3) ? row0 : col0;
        srcs[i] = pl + (size_t)(rb + o*16 + lr) * ND + lq*8;
        doffs[i] = p*4096 + o*512;
    }

    f32x4 acc[4][4];
    #pragma unroll
    for (int i = 0; i < 4; ++i)
        #pragma unroll
        for (int j = 0; j < 4; ++j)
            acc[i][j] = (f32x4){0.f, 0.f, 0.f, 0.f};

    // prologue: stage k-tile 0 into buf 0
    #pragma unroll
    for (int i = 0; i < NP*2; ++i)
        __builtin_amdgcn_global_load_lds((gas_p)srcs[i],
                                         (las_p)(&LDS[0][0][0] + doffs[i]), 16, 0, 0);

    for (int t = 0; t < 32; ++t) {
        if (t < 31) {
            u16* ldst = &LDS[(t + 1) & 1][0][0];
            #pragma unroll
            for (int i = 0; i < NP*2; ++i)
                __builtin_amdgcn_global_load_lds((gas_p)(srcs[i] + (size_t)(t + 1) * 32),
                                                 (las_p)(ldst + doffs[i]), 16, 0, 0);
            if constexpr (TERMS == 1) asm volatile("s_waitcnt vmcnt(4)" ::: "memory");
            else                      asm volatile("s_waitcnt vmcnt(8)" ::: "memory");
        } else {
            asm volatile("s_waitcnt vmcnt(0)" ::: "memory");
        }
        __builtin_amdgcn_sched_barrier(0);
        __builtin_amdgcn_s_barrier();
        __builtin_amdgcn_sched_barrier(0);

        const u16* AsH = &LDS[t & 1][0][0];
        const u16* BsH = &LDS[t & 1][1][0];

        bf16x8 a_h[4], b_h[4], b_l[4], a_l[4];
        #pragma unroll
        for (int f = 0; f < 4; ++f) {
            const int ar = wm*64 + f*16 + c;
            const int br = wn*64 + f*16 + c;
            a_h[f] = *(const bf16x8*)&AsH[ar*32 + 8*g];
            b_h[f] = *(const bf16x8*)&BsH[br*32 + 8*g];
            if constexpr (TERMS == 3) {
                b_l[f] = *(const bf16x8*)&LDS[t & 1][2][br*32 + 8*g];
                a_l[f] = *(const bf16x8*)&LDS[t & 1][3][ar*32 + 8*g];
            }
        }
        __builtin_amdgcn_s_setprio(1);
        #pragma unroll
        for (int fm = 0; fm < 4; ++fm) {
            #pragma unroll
            for (int fn = 0; fn < 4; ++fn) {
                acc[fm][fn] = __builtin_amdgcn_mfma_f32_16x16x32_bf16(a_h[fm], b_h[fn], acc[fm][fn], 0, 0, 0);
                if constexpr (TERMS == 3) {
                    acc[fm][fn] = __builtin_amdgcn_mfma_f32_16x16x32_bf16(a_h[fm], b_l[fn], acc[fm][fn], 0, 0, 0);
                    acc[fm][fn] = __builtin_amdgcn_mfma_f32_16x16x32_bf16(a_l[fm], b_h[fn], acc[fm][fn], 0, 0, 0);
                }
            }
        }
        __builtin_amdgcn_s_setprio(0);
        __builtin_amdgcn_sched_barrier(0);
        __builtin_amdgcn_s_barrier();
        __builtin_amdgcn_sched_barrier(0);
    }

    #pragma unroll
    for (int fm = 0; fm < 4; ++fm) {
        #pragma unroll
        for (int fn = 0; fn < 4; ++fn) {
            #pragma unroll
            for (int j = 0; j < 4; ++j) {
                const int m = row0 + wm*64 + fm*16 + 4*g + j;
                const int n = col0 + wn*64 + fn*16 + c;
                const float v = acc[fm][fn][j];
                if (mode == 0) {
                    const int plane = m >> 12;
                    const int mm = m & 4095;
                    const int b  = mm >> 11;
                    const int s  = mm & (NS - 1);
                    const int hh = n >> 6;
                    const int dk = n & 63;
                    const float val = v*scale + (plane == 0 ? bias[n]*scale : 0.f);
                    (plane ? Yi : Yr)[(((size_t)(b*NH + hh) * NS) + s) * NDK + dk] = f2bf(val);
                } else {
                    Yf[(size_t)m * ND + n] = v + bias[n];
                }
            }
        }
    }
}

// ============ MFMA flash attention (unchanged control from round 10) ============
__global__ __launch_bounds__(256)
void attn_mfma(const u16* __restrict__ Qr, const u16* __restrict__ Qi,
               const u16* __restrict__ Kr, const u16* __restrict__ Ki,
               const u16* __restrict__ Vt,
               u16* __restrict__ OH, u16* __restrict__ OL)
{
    __shared__ __align__(16) u16 Ks[8192];      // [kv64][128], XOR-swz content (single buf)
    __shared__ __align__(16) u16 Vs[2][4096];   // [buf][dk64][64], XOR-swz content
    __shared__ __align__(16) u16 Ps[4][1024];   // per-wave P[q16][kv64], XOR-swz

    const int tid  = threadIdx.x;
    const int wave = tid >> 6;
    const int lane = tid & 63;
    const int g = lane >> 4;
    const int c = lane & 15;

    const int nbx = gridDim.x;
    const int nwg = nbx * gridDim.y;
    const int wgid = blockIdx.y * nbx + blockIdx.x;
    const int swz = (wgid & 7) * (nwg >> 3) + (wgid >> 3);
    const int bh = swz / nbx;
    const int q0 = (swz % nbx) * 64;
    const size_t base = (size_t)bh * NS * NDK;

    bf16x8 qb[4];
    {
        const u16* qr = Qr + base + (size_t)(q0 + wave*16 + c) * NDK;
        const u16* qi = Qi + base + (size_t)(q0 + wave*16 + c) * NDK;
        #pragma unroll
        for (int s = 0; s < 2; ++s) {
            qb[s] = *(const bf16x8*)(qr + 32*s + 8*g);
            const bf16x8 t = *(const bf16x8*)(qi + 32*s + 8*g);
            bf16x8 f;
            #pragma unroll
            for (int j = 0; j < 8; ++j) f[j] = t[j] ^ (short)0x8000;
            qb[2+s] = f;
        }
    }

    const int slot = lane & 15;
    const int rloc = lane >> 4;
    const u16* kplane = (slot < 8 ? Kr : Ki) + base;
    const u16* srcK[4];
    #pragma unroll
    for (int i = 0; i < 4; ++i) {
        const int row = (wave*4 + i)*4 + rloc;
        srcK[i] = kplane + (size_t)row * NDK + ((slot ^ (row & 7)) & 7) * 8;
    }
    const int r8 = lane >> 3, sl = lane & 7;
    const u16* vbase = Vt + base;
    const u16* srcV[2];
    #pragma unroll
    for (int i = 0; i < 2; ++i) {
        const int dk = (wave*2 + i)*8 + r8;
        srcV[i] = vbase + (size_t)dk * NS + ((sl ^ r8) & 7) * 8;
    }

    f32x4 oacc[4];
    #pragma unroll
    for (int nt = 0; nt < 4; ++nt) oacc[nt] = (f32x4){0.f, 0.f, 0.f, 0.f};
    float mrun = -1e30f, lrun = 0.f;

    #pragma unroll
    for (int i = 0; i < 4; ++i)
        __builtin_amdgcn_global_load_lds((gas_p)srcK[i],
                                         (las_p)(&Ks[0] + (wave*4 + i)*512), 16, 0, 0);
    #pragma unroll
    for (int i = 0; i < 2; ++i)
        __builtin_amdgcn_global_load_lds((gas_p)srcV[i],
                                         (las_p)(&Vs[0][0] + (wave*2 + i)*512), 16, 0, 0);
    asm volatile("s_waitcnt vmcnt(0)" ::: "memory");
    __builtin_amdgcn_sched_barrier(0);
    __builtin_amdgcn_s_barrier();
    __builtin_amdgcn_sched_barrier(0);

    #define NTI (NS/64)
    for (int kt = 0; kt < NTI; ++kt) {
        const int cur = kt & 1;

        f32x4 sacc[4];
        #pragma unroll
        for (int nt = 0; nt < 4; ++nt) sacc[nt] = (f32x4){0.f, 0.f, 0.f, 0.f};
        __builtin_amdgcn_s_setprio(1);
        #pragma unroll
        for (int s = 0; s < 4; ++s) {
            #pragma unroll
            for (int nt = 0; nt < 4; ++nt) {
                const bf16x8 ka = *(const bf16x8*)((const char*)&Ks[0]
                                    + (nt*16 + c)*256 + ((64*s + 16*g) ^ ((c & 7) << 4)));
                sacc[nt] = __builtin_amdgcn_mfma_f32_16x16x32_bf16(ka, qb[s], sacc[nt], 0, 0, 0);
            }
        }
        __builtin_amdgcn_s_setprio(0);
        __builtin_amdgcn_sched_barrier(0);
        __builtin_amdgcn_s_barrier();
        __builtin_amdgcn_sched_barrier(0);

        if (kt + 1 < NTI) {
            const int nk0 = (kt + 1) * 64;
            #pragma unroll
            for (int i = 0; i < 4; ++i)
                __builtin_amdgcn_global_load_lds((gas_p)(srcK[i] + (size_t)nk0 * NDK),
                                                 (las_p)(&Ks[0] + (wave*4 + i)*512), 16, 0, 0);
            #pragma unroll
            for (int i = 0; i < 2; ++i)
                __builtin_amdgcn_global_load_lds((gas_p)(srcV[i] + nk0),
                                                 (las_p)(&Vs[cur ^ 1][0] + (wave*2 + i)*512), 16, 0, 0);
        }

        float m0 = fmaxf(fmaxf(sacc[0][0], sacc[0][1]), sacc[0][2]);
        float m1 = fmaxf(fmaxf(sacc[0][3], sacc[1][0]), sacc[1][1]);
        float m2 = fmaxf(fmaxf(sacc[1][2], sacc[1][3]), sacc[2][0]);
        float m3 = fmaxf(fmaxf(sacc[2][1], sacc[2][2]), sacc[2][3]);
        float m4 = fmaxf(fmaxf(sacc[3][0], sacc[3][1]), sacc[3][2]);
        float tmax = fmaxf(fmaxf(fmaxf(m0, m1), m2), fmaxf(fmaxf(m3, m4), sacc[3][3]));
        tmax = fmaxf(tmax, __shfl_xor(tmax, 16, 64));
        tmax = fmaxf(tmax, __shfl_xor(tmax, 32, 64));

        const bool noskip = !__all(tmax - mrun <= 11.0f);
        float corr = 1.0f;
        if (noskip) {
            const float mnew = fmaxf(mrun, tmax);
            corr = exp2f(mrun - mnew);
            mrun = mnew;
        }

        float psum = 0.f;
        #pragma unroll
        for (int nt = 0; nt < 4; ++nt) {
            float p0 = exp2f(sacc[nt][0] - mrun);
            float p1 = exp2f(sacc[nt][1] - mrun);
            float p2 = exp2f(sacc[nt][2] - mrun);
            float p3 = exp2f(sacc[nt][3] - mrun);
            psum += (p0 + p1) + (p2 + p3);
            uint2 pk;
            pk.x = cvt_pk_bf16(p0, p1);
            pk.y = cvt_pk_bf16(p2, p3);
            *(uint2*)((char*)&Ps[wave][0] + c*128 + ((32*nt + 8*g) ^ ((c & 7) << 4))) = pk;
        }
        psum += __shfl_xor(psum, 16, 64);
        psum += __shfl_xor(psum, 32, 64);

        if (noskip) {
            lrun = lrun * corr + psum;
            float corr4[4];
            #pragma unroll
            for (int j = 0; j < 4; ++j) corr4[j] = __shfl(corr, 4*g + j, 64);
            #pragma unroll
            for (int nt = 0; nt < 4; ++nt)
                #pragma unroll
                for (int j = 0; j < 4; ++j) oacc[nt][j] *= corr4[j];
        } else {
            lrun += psum;
        }

        __builtin_amdgcn_s_setprio(1);
        #pragma unroll
        for (int s = 0; s < 2; ++s) {
            const bf16x8 pa = *(const bf16x8*)((const char*)&Ps[wave][0]
                                + c*128 + ((64*s + 16*g) ^ ((c & 7) << 4)));
            #pragma unroll
            for (int nt = 0; nt < 4; ++nt) {
                const bf16x8 vb = *(const bf16x8*)((const char*)&Vs[cur][0]
                                    + (nt*16 + c)*128 + ((64*s + 16*g) ^ ((c & 7) << 4)));
                oacc[nt] = __builtin_amdgcn_mfma_f32_16x16x32_bf16(pa, vb, oacc[nt], 0, 0, 0);
            }
        }
        __builtin_amdgcn_s_setprio(0);

        if (kt + 1 < NTI) {
            asm volatile("s_waitcnt vmcnt(0)" ::: "memory");
            __builtin_amdgcn_sched_barrier(0);
            __builtin_amdgcn_s_barrier();
            __builtin_amdgcn_sched_barrier(0);
        }
    }

    const int b  = bh >> 4;
    const int hh = bh & 15;
    float linv[4];
    #pragma unroll
    for (int j = 0; j < 4; ++j) linv[j] = 1.0f / __shfl(lrun, 4*g + j, 64);
    #pragma unroll
    for (int j = 0; j < 4; ++j) {
        const int srow = q0 + wave*16 + 4*g + j;
        #pragma unroll
        for (int nt = 0; nt < 4; ++nt) {
            const float val = oacc[nt][j] * linv[j];
            const u16 hb = f2bf(val);
            const u16 lb = f2bf(val - bf2f(hb));
            const size_t o = (size_t)(b*NS + srow)*ND + hh*NDK + nt*16 + c;
            OH[o] = hb;
            OL[o] = lb;
        }
    }
}

extern "C" void kernel_launch(void* const* d_in, const int* in_sizes, int n_in,
                              void* d_out, int out_size, void* d_ws, size_t ws_size,
                              hipStream_t stream)
{
    const float* xr = (const float*)d_in[0];
    const float* xi = (const float*)d_in[1];
    const float* Wq = (const float*)d_in[2];
    const float* bq = (const float*)d_in[3];
    const float* Wk = (const float*)d_in[4];
    const float* bk = (const float*)d_in[5];
    const float* Wv = (const float*)d_in[6];
    const float* bv = (const float*)d_in[7];
    const float* Wo = (const float*)d_in[8];
    const float* bo = (const float*)d_in[9];
    float* out = (float*)d_out;

    u16* ws = (u16*)d_ws;
    const size_t PL = (size_t)NM * ND;           // 4,194,304 elems
    u16* XH = ws;                                 // stacked [xr;xi] hi, 2*PL
    u16* WT = ws + 2*PL;                          // 4 x (hi 1M + lo 1M)
    u16* QP = WT + 8 * 1048576;
    u16* Qr = QP;          u16* Qi = QP + PL;
    u16* Kr = QP + 2*PL;   u16* Ki = QP + 3*PL;
    u16* Vv = QP + 4*PL;   u16* Vt = QP + 5*PL;
    u16* OH = ws;                                 // alias dead XH region
    u16* OL = ws + PL;

    conv_x<<<2*PL/(256*4), 256, 0, stream>>>(xr, xi, XH);
    conv_wt<<<dim3(ND/64, ND/64, 4), 256, 0, stream>>>(Wq, Wk, Wv, Wo, WT);

    u16* WTq = WT;  u16* WTk = WT + 2097152;  u16* WTv = WT + 2*2097152;  u16* WTo = WT + 3*2097152;

    // Q scaled by (1/8)*log2e for exp2-domain softmax
    gemm_split<1><<<dim3(ND/128, 2*NM/128), 256, 0, stream>>>(XH, XH, WTq, WTq + 1048576, bq, Qr, Qi, nullptr, 0, 0.125f * LOG2E);
    gemm_split<1><<<dim3(ND/128, 2*NM/128), 256, 0, stream>>>(XH, XH, WTk, WTk + 1048576, bk, Kr, Ki, nullptr, 0, 1.0f);
    gemm_split<1><<<dim3(ND/128,   NM/128), 256, 0, stream>>>(XH, XH, WTv, WTv + 1048576, bv, Vv, Vv, nullptr, 0, 1.0f);

    vt_trans<<<dim3(NS/64, NB*NH), 256, 0, stream>>>(Vv, Vt);

    attn_mfma<<<dim3(NS/64, NB*NH), 256, 0, stream>>>(Qr, Qi, Kr, Ki, Vt, OH, OL);

    gemm_split<3><<<dim3(ND/128,   NM/128), 256, 0, stream>>>(OH, OL, WTo, WTo + 1048576, bo, nullptr, nullptr, out, 1, 1.0f);
}

// Round 12
// 238.076 us; speedup vs baseline: 8.9332x; 1.1388x over previous
//
#include <hip/hip_runtime.h>

#define NB 2
#define NS 2048
#define ND 1024
#define NH 16
#define NDK 64
#define NM (NB*NS)   // 4096

typedef unsigned short u16;
typedef unsigned int u32;
typedef short bf16x8 __attribute__((ext_vector_type(8)));
typedef float f32x4 __attribute__((ext_vector_type(4)));
typedef const __attribute__((address_space(1))) void* gas_p;
typedef __attribute__((address_space(3))) void* las_p;

#define LOG2E 1.4426950408889634f

__device__ __forceinline__ u16 f2bf(float f) {
    unsigned u = __builtin_bit_cast(unsigned, f);
    u += 0x7fffu + ((u >> 16) & 1u);         // RTNE
    return (u16)(u >> 16);
}
__device__ __forceinline__ float bf2f(u16 h) {
    return __builtin_bit_cast(float, (unsigned)h << 16);
}
__device__ __forceinline__ u32 cvt_pk_bf16(float a, float b) {
    u32 r;
    asm("v_cvt_pk_bf16_f32 %0, %1, %2" : "=v"(r) : "v"(a), "v"(b));
    return r;   // [15:0]=bf16(a), [31:16]=bf16(b)
}

// ============ conv_x: xr,xi fp32 -> stacked hi bf16 plane [xr; xi] ============
__global__ __launch_bounds__(256)
void conv_x(const float* __restrict__ xr, const float* __restrict__ xi,
            u16* __restrict__ XH)
{
    const size_t gid = (size_t)blockIdx.x * 256 + threadIdx.x;
    const size_t PQ = (size_t)NM * ND / 4;
    const int p = gid >= PQ;
    const size_t off = (gid - (p ? PQ : 0)) * 4;
    const float4 v = *(const float4*)&((p ? xi : xr)[off]);
    const size_t d = (size_t)p * NM * ND + off;
    float vs[4] = {v.x, v.y, v.z, v.w};
    ushort4 h;
    u16* hp = (u16*)&h;
    #pragma unroll
    for (int j = 0; j < 4; ++j) hp[j] = f2bf(vs[j]);
    *(ushort4*)&XH[d] = h;
}

// ============ conv_wt: W (K x N fp32) -> W^T hi (all) + lo (Wo only) ============
__global__ __launch_bounds__(256)
void conv_wt(const float* __restrict__ W0, const float* __restrict__ W1,
             const float* __restrict__ W2, const float* __restrict__ W3,
             u16* __restrict__ WT)
{
    __shared__ float tls[64][68];
    const int z = blockIdx.z;
    const float* W = z == 0 ? W0 : z == 1 ? W1 : z == 2 ? W2 : W3;
    u16* dh = WT + (size_t)z * 2097152;
    u16* dl = dh + 1048576;
    const int kt0 = blockIdx.y * 64;
    const int nt0 = blockIdx.x * 64;
    const int tid = threadIdx.x;

    {
        const int kk = tid >> 4;
        const int nn = (tid & 15) * 4;
        #pragma unroll
        for (int i = 0; i < 4; ++i) {
            const float4 v = *(const float4*)&W[(size_t)(kt0 + kk + 16*i) * ND + nt0 + nn];
            tls[kk + 16*i][nn] = v.x; tls[kk + 16*i][nn+1] = v.y;
            tls[kk + 16*i][nn+2] = v.z; tls[kk + 16*i][nn+3] = v.w;
        }
    }
    __syncthreads();

    const int n  = tid >> 2;
    const int kc = (tid & 3) * 16;
    u16 hb[16], lb[16];
    #pragma unroll
    for (int k = 0; k < 16; ++k) {
        const float v = tls[kc + k][n];
        hb[k] = f2bf(v);
        lb[k] = f2bf(v - bf2f(hb[k]));
    }
    #pragma unroll
    for (int half = 0; half < 2; ++half)
        *(bf16x8*)&dh[(size_t)(nt0 + n) * ND + kt0 + kc + 8*half] = *(bf16x8*)&hb[8*half];
    if (z == 3) {   // lo plane needed only for the 3-term final projection
        #pragma unroll
        for (int half = 0; half < 2; ++half)
            *(bf16x8*)&dl[(size_t)(nt0 + n) * ND + kt0 + kc + 8*half] = *(bf16x8*)&lb[8*half];
    }
}

// ============ vt_trans: Vv [bh][s][dk] -> Vt [bh][dk][s] ============
__global__ __launch_bounds__(256)
void vt_trans(const u16* __restrict__ Vv, u16* __restrict__ Vt)
{
    __shared__ u16 T[64][72];
    const int bh = blockIdx.y;
    const int s0 = blockIdx.x * 64;
    const int tid = threadIdx.x;
    const size_t base = (size_t)bh * NS * NDK;

    const int r = tid >> 3, cb = (tid & 7) * 8;
    #pragma unroll
    for (int i = 0; i < 2; ++i) {
        const int row = r + 32*i;
        *(bf16x8*)&T[row][cb] = *(const bf16x8*)(Vv + base + (size_t)(s0 + row) * NDK + cb);
    }
    __syncthreads();

    const int dk = tid >> 2, sb = (tid & 3) * 16;
    u16 buf[16];
    #pragma unroll
    for (int k = 0; k < 16; ++k) buf[k] = T[sb + k][dk];
    *(bf16x8*)(Vt + base + (size_t)dk * NS + s0 + sb)     = *(bf16x8*)&buf[0];
    *(bf16x8*)(Vt + base + (size_t)dk * NS + s0 + sb + 8) = *(bf16x8*)&buf[8];
}

// ============ bf16 MFMA GEMM, dbuf gld_lds pipeline (frozen from r11) ============
template<int TERMS>
__global__ __launch_bounds__(256)
void gemm_split(const u16* __restrict__ Ah, const u16* __restrict__ Al,
                const u16* __restrict__ Bh, const u16* __restrict__ Bl,
                const float* __restrict__ bias,
                u16* __restrict__ Yr, u16* __restrict__ Yi,
                float* __restrict__ Yf, const int mode, const float scale)
{
    constexpr int NP = TERMS + 1;            // planes: AH, BH [, BL, AL]
    __shared__ u16 LDS[2][NP][4096];         // [buf][plane][128*32]

    const int tid  = threadIdx.x;
    const int wave = tid >> 6;
    const int lane = tid & 63;
    const int g = lane >> 4;
    const int c = lane & 15;
    const int wm = wave >> 1;
    const int wn = wave & 1;

    const int nbx = gridDim.x;
    const int nwg = nbx * gridDim.y;
    const int wgid = blockIdx.y * nbx + blockIdx.x;
    const int swz = (wgid & 7) * (nwg >> 3) + (wgid >> 3);
    const int row0 = (swz / nbx) * 128;
    const int col0 = (swz % nbx) * 128;

    const int lr = lane >> 2;
    const int lq = lane & 3;
    const u16* srcs[8];
    int doffs[8];
    #pragma unroll
    for (int i = 0; i < NP*2; ++i) {
        const int ci = wave * (NP*2) + i;
        const int p = ci >> 3;
        const int o = ci & 7;
        const u16* pl = (p == 0) ? Ah : (p == 1) ? Bh : (p == 2) ? Bl : Al;
        const int rb = (p == 0 || p == 3) ? row0 : col0;
        srcs[i] = pl + (size_t)(rb + o*16 + lr) * ND + lq*8;
        doffs[i] = p*4096 + o*512;
    }

    f32x4 acc[4][4];
    #pragma unroll
    for (int i = 0; i < 4; ++i)
        #pragma unroll
        for (int j = 0; j < 4; ++j)
            acc[i][j] = (f32x4){0.f, 0.f, 0.f, 0.f};

    #pragma unroll
    for (int i = 0; i < NP*2; ++i)
        __builtin_amdgcn_global_load_lds((gas_p)srcs[i],
                                         (las_p)(&LDS[0][0][0] + doffs[i]), 16, 0, 0);

    for (int t = 0; t < 32; ++t) {
        if (t < 31) {
            u16* ldst = &LDS[(t + 1) & 1][0][0];
            #pragma unroll
            for (int i = 0; i < NP*2; ++i)
                __builtin_amdgcn_global_load_lds((gas_p)(srcs[i] + (size_t)(t + 1) * 32),
                                                 (las_p)(ldst + doffs[i]), 16, 0, 0);
            if constexpr (TERMS == 1) asm volatile("s_waitcnt vmcnt(4)" ::: "memory");
            else                      asm volatile("s_waitcnt vmcnt(8)" ::: "memory");
        } else {
            asm volatile("s_waitcnt vmcnt(0)" ::: "memory");
        }
        __builtin_amdgcn_sched_barrier(0);
        __builtin_amdgcn_s_barrier();
        __builtin_amdgcn_sched_barrier(0);

        const u16* AsH = &LDS[t & 1][0][0];
        const u16* BsH = &LDS[t & 1][1][0];

        bf16x8 a_h[4], b_h[4], b_l[4], a_l[4];
        #pragma unroll
        for (int f = 0; f < 4; ++f) {
            const int ar = wm*64 + f*16 + c;
            const int br = wn*64 + f*16 + c;
            a_h[f] = *(const bf16x8*)&AsH[ar*32 + 8*g];
            b_h[f] = *(const bf16x8*)&BsH[br*32 + 8*g];
            if constexpr (TERMS == 3) {
                b_l[f] = *(const bf16x8*)&LDS[t & 1][2][br*32 + 8*g];
                a_l[f] = *(const bf16x8*)&LDS[t & 1][3][ar*32 + 8*g];
            }
        }
        __builtin_amdgcn_s_setprio(1);
        #pragma unroll
        for (int fm = 0; fm < 4; ++fm) {
            #pragma unroll
            for (int fn = 0; fn < 4; ++fn) {
                acc[fm][fn] = __builtin_amdgcn_mfma_f32_16x16x32_bf16(a_h[fm], b_h[fn], acc[fm][fn], 0, 0, 0);
                if constexpr (TERMS == 3) {
                    acc[fm][fn] = __builtin_amdgcn_mfma_f32_16x16x32_bf16(a_h[fm], b_l[fn], acc[fm][fn], 0, 0, 0);
                    acc[fm][fn] = __builtin_amdgcn_mfma_f32_16x16x32_bf16(a_l[fm], b_h[fn], acc[fm][fn], 0, 0, 0);
                }
            }
        }
        __builtin_amdgcn_s_setprio(0);
        __builtin_amdgcn_sched_barrier(0);
        __builtin_amdgcn_s_barrier();
        __builtin_amdgcn_sched_barrier(0);
    }

    #pragma unroll
    for (int fm = 0; fm < 4; ++fm) {
        #pragma unroll
        for (int fn = 0; fn < 4; ++fn) {
            #pragma unroll
            for (int j = 0; j < 4; ++j) {
                const int m = row0 + wm*64 + fm*16 + 4*g + j;
                const int n = col0 + wn*64 + fn*16 + c;
                const float v = acc[fm][fn][j];
                if (mode == 0) {
                    const int plane = m >> 12;
                    const int mm = m & 4095;
                    const int b  = mm >> 11;
                    const int s  = mm & (NS - 1);
                    const int hh = n >> 6;
                    const int dk = n & 63;
                    const float val = v*scale + (plane == 0 ? bias[n]*scale : 0.f);
                    (plane ? Yi : Yr)[(((size_t)(b*NH + hh) * NS) + s) * NDK + dk] = f2bf(val);
                } else {
                    Yf[(size_t)m * ND + n] = v + bias[n];
                }
            }
        }
    }
}

// ============ MFMA flash attention: 8-wave / 512-thread blocks (128 q-rows),
// K single-buffer / V double-buffer, gld_lds staging, cvt_pk softmax ============
__global__ __launch_bounds__(512)
void attn_mfma(const u16* __restrict__ Qr, const u16* __restrict__ Qi,
               const u16* __restrict__ Kr, const u16* __restrict__ Ki,
               const u16* __restrict__ Vt,
               u16* __restrict__ OH, u16* __restrict__ OL)
{
    __shared__ __align__(16) u16 Ks[8192];      // [kv64][128], XOR-swz content
    __shared__ __align__(16) u16 Vs[2][4096];   // [buf][dk64][64], XOR-swz content
    __shared__ __align__(16) u16 Ps[8][1024];   // per-wave P[q16][kv64], XOR-swz

    const int tid  = threadIdx.x;
    const int wave = tid >> 6;      // 0..7
    const int lane = tid & 63;
    const int g = lane >> 4;
    const int c = lane & 15;

    const int nbx = gridDim.x;                  // 16
    const int nwg = nbx * gridDim.y;            // 512
    const int wgid = blockIdx.y * nbx + blockIdx.x;
    const int swz = (wgid & 7) * (nwg >> 3) + (wgid >> 3);
    const int bh = swz / nbx;
    const int q0 = (swz % nbx) * 128;
    const size_t base = (size_t)bh * NS * NDK;

    // Q' fragments (B-operand): lane (g,c) holds Q'[q=c][k=32s+8g+b]
    bf16x8 qb[4];
    {
        const u16* qr = Qr + base + (size_t)(q0 + wave*16 + c) * NDK;
        const u16* qi = Qi + base + (size_t)(q0 + wave*16 + c) * NDK;
        #pragma unroll
        for (int s = 0; s < 2; ++s) {
            qb[s] = *(const bf16x8*)(qr + 32*s + 8*g);
            const bf16x8 t = *(const bf16x8*)(qi + 32*s + 8*g);
            bf16x8 f;
            #pragma unroll
            for (int j = 0; j < 8; ++j) f[j] = t[j] ^ (short)0x8000;
            qb[2+s] = f;
        }
    }

    // staging maps: pre-swizzled global source + linear LDS dest (rule #21)
    // K: 16 chunks of 4 rows; wave handles chunks 2w, 2w+1
    const int slot = lane & 15;
    const int rloc = lane >> 4;
    const u16* kplane = (slot < 8 ? Kr : Ki) + base;
    const u16* srcK[2];
    #pragma unroll
    for (int i = 0; i < 2; ++i) {
        const int row = (wave*2 + i)*4 + rloc;
        srcK[i] = kplane + (size_t)row * NDK + ((slot ^ (row & 7)) & 7) * 8;
    }
    // V: 8 chunks of 8 dk-rows; wave handles chunk w
    const int r8 = lane >> 3, sl = lane & 7;
    const int dkw = wave*8 + r8;
    const u16* srcV = Vt + base + (size_t)dkw * NS + ((sl ^ r8) & 7) * 8;

    f32x4 oacc[4];
    #pragma unroll
    for (int nt = 0; nt < 4; ++nt) oacc[nt] = (f32x4){0.f, 0.f, 0.f, 0.f};
    float mrun = -1e30f, lrun = 0.f;      // state for q-row = c

    // prologue: stage tile 0
    #pragma unroll
    for (int i = 0; i < 2; ++i)
        __builtin_amdgcn_global_load_lds((gas_p)srcK[i],
                                         (las_p)(&Ks[0] + (wave*2 + i)*512), 16, 0, 0);
    __builtin_amdgcn_global_load_lds((gas_p)srcV,
                                     (las_p)(&Vs[0][0] + wave*512), 16, 0, 0);
    asm volatile("s_waitcnt vmcnt(0)" ::: "memory");
    __builtin_amdgcn_sched_barrier(0);
    __builtin_amdgcn_s_barrier();
    __builtin_amdgcn_sched_barrier(0);

    #define NTI (NS/64)
    for (int kt = 0; kt < NTI; ++kt) {
        const int cur = kt & 1;

        // ---- swapped QK^T: sacc[nt] = S[kv=16nt+4g+j][q=c] ----
        f32x4 sacc[4];
        #pragma unroll
        for (int nt = 0; nt < 4; ++nt) sacc[nt] = (f32x4){0.f, 0.f, 0.f, 0.f};
        __builtin_amdgcn_s_setprio(1);
        #pragma unroll
        for (int s = 0; s < 4; ++s) {
            #pragma unroll
            for (int nt = 0; nt < 4; ++nt) {
                const bf16x8 ka = *(const bf16x8*)((const char*)&Ks[0]
                                    + (nt*16 + c)*256 + ((64*s + 16*g) ^ ((c & 7) << 4)));
                sacc[nt] = __builtin_amdgcn_mfma_f32_16x16x32_bf16(ka, qb[s], sacc[nt], 0, 0, 0);
            }
        }
        __builtin_amdgcn_s_setprio(0);
        __builtin_amdgcn_sched_barrier(0);
        __builtin_amdgcn_s_barrier();       // B1: all waves done reading Ks
        __builtin_amdgcn_sched_barrier(0);

        // ---- issue next tile's loads (land during softmax+PV) ----
        if (kt + 1 < NTI) {
            const int nk0 = (kt + 1) * 64;
            #pragma unroll
            for (int i = 0; i < 2; ++i)
                __builtin_amdgcn_global_load_lds((gas_p)(srcK[i] + (size_t)nk0 * NDK),
                                                 (las_p)(&Ks[0] + (wave*2 + i)*512), 16, 0, 0);
            __builtin_amdgcn_global_load_lds((gas_p)(srcV + nk0),
                                             (las_p)(&Vs[cur ^ 1][0] + wave*512), 16, 0, 0);
        }

        // ---- per-lane softmax for q-row c (exp2 domain), defer-max ----
        float m0 = fmaxf(fmaxf(sacc[0][0], sacc[0][1]), sacc[0][2]);
        float m1 = fmaxf(fmaxf(sacc[0][3], sacc[1][0]), sacc[1][1]);
        float m2 = fmaxf(fmaxf(sacc[1][2], sacc[1][3]), sacc[2][0]);
        float m3 = fmaxf(fmaxf(sacc[2][1], sacc[2][2]), sacc[2][3]);
        float m4 = fmaxf(fmaxf(sacc[3][0], sacc[3][1]), sacc[3][2]);
        float tmax = fmaxf(fmaxf(fmaxf(m0, m1), m2), fmaxf(fmaxf(m3, m4), sacc[3][3]));
        tmax = fmaxf(tmax, __shfl_xor(tmax, 16, 64));
        tmax = fmaxf(tmax, __shfl_xor(tmax, 32, 64));

        const bool noskip = !__all(tmax - mrun <= 11.0f);
        float corr = 1.0f;
        if (noskip) {
            const float mnew = fmaxf(mrun, tmax);
            corr = exp2f(mrun - mnew);
            mrun = mnew;
        }

        float psum = 0.f;
        #pragma unroll
        for (int nt = 0; nt < 4; ++nt) {
            float p0 = exp2f(sacc[nt][0] - mrun);
            float p1 = exp2f(sacc[nt][1] - mrun);
            float p2 = exp2f(sacc[nt][2] - mrun);
            float p3 = exp2f(sacc[nt][3] - mrun);
            psum += (p0 + p1) + (p2 + p3);
            uint2 pk;
            pk.x = cvt_pk_bf16(p0, p1);
            pk.y = cvt_pk_bf16(p2, p3);
            *(uint2*)((char*)&Ps[wave][0] + c*128 + ((32*nt + 8*g) ^ ((c & 7) << 4))) = pk;
        }
        psum += __shfl_xor(psum, 16, 64);
        psum += __shfl_xor(psum, 32, 64);

        if (noskip) {
            lrun = lrun * corr + psum;
            float corr4[4];
            #pragma unroll
            for (int j = 0; j < 4; ++j) corr4[j] = __shfl(corr, 4*g + j, 64);
            #pragma unroll
            for (int nt = 0; nt < 4; ++nt)
                #pragma unroll
                for (int j = 0; j < 4; ++j) oacc[nt][j] *= corr4[j];
        } else {
            lrun += psum;
        }

        // ---- PV: O += P @ V^T-tiles ----
        __builtin_amdgcn_s_setprio(1);
        #pragma unroll
        for (int s = 0; s < 2; ++s) {
            const bf16x8 pa = *(const bf16x8*)((const char*)&Ps[wave][0]
                                + c*128 + ((64*s + 16*g) ^ ((c & 7) << 4)));
            #pragma unroll
            for (int nt = 0; nt < 4; ++nt) {
                const bf16x8 vb = *(const bf16x8*)((const char*)&Vs[cur][0]
                                    + (nt*16 + c)*128 + ((64*s + 16*g) ^ ((c & 7) << 4)));
                oacc[nt] = __builtin_amdgcn_mfma_f32_16x16x32_bf16(pa, vb, oacc[nt], 0, 0, 0);
            }
        }
        __builtin_amdgcn_s_setprio(0);

        if (kt + 1 < NTI) {
            asm volatile("s_waitcnt vmcnt(0)" ::: "memory");   // next K+V landed
            __builtin_amdgcn_sched_barrier(0);
            __builtin_amdgcn_s_barrier();   // B2
            __builtin_amdgcn_sched_barrier(0);
        }
    }

    // ---- epilogue: hi/lo split of O/l -> (B*S, D) ----
    const int b  = bh >> 4;
    const int hh = bh & 15;
    float linv[4];
    #pragma unroll
    for (int j = 0; j < 4; ++j) linv[j] = 1.0f / __shfl(lrun, 4*g + j, 64);
    #pragma unroll
    for (int j = 0; j < 4; ++j) {
        const int srow = q0 + wave*16 + 4*g + j;
        #pragma unroll
        for (int nt = 0; nt < 4; ++nt) {
            const float val = oacc[nt][j] * linv[j];
            const u16 hb = f2bf(val);
            const u16 lb = f2bf(val - bf2f(hb));
            const size_t o = (size_t)(b*NS + srow)*ND + hh*NDK + nt*16 + c;
            OH[o] = hb;
            OL[o] = lb;
        }
    }
}

extern "C" void kernel_launch(void* const* d_in, const int* in_sizes, int n_in,
                              void* d_out, int out_size, void* d_ws, size_t ws_size,
                              hipStream_t stream)
{
    const float* xr = (const float*)d_in[0];
    const float* xi = (const float*)d_in[1];
    const float* Wq = (const float*)d_in[2];
    const float* bq = (const float*)d_in[3];
    const float* Wk = (const float*)d_in[4];
    const float* bk = (const float*)d_in[5];
    const float* Wv = (const float*)d_in[6];
    const float* bv = (const float*)d_in[7];
    const float* Wo = (const float*)d_in[8];
    const float* bo = (const float*)d_in[9];
    float* out = (float*)d_out;

    u16* ws = (u16*)d_ws;
    const size_t PL = (size_t)NM * ND;           // 4,194,304 elems
    u16* XH = ws;                                 // stacked [xr;xi] hi, 2*PL
    u16* WT = ws + 2*PL;                          // 4 x (hi 1M + lo 1M)
    u16* QP = WT + 8 * 1048576;
    u16* Qr = QP;          u16* Qi = QP + PL;
    u16* Kr = QP + 2*PL;   u16* Ki = QP + 3*PL;
    u16* Vv = QP + 4*PL;   u16* Vt = QP + 5*PL;
    u16* OH = ws;                                 // alias dead XH region
    u16* OL = ws + PL;

    conv_x<<<2*PL/(256*4), 256, 0, stream>>>(xr, xi, XH);
    conv_wt<<<dim3(ND/64, ND/64, 4), 256, 0, stream>>>(Wq, Wk, Wv, Wo, WT);

    u16* WTq = WT;  u16* WTk = WT + 2097152;  u16* WTv = WT + 2*2097152;  u16* WTo = WT + 3*2097152;

    // Q scaled by (1/8)*log2e for exp2-domain softmax
    gemm_split<1><<<dim3(ND/128, 2*NM/128), 256, 0, stream>>>(XH, XH, WTq, WTq + 1048576, bq, Qr, Qi, nullptr, 0, 0.125f * LOG2E);
    gemm_split<1><<<dim3(ND/128, 2*NM/128), 256, 0, stream>>>(XH, XH, WTk, WTk + 1048576, bk, Kr, Ki, nullptr, 0, 1.0f);
    gemm_split<1><<<dim3(ND/128,   NM/128), 256, 0, stream>>>(XH, XH, WTv, WTv + 1048576, bv, Vv, Vv, nullptr, 0, 1.0f);

    vt_trans<<<dim3(NS/64, NB*NH), 256, 0, stream>>>(Vv, Vt);

    attn_mfma<<<dim3(NS/128, NB*NH), 512, 0, stream>>>(Qr, Qi, Kr, Ki, Vt, OH, OL);

    gemm_split<3><<<dim3(ND/128,   NM/128), 256, 0, stream>>>(OH, OL, WTo, WTo + 1048576, bo, nullptr, nullptr, out, 1, 1.0f);
}

// Round 13
// 220.298 us; speedup vs baseline: 9.6542x; 1.0807x over previous
//
#include <hip/hip_runtime.h>

#define NB 2
#define NS 2048
#define ND 1024
#define NH 16
#define NDK 64
#define NM (NB*NS)   // 4096

typedef unsigned short u16;
typedef unsigned int u32;
typedef short bf16x8 __attribute__((ext_vector_type(8)));
typedef float f32x4 __attribute__((ext_vector_type(4)));
typedef const __attribute__((address_space(1))) void* gas_p;
typedef __attribute__((address_space(3))) void* las_p;

#define LOG2E 1.4426950408889634f

__device__ __forceinline__ u16 f2bf(float f) {
    unsigned u = __builtin_bit_cast(unsigned, f);
    u += 0x7fffu + ((u >> 16) & 1u);         // RTNE
    return (u16)(u >> 16);
}
__device__ __forceinline__ float bf2f(u16 h) {
    return __builtin_bit_cast(float, (unsigned)h << 16);
}
__device__ __forceinline__ u32 cvt_pk_bf16(float a, float b) {
    u32 r;
    asm("v_cvt_pk_bf16_f32 %0, %1, %2" : "=v"(r) : "v"(a), "v"(b));
    return r;   // [15:0]=bf16(a), [31:16]=bf16(b)
}

// ============ conv_x: xr,xi fp32 -> stacked hi bf16 plane [xr; xi] ============
__global__ __launch_bounds__(256)
void conv_x(const float* __restrict__ xr, const float* __restrict__ xi,
            u16* __restrict__ XH)
{
    const size_t gid = (size_t)blockIdx.x * 256 + threadIdx.x;
    const size_t PQ = (size_t)NM * ND / 4;
    const int p = gid >= PQ;
    const size_t off = (gid - (p ? PQ : 0)) * 4;
    const float4 v = *(const float4*)&((p ? xi : xr)[off]);
    const size_t d = (size_t)p * NM * ND + off;
    float vs[4] = {v.x, v.y, v.z, v.w};
    ushort4 h;
    u16* hp = (u16*)&h;
    #pragma unroll
    for (int j = 0; j < 4; ++j) hp[j] = f2bf(vs[j]);
    *(ushort4*)&XH[d] = h;
}

// ============ conv_wt: W (K x N fp32) -> W^T hi (all) + lo (Wo only) ============
__global__ __launch_bounds__(256)
void conv_wt(const float* __restrict__ W0, const float* __restrict__ W1,
             const float* __restrict__ W2, const float* __restrict__ W3,
             u16* __restrict__ WT)
{
    __shared__ float tls[64][68];
    const int z = blockIdx.z;
    const float* W = z == 0 ? W0 : z == 1 ? W1 : z == 2 ? W2 : W3;
    u16* dh = WT + (size_t)z * 2097152;
    u16* dl = dh + 1048576;
    const int kt0 = blockIdx.y * 64;
    const int nt0 = blockIdx.x * 64;
    const int tid = threadIdx.x;

    {
        const int kk = tid >> 4;
        const int nn = (tid & 15) * 4;
        #pragma unroll
        for (int i = 0; i < 4; ++i) {
            const float4 v = *(const float4*)&W[(size_t)(kt0 + kk + 16*i) * ND + nt0 + nn];
            tls[kk + 16*i][nn] = v.x; tls[kk + 16*i][nn+1] = v.y;
            tls[kk + 16*i][nn+2] = v.z; tls[kk + 16*i][nn+3] = v.w;
        }
    }
    __syncthreads();

    const int n  = tid >> 2;
    const int kc = (tid & 3) * 16;
    u16 hb[16], lb[16];
    #pragma unroll
    for (int k = 0; k < 16; ++k) {
        const float v = tls[kc + k][n];
        hb[k] = f2bf(v);
        lb[k] = f2bf(v - bf2f(hb[k]));
    }
    #pragma unroll
    for (int half = 0; half < 2; ++half)
        *(bf16x8*)&dh[(size_t)(nt0 + n) * ND + kt0 + kc + 8*half] = *(bf16x8*)&hb[8*half];
    if (z == 3) {   // lo plane needed only for the 3-term final projection
        #pragma unroll
        for (int half = 0; half < 2; ++half)
            *(bf16x8*)&dl[(size_t)(nt0 + n) * ND + kt0 + kc + 8*half] = *(bf16x8*)&lb[8*half];
    }
}

// ============ bf16 MFMA GEMM, dbuf gld_lds pipeline ============
// TERMS=1: C = Ah@Bh                 — Q/K/V (outputs stored bf16 anyway).
// TERMS=3: C = Ah@Bh + Ah@Bl + Al@Bh — final fp32 projection.
// mode 0: scatter bf16 to (B,NH,S,DK) planes. mode 1: fp32 (M,N) out.
// mode 2: fused-transpose bf16 V^T out: [bh][dk][s] (packed uint2 writes).
template<int TERMS>
__global__ __launch_bounds__(256)
void gemm_split(const u16* __restrict__ Ah, const u16* __restrict__ Al,
                const u16* __restrict__ Bh, const u16* __restrict__ Bl,
                const float* __restrict__ bias,
                u16* __restrict__ Yr, u16* __restrict__ Yi,
                float* __restrict__ Yf, const int mode, const float scale)
{
    constexpr int NP = TERMS + 1;            // planes: AH, BH [, BL, AL]
    __shared__ u16 LDS[2][NP][4096];         // [buf][plane][128*32]

    const int tid  = threadIdx.x;
    const int wave = tid >> 6;
    const int lane = tid & 63;
    const int g = lane >> 4;
    const int c = lane & 15;
    const int wm = wave >> 1;
    const int wn = wave & 1;

    const int nbx = gridDim.x;
    const int nwg = nbx * gridDim.y;
    const int wgid = blockIdx.y * nbx + blockIdx.x;
    const int swz = (wgid & 7) * (nwg >> 3) + (wgid >> 3);
    const int row0 = (swz / nbx) * 128;
    const int col0 = (swz % nbx) * 128;

    const int lr = lane >> 2;
    const int lq = lane & 3;
    const u16* srcs[8];
    int doffs[8];
    #pragma unroll
    for (int i = 0; i < NP*2; ++i) {
        const int ci = wave * (NP*2) + i;
        const int p = ci >> 3;
        const int o = ci & 7;
        const u16* pl = (p == 0) ? Ah : (p == 1) ? Bh : (p == 2) ? Bl : Al;
        const int rb = (p == 0 || p == 3) ? row0 : col0;
        srcs[i] = pl + (size_t)(rb + o*16 + lr) * ND + lq*8;
        doffs[i] = p*4096 + o*512;
    }

    f32x4 acc[4][4];
    #pragma unroll
    for (int i = 0; i < 4; ++i)
        #pragma unroll
        for (int j = 0; j < 4; ++j)
            acc[i][j] = (f32x4){0.f, 0.f, 0.f, 0.f};

    #pragma unroll
    for (int i = 0; i < NP*2; ++i)
        __builtin_amdgcn_global_load_lds((gas_p)srcs[i],
                                         (las_p)(&LDS[0][0][0] + doffs[i]), 16, 0, 0);

    for (int t = 0; t < 32; ++t) {
        if (t < 31) {
            u16* ldst = &LDS[(t + 1) & 1][0][0];
            #pragma unroll
            for (int i = 0; i < NP*2; ++i)
                __builtin_amdgcn_global_load_lds((gas_p)(srcs[i] + (size_t)(t + 1) * 32),
                                                 (las_p)(ldst + doffs[i]), 16, 0, 0);
            if constexpr (TERMS == 1) asm volatile("s_waitcnt vmcnt(4)" ::: "memory");
            else                      asm volatile("s_waitcnt vmcnt(8)" ::: "memory");
        } else {
            asm volatile("s_waitcnt vmcnt(0)" ::: "memory");
        }
        __builtin_amdgcn_sched_barrier(0);
        __builtin_amdgcn_s_barrier();
        __builtin_amdgcn_sched_barrier(0);

        const u16* AsH = &LDS[t & 1][0][0];
        const u16* BsH = &LDS[t & 1][1][0];

        bf16x8 a_h[4], b_h[4], b_l[4], a_l[4];
        #pragma unroll
        for (int f = 0; f < 4; ++f) {
            const int ar = wm*64 + f*16 + c;
            const int br = wn*64 + f*16 + c;
            a_h[f] = *(const bf16x8*)&AsH[ar*32 + 8*g];
            b_h[f] = *(const bf16x8*)&BsH[br*32 + 8*g];
            if constexpr (TERMS == 3) {
                b_l[f] = *(const bf16x8*)&LDS[t & 1][2][br*32 + 8*g];
                a_l[f] = *(const bf16x8*)&LDS[t & 1][3][ar*32 + 8*g];
            }
        }
        __builtin_amdgcn_s_setprio(1);
        #pragma unroll
        for (int fm = 0; fm < 4; ++fm) {
            #pragma unroll
            for (int fn = 0; fn < 4; ++fn) {
                acc[fm][fn] = __builtin_amdgcn_mfma_f32_16x16x32_bf16(a_h[fm], b_h[fn], acc[fm][fn], 0, 0, 0);
                if constexpr (TERMS == 3) {
                    acc[fm][fn] = __builtin_amdgcn_mfma_f32_16x16x32_bf16(a_h[fm], b_l[fn], acc[fm][fn], 0, 0, 0);
                    acc[fm][fn] = __builtin_amdgcn_mfma_f32_16x16x32_bf16(a_l[fm], b_h[fn], acc[fm][fn], 0, 0, 0);
                }
            }
        }
        __builtin_amdgcn_s_setprio(0);
        __builtin_amdgcn_sched_barrier(0);
        __builtin_amdgcn_s_barrier();
        __builtin_amdgcn_sched_barrier(0);
    }

    #pragma unroll
    for (int fm = 0; fm < 4; ++fm) {
        #pragma unroll
        for (int fn = 0; fn < 4; ++fn) {
            const int n = col0 + wn*64 + fn*16 + c;
            if (mode == 2) {
                // fused V^T: m -> (b,s) consecutive in j; write packed 4x bf16
                const int m0 = row0 + wm*64 + fm*16 + 4*g;
                const int b  = m0 >> 11;
                const int s  = m0 & (NS - 1);
                const int hh = n >> 6;
                const int dk = n & 63;
                const float bv = bias[n];
                uint2 pk;
                pk.x = cvt_pk_bf16(acc[fm][fn][0] + bv, acc[fm][fn][1] + bv);
                pk.y = cvt_pk_bf16(acc[fm][fn][2] + bv, acc[fm][fn][3] + bv);
                *(uint2*)&Yr[((size_t)(b*NH + hh) * NDK + dk) * NS + s] = pk;
            } else {
                #pragma unroll
                for (int j = 0; j < 4; ++j) {
                    const int m = row0 + wm*64 + fm*16 + 4*g + j;
                    const float v = acc[fm][fn][j];
                    if (mode == 0) {
                        const int plane = m >> 12;
                        const int mm = m & 4095;
                        const int b  = mm >> 11;
                        const int s  = mm & (NS - 1);
                        const int hh = n >> 6;
                        const int dk = n & 63;
                        const float val = v*scale + (plane == 0 ? bias[n]*scale : 0.f);
                        (plane ? Yi : Yr)[(((size_t)(b*NH + hh) * NS) + s) * NDK + dk] = f2bf(val);
                    } else {
                        Yf[(size_t)m * ND + n] = v + bias[n];
                    }
                }
            }
        }
    }
}

// ============ MFMA flash attention: 8-wave blocks, NO max-tracking softmax
// (scores bounded: P = exp2(s) exact-identity), deferred l-reduce ============
__global__ __launch_bounds__(512)
void attn_mfma(const u16* __restrict__ Qr, const u16* __restrict__ Qi,
               const u16* __restrict__ Kr, const u16* __restrict__ Ki,
               const u16* __restrict__ Vt,
               u16* __restrict__ OH, u16* __restrict__ OL)
{
    __shared__ __align__(16) u16 Ks[8192];      // [kv64][128], XOR-swz content
    __shared__ __align__(16) u16 Vs[2][4096];   // [buf][dk64][64], XOR-swz content
    __shared__ __align__(16) u16 Ps[8][1024];   // per-wave P[q16][kv64], XOR-swz

    const int tid  = threadIdx.x;
    const int wave = tid >> 6;      // 0..7
    const int lane = tid & 63;
    const int g = lane >> 4;
    const int c = lane & 15;

    const int nbx = gridDim.x;                  // 16
    const int nwg = nbx * gridDim.y;            // 512
    const int wgid = blockIdx.y * nbx + blockIdx.x;
    const int swz = (wgid & 7) * (nwg >> 3) + (wgid >> 3);
    const int bh = swz / nbx;
    const int q0 = (swz % nbx) * 128;
    const size_t base = (size_t)bh * NS * NDK;

    // Q' fragments (B-operand): lane (g,c) holds Q'[q=c][k=32s+8g+b]
    bf16x8 qb[4];
    {
        const u16* qr = Qr + base + (size_t)(q0 + wave*16 + c) * NDK;
        const u16* qi = Qi + base + (size_t)(q0 + wave*16 + c) * NDK;
        #pragma unroll
        for (int s = 0; s < 2; ++s) {
            qb[s] = *(const bf16x8*)(qr + 32*s + 8*g);
            const bf16x8 t = *(const bf16x8*)(qi + 32*s + 8*g);
            bf16x8 f;
            #pragma unroll
            for (int j = 0; j < 8; ++j) f[j] = t[j] ^ (short)0x8000;
            qb[2+s] = f;
        }
    }

    // staging maps: pre-swizzled global source + linear LDS dest (rule #21)
    const int slot = lane & 15;
    const int rloc = lane >> 4;
    const u16* kplane = (slot < 8 ? Kr : Ki) + base;
    const u16* srcK[2];
    #pragma unroll
    for (int i = 0; i < 2; ++i) {
        const int row = (wave*2 + i)*4 + rloc;
        srcK[i] = kplane + (size_t)row * NDK + ((slot ^ (row & 7)) & 7) * 8;
    }
    const int r8 = lane >> 3, sl = lane & 7;
    const int dkw = wave*8 + r8;
    const u16* srcV = Vt + base + (size_t)dkw * NS + ((sl ^ r8) & 7) * 8;

    f32x4 oacc[4];
    #pragma unroll
    for (int nt = 0; nt < 4; ++nt) oacc[nt] = (f32x4){0.f, 0.f, 0.f, 0.f};
    float lrun = 0.f;                      // per-lane partial; reduced at epilogue

    // prologue: stage tile 0
    #pragma unroll
    for (int i = 0; i < 2; ++i)
        __builtin_amdgcn_global_load_lds((gas_p)srcK[i],
                                         (las_p)(&Ks[0] + (wave*2 + i)*512), 16, 0, 0);
    __builtin_amdgcn_global_load_lds((gas_p)srcV,
                                     (las_p)(&Vs[0][0] + wave*512), 16, 0, 0);
    asm volatile("s_waitcnt vmcnt(0)" ::: "memory");
    __builtin_amdgcn_sched_barrier(0);
    __builtin_amdgcn_s_barrier();
    __builtin_amdgcn_sched_barrier(0);

    #define NTI (NS/64)
    for (int kt = 0; kt < NTI; ++kt) {
        const int cur = kt & 1;

        // ---- swapped QK^T: sacc[nt] = S[kv=16nt+4g+j][q=c] ----
        f32x4 sacc[4];
        #pragma unroll
        for (int nt = 0; nt < 4; ++nt) sacc[nt] = (f32x4){0.f, 0.f, 0.f, 0.f};
        __builtin_amdgcn_s_setprio(1);
        #pragma unroll
        for (int s = 0; s < 4; ++s) {
            #pragma unroll
            for (int nt = 0; nt < 4; ++nt) {
                const bf16x8 ka = *(const bf16x8*)((const char*)&Ks[0]
                                    + (nt*16 + c)*256 + ((64*s + 16*g) ^ ((c & 7) << 4)));
                sacc[nt] = __builtin_amdgcn_mfma_f32_16x16x32_bf16(ka, qb[s], sacc[nt], 0, 0, 0);
            }
        }
        __builtin_amdgcn_s_setprio(0);
        __builtin_amdgcn_sched_barrier(0);
        __builtin_amdgcn_s_barrier();       // B1: all waves done reading Ks
        __builtin_amdgcn_sched_barrier(0);

        // ---- issue next tile's loads (land during softmax+PV) ----
        if (kt + 1 < NTI) {
            const int nk0 = (kt + 1) * 64;
            #pragma unroll
            for (int i = 0; i < 2; ++i)
                __builtin_amdgcn_global_load_lds((gas_p)(srcK[i] + (size_t)nk0 * NDK),
                                                 (las_p)(&Ks[0] + (wave*2 + i)*512), 16, 0, 0);
            __builtin_amdgcn_global_load_lds((gas_p)(srcV + nk0),
                                             (las_p)(&Vs[cur ^ 1][0] + wave*512), 16, 0, 0);
        }

        // ---- max-free softmax: P = exp2(s) (scores bounded ~|s|<=12) ----
        #pragma unroll
        for (int nt = 0; nt < 4; ++nt) {
            float p0 = exp2f(sacc[nt][0]);
            float p1 = exp2f(sacc[nt][1]);
            float p2 = exp2f(sacc[nt][2]);
            float p3 = exp2f(sacc[nt][3]);
            lrun += (p0 + p1) + (p2 + p3);
            uint2 pk;
            pk.x = cvt_pk_bf16(p0, p1);
            pk.y = cvt_pk_bf16(p2, p3);
            *(uint2*)((char*)&Ps[wave][0] + c*128 + ((32*nt + 8*g) ^ ((c & 7) << 4))) = pk;
        }

        // ---- PV: O += P @ V^T-tiles ----
        __builtin_amdgcn_s_setprio(1);
        #pragma unroll
        for (int s = 0; s < 2; ++s) {
            const bf16x8 pa = *(const bf16x8*)((const char*)&Ps[wave][0]
                                + c*128 + ((64*s + 16*g) ^ ((c & 7) << 4)));
            #pragma unroll
            for (int nt = 0; nt < 4; ++nt) {
                const bf16x8 vb = *(const bf16x8*)((const char*)&Vs[cur][0]
                                    + (nt*16 + c)*128 + ((64*s + 16*g) ^ ((c & 7) << 4)));
                oacc[nt] = __builtin_amdgcn_mfma_f32_16x16x32_bf16(pa, vb, oacc[nt], 0, 0, 0);
            }
        }
        __builtin_amdgcn_s_setprio(0);

        if (kt + 1 < NTI) {
            asm volatile("s_waitcnt vmcnt(0)" ::: "memory");   // next K+V landed
            __builtin_amdgcn_sched_barrier(0);
            __builtin_amdgcn_s_barrier();   // B2
            __builtin_amdgcn_sched_barrier(0);
        }
    }

    // ---- epilogue: reduce l once, hi/lo split of O/l -> (B*S, D) ----
    lrun += __shfl_xor(lrun, 16, 64);
    lrun += __shfl_xor(lrun, 32, 64);
    const int b  = bh >> 4;
    const int hh = bh & 15;
    float linv[4];
    #pragma unroll
    for (int j = 0; j < 4; ++j) linv[j] = 1.0f / __shfl(lrun, 4*g + j, 64);
    #pragma unroll
    for (int j = 0; j < 4; ++j) {
        const int srow = q0 + wave*16 + 4*g + j;
        #pragma unroll
        for (int nt = 0; nt < 4; ++nt) {
            const float val = oacc[nt][j] * linv[j];
            const u16 hb = f2bf(val);
            const u16 lb = f2bf(val - bf2f(hb));
            const size_t o = (size_t)(b*NS + srow)*ND + hh*NDK + nt*16 + c;
            OH[o] = hb;
            OL[o] = lb;
        }
    }
}

extern "C" void kernel_launch(void* const* d_in, const int* in_sizes, int n_in,
                              void* d_out, int out_size, void* d_ws, size_t ws_size,
                              hipStream_t stream)
{
    const float* xr = (const float*)d_in[0];
    const float* xi = (const float*)d_in[1];
    const float* Wq = (const float*)d_in[2];
    const float* bq = (const float*)d_in[3];
    const float* Wk = (const float*)d_in[4];
    const float* bk = (const float*)d_in[5];
    const float* Wv = (const float*)d_in[6];
    const float* bv = (const float*)d_in[7];
    const float* Wo = (const float*)d_in[8];
    const float* bo = (const float*)d_in[9];
    float* out = (float*)d_out;

    u16* ws = (u16*)d_ws;
    const size_t PL = (size_t)NM * ND;           // 4,194,304 elems
    u16* XH = ws;                                 // stacked [xr;xi] hi, 2*PL
    u16* WT = ws + 2*PL;                          // 4 x (hi 1M + lo 1M)
    u16* QP = WT + 8 * 1048576;
    u16* Qr = QP;          u16* Qi = QP + PL;
    u16* Kr = QP + 2*PL;   u16* Ki = QP + 3*PL;
    u16* Vt = QP + 4*PL;                          // V^T [bh][dk][s], written by gemm mode 2
    u16* OH = ws;                                 // alias dead XH region
    u16* OL = ws + PL;

    conv_x<<<2*PL/(256*4), 256, 0, stream>>>(xr, xi, XH);
    conv_wt<<<dim3(ND/64, ND/64, 4), 256, 0, stream>>>(Wq, Wk, Wv, Wo, WT);

    u16* WTq = WT;  u16* WTk = WT + 2097152;  u16* WTv = WT + 2*2097152;  u16* WTo = WT + 3*2097152;

    // Q scaled by (1/8)*log2e for exp2-domain softmax
    gemm_split<1><<<dim3(ND/128, 2*NM/128), 256, 0, stream>>>(XH, XH, WTq, WTq + 1048576, bq, Qr, Qi, nullptr, 0, 0.125f * LOG2E);
    gemm_split<1><<<dim3(ND/128, 2*NM/128), 256, 0, stream>>>(XH, XH, WTk, WTk + 1048576, bk, Kr, Ki, nullptr, 0, 1.0f);
    gemm_split<1><<<dim3(ND/128,   NM/128), 256, 0, stream>>>(XH, XH, WTv, WTv + 1048576, bv, Vt, nullptr, nullptr, 2, 1.0f);

    attn_mfma<<<dim3(NS/128, NB*NH), 512, 0, stream>>>(Qr, Qi, Kr, Ki, Vt, OH, OL);

    gemm_split<3><<<dim3(ND/128,   NM/128), 256, 0, stream>>>(OH, OL, WTo, WTo + 1048576, bo, nullptr, nullptr, out, 1, 1.0f);
}